// Round 1
// baseline (11769.337 us; speedup 1.0000x reference)
//
#include <hip/hip_runtime.h>
#include <math.h>
#include <stdio.h>

#define N_NODES 16384
#define DIM     512
#define BSZ     16
#define SEQ     1024      /* N_NODES / BSZ */
#define MCTX    256
#define NHEAD   8
#define DHEAD   64
#define NLAYER  4
#define NEDGE   262144
#define DFF     2048      /* 4*D */
#define DG      4096      /* 8*D */
#define LNEPS   1e-5f

__device__ __forceinline__ float gelu_exact(float x) {
    return 0.5f * x * (1.0f + erff(x * 0.70710678118654752f));
}

// ---------------------------------------------------------------------------
// Generic f32 GEMM: C = [resid +] A(MxK) @ B(KxN) [+ bias]
// Tiles: 128x128, BK=16, 256 threads, 8x8 per thread, k-major LDS.
// GEGLU=true: A(r,k) = U[r*lda+k] * gelu(U[r*lda+k+DFF])   (K = DFF, lda = DG)
// ---------------------------------------------------------------------------
template<bool GEGLU>
__global__ __launch_bounds__(256) void gemm128(
    const float* __restrict__ A, int lda,
    const float* __restrict__ B, int ldb,
    const float* __restrict__ bias,
    const float* __restrict__ resid, int ldr,
    float* __restrict__ C, int ldc, int K)
{
    __shared__ float As[16][128];
    __shared__ float Bs[16][128];
    const int tid = threadIdx.x;
    const int tx = tid & 15, ty = tid >> 4;
    const int row0 = blockIdx.y * 128;
    const int col0 = blockIdx.x * 128;

    float acc[8][8];
#pragma unroll
    for (int i = 0; i < 8; ++i)
#pragma unroll
        for (int j = 0; j < 8; ++j) acc[i][j] = 0.f;

    for (int k0 = 0; k0 < K; k0 += 16) {
#pragma unroll
        for (int i = 0; i < 2; ++i) {
            int idx = tid * 2 + i;
            int r = idx >> 2, kq = idx & 3;
            const float* ap = A + (size_t)(row0 + r) * lda + k0 + kq * 4;
            float4 v = *(const float4*)ap;
            if (GEGLU) {
                float4 g = *(const float4*)(ap + DFF);
                v.x *= gelu_exact(g.x); v.y *= gelu_exact(g.y);
                v.z *= gelu_exact(g.z); v.w *= gelu_exact(g.w);
            }
            As[kq * 4 + 0][r] = v.x; As[kq * 4 + 1][r] = v.y;
            As[kq * 4 + 2][r] = v.z; As[kq * 4 + 3][r] = v.w;
        }
#pragma unroll
        for (int i = 0; i < 2; ++i) {
            int idx = tid * 2 + i;
            int k = idx >> 5, cq = idx & 31;
            *(float4*)&Bs[k][cq * 4] =
                *(const float4*)(B + (size_t)(k0 + k) * ldb + col0 + cq * 4);
        }
        __syncthreads();
#pragma unroll
        for (int k = 0; k < 16; ++k) {
            float a[8], bb[8];
            *(float4*)&a[0]  = *(const float4*)&As[k][ty * 8];
            *(float4*)&a[4]  = *(const float4*)&As[k][ty * 8 + 4];
            *(float4*)&bb[0] = *(const float4*)&Bs[k][tx * 4];
            *(float4*)&bb[4] = *(const float4*)&Bs[k][64 + tx * 4];
#pragma unroll
            for (int i2 = 0; i2 < 8; ++i2)
#pragma unroll
                for (int j = 0; j < 8; ++j)
                    acc[i2][j] = fmaf(a[i2], bb[j], acc[i2][j]);
        }
        __syncthreads();
    }

#pragma unroll
    for (int i = 0; i < 8; ++i) {
        size_t r = (size_t)row0 + ty * 8 + i;
        float o[8];
#pragma unroll
        for (int j = 0; j < 8; ++j) o[j] = acc[i][j];
        int c0 = col0 + tx * 4, c1 = col0 + 64 + tx * 4;
        if (bias) {
#pragma unroll
            for (int j = 0; j < 4; ++j) { o[j] += bias[c0 + j]; o[4 + j] += bias[c1 + j]; }
        }
        if (resid) {
            const float* rp = resid + r * ldr;
#pragma unroll
            for (int j = 0; j < 4; ++j) { o[j] += rp[c0 + j]; o[4 + j] += rp[c1 + j]; }
        }
        float* cp = C + r * ldc;
        float4 s0 = make_float4(o[0], o[1], o[2], o[3]);
        float4 s1 = make_float4(o[4], o[5], o[6], o[7]);
        *(float4*)(cp + c0) = s0;
        *(float4*)(cp + c1) = s1;
    }
}

// ---------------------------------------------------------------------------
// BatchNorm over axis 0 (batch stats, biased var)
// ---------------------------------------------------------------------------
__global__ __launch_bounds__(512) void bn_colstats(const float* __restrict__ x,
                                                   float* __restrict__ cs,
                                                   float* __restrict__ cq)
{
    int c = threadIdx.x;
    int r0 = blockIdx.x * 128;
    float s = 0.f, q = 0.f;
    for (int r = 0; r < 128; ++r) {
        float v = x[(size_t)(r0 + r) * DIM + c];
        s += v; q += v * v;
    }
    atomicAdd(&cs[c], s);
    atomicAdd(&cq[c], q);
}

__global__ void bn_finalize(const float* __restrict__ cs, const float* __restrict__ cq,
                            const float* __restrict__ bw, const float* __restrict__ bb,
                            float* __restrict__ scale, float* __restrict__ shift)
{
    int c = threadIdx.x;
    float m   = cs[c] * (1.f / N_NODES);
    float var = cq[c] * (1.f / N_NODES) - m * m;
    float rs  = rsqrtf(var + LNEPS);
    float sc  = rs * bw[c];
    scale[c] = sc;
    shift[c] = bb[c] - m * sc;
}

__global__ __launch_bounds__(256) void bn_apply(const float* __restrict__ x,
                                                const float* __restrict__ scale,
                                                const float* __restrict__ shift,
                                                float* __restrict__ out)
{
    size_t idx = (size_t)blockIdx.x * 256 + threadIdx.x;   // float4 index
    int c4 = (int)(idx & 127);
    float4 v  = ((const float4*)x)[idx];
    float4 sc = ((const float4*)scale)[c4];
    float4 sh = ((const float4*)shift)[c4];
    float4 o;
    o.x = v.x * sc.x + sh.x; o.y = v.y * sc.y + sh.y;
    o.z = v.z * sc.z + sh.z; o.w = v.w * sc.w + sh.w;
    ((float4*)out)[idx] = o;
}

// ---------------------------------------------------------------------------
// LayerNorm (rows of 512), one wave per row
// ---------------------------------------------------------------------------
__global__ __launch_bounds__(256) void layernorm_k(const float* __restrict__ in,
                                                   const float* __restrict__ w,
                                                   const float* __restrict__ bsh,
                                                   float* __restrict__ out)
{
    int lane = threadIdx.x & 63, wv = threadIdx.x >> 6;
    size_t row = (size_t)blockIdx.x * 4 + wv;
    const float* p = in + row * DIM;
    float4 v0 = *(const float4*)(p + lane * 4);
    float4 v1 = *(const float4*)(p + 256 + lane * 4);
    float s = v0.x + v0.y + v0.z + v0.w + v1.x + v1.y + v1.z + v1.w;
    float q = v0.x * v0.x + v0.y * v0.y + v0.z * v0.z + v0.w * v0.w +
              v1.x * v1.x + v1.y * v1.y + v1.z * v1.z + v1.w * v1.w;
    for (int m = 1; m < 64; m <<= 1) {
        s += __shfl_xor(s, m, 64);
        q += __shfl_xor(q, m, 64);
    }
    float mean = s * (1.f / DIM);
    float rs = rsqrtf(q * (1.f / DIM) - mean * mean + LNEPS);
    float4 w0 = *(const float4*)(w + lane * 4),  w1 = *(const float4*)(w + 256 + lane * 4);
    float4 b0 = *(const float4*)(bsh + lane * 4), b1 = *(const float4*)(bsh + 256 + lane * 4);
    float* o = out + row * DIM;
    float4 r0, r1;
    r0.x = (v0.x - mean) * rs * w0.x + b0.x; r0.y = (v0.y - mean) * rs * w0.y + b0.y;
    r0.z = (v0.z - mean) * rs * w0.z + b0.z; r0.w = (v0.w - mean) * rs * w0.w + b0.w;
    r1.x = (v1.x - mean) * rs * w1.x + b1.x; r1.y = (v1.y - mean) * rs * w1.y + b1.y;
    r1.z = (v1.z - mean) * rs * w1.z + b1.z; r1.w = (v1.w - mean) * rs * w1.w + b1.w;
    *(float4*)(o + lane * 4) = r0;
    *(float4*)(o + 256 + lane * 4) = r1;
}

// ---------------------------------------------------------------------------
// Attention (two-pass, 4-batch chunks). S layout: [bl][h][r][m]
// ---------------------------------------------------------------------------
__global__ __launch_bounds__(256) void attn_qk(const float* __restrict__ Q,
                                               const float* __restrict__ Kb,
                                               float* __restrict__ S, int bchunk)
{
    __shared__ float Qs[64][64];   // k-major: Qs[k][r]
    __shared__ float Ks[64][64];   // k-major: Ks[k][m]
    const int tid = threadIdx.x;
    const int tx = tid & 15, ty = tid >> 4;
    const int bl = blockIdx.z >> 3, hh = blockIdx.z & 7;
    const int b = bchunk * 4 + bl;
    const int r0 = blockIdx.y * 64, m0 = blockIdx.x * 64;

#pragma unroll
    for (int i = 0; i < 4; ++i) {
        int fidx = i * 256 + tid;
        int r = fidx >> 4, kq = fidx & 15;
        float4 v = *(const float4*)(Q + (size_t)(b * SEQ + r0 + r) * DIM + hh * DHEAD + kq * 4);
        Qs[kq * 4 + 0][r] = v.x; Qs[kq * 4 + 1][r] = v.y;
        Qs[kq * 4 + 2][r] = v.z; Qs[kq * 4 + 3][r] = v.w;
        float4 w = *(const float4*)(Kb + (size_t)(b * MCTX + m0 + r) * DIM + hh * DHEAD + kq * 4);
        Ks[kq * 4 + 0][r] = w.x; Ks[kq * 4 + 1][r] = w.y;
        Ks[kq * 4 + 2][r] = w.z; Ks[kq * 4 + 3][r] = w.w;
    }
    __syncthreads();

    float acc[4][4];
#pragma unroll
    for (int i = 0; i < 4; ++i)
#pragma unroll
        for (int j = 0; j < 4; ++j) acc[i][j] = 0.f;

#pragma unroll
    for (int k = 0; k < 64; ++k) {
        float4 a  = *(const float4*)&Qs[k][ty * 4];
        float4 bb = *(const float4*)&Ks[k][tx * 4];
        float av[4] = {a.x, a.y, a.z, a.w};
        float bv[4] = {bb.x, bb.y, bb.z, bb.w};
#pragma unroll
        for (int i = 0; i < 4; ++i)
#pragma unroll
            for (int j = 0; j < 4; ++j)
                acc[i][j] = fmaf(av[i], bv[j], acc[i][j]);
    }
    const float sc = 0.125f;   // DH^-0.5
    size_t base = (size_t)(bl * NHEAD + hh) * SEQ;
#pragma unroll
    for (int i = 0; i < 4; ++i) {
        float4 v = make_float4(acc[i][0] * sc, acc[i][1] * sc, acc[i][2] * sc, acc[i][3] * sc);
        *(float4*)(S + (base + r0 + ty * 4 + i) * MCTX + m0 + tx * 4) = v;
    }
}

__global__ __launch_bounds__(256) void softmax_k(float* __restrict__ S)
{
    int lane = threadIdx.x & 63, wv = threadIdx.x >> 6;
    size_t row = (size_t)blockIdx.x * 4 + wv;
    float* p = S + row * MCTX + lane * 4;
    float4 v = *(float4*)p;
    float mx = fmaxf(fmaxf(v.x, v.y), fmaxf(v.z, v.w));
    for (int m = 1; m < 64; m <<= 1) mx = fmaxf(mx, __shfl_xor(mx, m, 64));
    v.x = expf(v.x - mx); v.y = expf(v.y - mx);
    v.z = expf(v.z - mx); v.w = expf(v.w - mx);
    float s = v.x + v.y + v.z + v.w;
    for (int m = 1; m < 64; m <<= 1) s += __shfl_xor(s, m, 64);
    float inv = 1.f / s;
    v.x *= inv; v.y *= inv; v.z *= inv; v.w *= inv;
    *(float4*)p = v;
}

__global__ __launch_bounds__(256) void attn_pv(const float* __restrict__ S,
                                               const float* __restrict__ Vb,
                                               float* __restrict__ O, int bchunk)
{
    __shared__ float Ps[64][64];   // k-major: Ps[m][r]
    __shared__ float Vs[64][64];   // Vs[m][dh]
    const int tid = threadIdx.x;
    const int tx = tid & 15, ty = tid >> 4;
    const int bl = blockIdx.y >> 3, hh = blockIdx.y & 7;
    const int b = bchunk * 4 + bl;
    const int r0 = blockIdx.x * 64;

    float acc[4][4];
#pragma unroll
    for (int i = 0; i < 4; ++i)
#pragma unroll
        for (int j = 0; j < 4; ++j) acc[i][j] = 0.f;

    size_t sbase = (size_t)(bl * NHEAD + hh) * SEQ;
    for (int m0 = 0; m0 < MCTX; m0 += 64) {
#pragma unroll
        for (int i = 0; i < 4; ++i) {
            int fidx = i * 256 + tid;
            int rr = fidx >> 4, mq = fidx & 15;
            float4 v = *(const float4*)(S + (sbase + r0 + rr) * MCTX + m0 + mq * 4);
            Ps[mq * 4 + 0][rr] = v.x; Ps[mq * 4 + 1][rr] = v.y;
            Ps[mq * 4 + 2][rr] = v.z; Ps[mq * 4 + 3][rr] = v.w;
            int m = fidx >> 4, dq = fidx & 15;
            *(float4*)&Vs[m][dq * 4] =
                *(const float4*)(Vb + (size_t)(b * MCTX + m0 + m) * DIM + hh * DHEAD + dq * 4);
        }
        __syncthreads();
#pragma unroll
        for (int m = 0; m < 64; ++m) {
            float4 a  = *(const float4*)&Ps[m][ty * 4];
            float4 bb = *(const float4*)&Vs[m][tx * 4];
            float av[4] = {a.x, a.y, a.z, a.w};
            float bv[4] = {bb.x, bb.y, bb.z, bb.w};
#pragma unroll
            for (int i = 0; i < 4; ++i)
#pragma unroll
                for (int j = 0; j < 4; ++j)
                    acc[i][j] = fmaf(av[i], bv[j], acc[i][j]);
        }
        __syncthreads();
    }
#pragma unroll
    for (int i = 0; i < 4; ++i) {
        float4 v = make_float4(acc[i][0], acc[i][1], acc[i][2], acc[i][3]);
        *(float4*)(O + (size_t)(b * SEQ + r0 + ty * 4 + i) * DIM + hh * DHEAD + tx * 4) = v;
    }
}

// ---------------------------------------------------------------------------
// GCN: edge-dtype detect, degree, dinv, CSR build, gather
// ---------------------------------------------------------------------------
__global__ void detect_i64(const int* __restrict__ e, int* __restrict__ flag)
{
    int idx = blockIdx.x * blockDim.x + threadIdx.x;   // idx < NEDGE
    if (e[2 * idx + 1] != 0) flag[0] = 1;              // int32 layout detected
}

__global__ void deg_count(const int* __restrict__ eb, const int* __restrict__ flag,
                          int* __restrict__ deg)
{
    int e = blockIdx.x * blockDim.x + threadIdx.x;
    int d;
    if (flag[0]) d = eb[NEDGE + e];
    else         d = (int)((const long long*)eb)[NEDGE + e];
    atomicAdd(&deg[d], 1);
}

__global__ void dinv_k(const int* __restrict__ deg, float* __restrict__ dinv)
{
    int i = blockIdx.x * blockDim.x + threadIdx.x;
    dinv[i] = rsqrtf((float)(deg[i] + 1));   // +1 self loop
}

__global__ __launch_bounds__(1024) void scan_deg(const int* __restrict__ deg,
                                                 int* __restrict__ off)
{
    __shared__ int sums[1024];
    int t = threadIdx.x;
    int base = t * 16;
    int v[16]; int s = 0;
#pragma unroll
    for (int i = 0; i < 16; ++i) { v[i] = deg[base + i]; s += v[i]; }
    sums[t] = s;
    __syncthreads();
    for (int ofs = 1; ofs < 1024; ofs <<= 1) {
        int x = (t >= ofs) ? sums[t - ofs] : 0;
        __syncthreads();
        sums[t] += x;
        __syncthreads();
    }
    int run = (t == 0) ? 0 : sums[t - 1];
#pragma unroll
    for (int i = 0; i < 16; ++i) { off[base + i] = run; run += v[i]; }
    if (t == 1023) off[N_NODES] = run;
}

__global__ void fill_k(const int* __restrict__ eb, const int* __restrict__ flag,
                       const int* __restrict__ off, int* __restrict__ cursor,
                       int* __restrict__ csr)
{
    int e = blockIdx.x * blockDim.x + threadIdx.x;
    int s, d;
    if (flag[0]) { s = eb[e]; d = eb[NEDGE + e]; }
    else {
        const long long* p = (const long long*)eb;
        s = (int)p[e]; d = (int)p[NEDGE + e];
    }
    int pos = atomicAdd(&cursor[d], 1);
    csr[off[d] + pos] = s;
}

__global__ __launch_bounds__(256) void gcn_gather(
    const float* __restrict__ h2, const int* __restrict__ csr,
    const int* __restrict__ off, const float* __restrict__ dinv,
    const float* __restrict__ bias, const float* __restrict__ addx,
    float* __restrict__ out)
{
    int lane = threadIdx.x & 63, wv = threadIdx.x >> 6;
    int d = blockIdx.x * 4 + wv;
    float acc[8];
#pragma unroll
    for (int j = 0; j < 8; ++j) acc[j] = 0.f;
    int e0 = off[d], e1 = off[d + 1];
    float dd = dinv[d];
    for (int e = e0; e < e1; ++e) {
        int sidx = csr[e];
        float wgt = dinv[sidx] * dd;
        const float* hp = h2 + (size_t)sidx * DIM;
#pragma unroll
        for (int j = 0; j < 8; ++j) acc[j] = fmaf(hp[j * 64 + lane], wgt, acc[j]);
    }
    const float* hd = h2 + (size_t)d * DIM;
    float sw = dd * dd;
#pragma unroll
    for (int j = 0; j < 8; ++j) acc[j] = fmaf(hd[j * 64 + lane], sw, acc[j]);
    float* op = out + (size_t)d * DIM;
#pragma unroll
    for (int j = 0; j < 8; ++j) {
        float o = acc[j] + bias[j * 64 + lane];
        if (addx) o += addx[(size_t)d * DIM + j * 64 + lane];
        op[j * 64 + lane] = o;
    }
}

// ---------------------------------------------------------------------------
extern "C" void kernel_launch(void* const* d_in, const int* in_sizes, int n_in,
                              void* d_out, int out_size, void* d_ws, size_t ws_size,
                              hipStream_t stream)
{
    const float* x         = (const float*)d_in[0];
    const int*   edges     = (const int*)d_in[1];
    const float* cond      = (const float*)d_in[2];
    const float* bn_w      = (const float*)d_in[3];
    const float* bn_b      = (const float*)d_in[4];
    const float* gcn_in_w  = (const float*)d_in[5];
    const float* gcn_in_b  = (const float*)d_in[6];
    const float* gcn_out_w = (const float*)d_in[7];
    const float* gcn_out_b = (const float*)d_in[8];
    const float* Wq  = (const float*)d_in[9];
    const float* Wk  = (const float*)d_in[10];
    const float* Wv  = (const float*)d_in[11];
    const float* Wo  = (const float*)d_in[12];
    const float* ln2w = (const float*)d_in[13];
    const float* ln2b = (const float*)d_in[14];
    const float* ln3w = (const float*)d_in[15];
    const float* ln3b = (const float*)d_in[16];
    const float* ggw = (const float*)d_in[17];
    const float* ggb = (const float*)d_in[18];
    const float* fow = (const float*)d_in[19];
    const float* fob = (const float*)d_in[20];
    float* outp = (float*)d_out;

    // --- workspace layout (f32 elements) ---
    const size_t TAILF = 33808 + 512 + 512 + N_NODES + (N_NODES + 4) + NEDGE;
    size_t fixedf = (size_t)4 * N_NODES * DIM + (size_t)2 * BSZ * MCTX * DIM;
    int nch = 0;
    size_t bigf = 0;
    for (int c = 2; c <= 8; c *= 2) {
        size_t bf = ((size_t)N_NODES / c) * DG;
        if ((fixedf + bf + TAILF) * 4 <= ws_size) { nch = c; bigf = bf; break; }
    }
    if (nch == 0) {
        fprintf(stderr, "kernel_launch: ws_size %zu too small\n", ws_size);
        return;
    }

    float* ws = (float*)d_ws;
    size_t off = 0;
    float* h  = ws + off; off += (size_t)N_NODES * DIM;
    float* t0 = ws + off; off += (size_t)N_NODES * DIM;
    float* t1 = ws + off; off += (size_t)N_NODES * DIM;
    float* t2 = ws + off; off += (size_t)N_NODES * DIM;
    float* kb = ws + off; off += (size_t)BSZ * MCTX * DIM;
    float* vb = ws + off; off += (size_t)BSZ * MCTX * DIM;
    float* big = ws + off; off += bigf;
    // zero region
    float* zbase  = ws + off;
    float* colsum = ws + off; off += DIM;
    float* colsq  = ws + off; off += DIM;
    int* deg    = (int*)(ws + off); off += N_NODES;
    int* cursor = (int*)(ws + off); off += N_NODES;
    int* eflag  = (int*)(ws + off); off += 16;
    size_t zcount = (size_t)((ws + off) - zbase);
    // non-zeroed tail
    float* bscale = ws + off; off += DIM;
    float* bshift = ws + off; off += DIM;
    float* dinv   = ws + off; off += N_NODES;
    int* csr_off = (int*)(ws + off); off += N_NODES + 4;
    int* csr_src = (int*)(ws + off); off += NEDGE;

    hipMemsetAsync(zbase, 0, zcount * sizeof(float), stream);

    // edge dtype detection (int32 vs int64 layout)
    detect_i64<<<NEDGE / 256, 256, 0, stream>>>(edges, eflag);

    // BatchNorm
    bn_colstats<<<128, 512, 0, stream>>>(x, colsum, colsq);
    bn_finalize<<<1, 512, 0, stream>>>(colsum, colsq, bn_w, bn_b, bscale, bshift);
    bn_apply<<<(N_NODES * DIM / 4) / 256, 256, 0, stream>>>(x, bscale, bshift, t0);

    // graph prep
    deg_count<<<NEDGE / 256, 256, 0, stream>>>(edges, eflag, deg);
    dinv_k<<<N_NODES / 256, 256, 0, stream>>>(deg, dinv);
    scan_deg<<<1, 1024, 0, stream>>>(deg, csr_off);
    fill_k<<<NEDGE / 256, 256, 0, stream>>>(edges, eflag, csr_off, cursor, csr_src);

    // GCN in: h = gather(BN(x) @ W) + b
    gemm128<false><<<dim3(DIM / 128, N_NODES / 128), 256, 0, stream>>>(
        t0, DIM, gcn_in_w, DIM, nullptr, nullptr, 0, t1, DIM, DIM);
    gcn_gather<<<N_NODES / 4, 256, 0, stream>>>(t1, csr_src, csr_off, dinv,
                                                gcn_in_b, nullptr, h);

    const int ffrows = N_NODES / nch;
    for (int i = 0; i < NLAYER; ++i) {
        // --- attention ---
        layernorm_k<<<N_NODES / 4, 256, 0, stream>>>(h, ln2w + i * DIM, ln2b + i * DIM, t0);
        gemm128<false><<<dim3(4, 128), 256, 0, stream>>>(
            t0, DIM, Wq + (size_t)i * DIM * DIM, DIM, nullptr, nullptr, 0, t1, DIM, DIM);
        gemm128<false><<<dim3(4, 32), 256, 0, stream>>>(
            cond, DIM, Wk + (size_t)i * DIM * DIM, DIM, nullptr, nullptr, 0, kb, DIM, DIM);
        gemm128<false><<<dim3(4, 32), 256, 0, stream>>>(
            cond, DIM, Wv + (size_t)i * DIM * DIM, DIM, nullptr, nullptr, 0, vb, DIM, DIM);
        for (int c = 0; c < 4; ++c) {
            attn_qk<<<dim3(4, 16, 32), 256, 0, stream>>>(t1, kb, big, c);
            softmax_k<<<(4 * NHEAD * SEQ) / 4, 256, 0, stream>>>(big);
            attn_pv<<<dim3(16, 32), 256, 0, stream>>>(big, vb, t2, c);
        }
        gemm128<false><<<dim3(4, 128), 256, 0, stream>>>(
            t2, DIM, Wo + (size_t)i * DIM * DIM, DIM, nullptr, h, DIM, h, DIM, DIM);

        // --- GEGLU FFN ---
        layernorm_k<<<N_NODES / 4, 256, 0, stream>>>(h, ln3w + i * DIM, ln3b + i * DIM, t0);
        for (int c = 0; c < nch; ++c) {
            const float* a = t0 + (size_t)c * ffrows * DIM;
            float* hc = h + (size_t)c * ffrows * DIM;
            gemm128<false><<<dim3(DG / 128, ffrows / 128), 256, 0, stream>>>(
                a, DIM, ggw + (size_t)i * DIM * DG, DG, ggb + (size_t)i * DG,
                nullptr, 0, big, DG, DIM);
            gemm128<true><<<dim3(DIM / 128, ffrows / 128), 256, 0, stream>>>(
                big, DG, fow + (size_t)i * DFF * DIM, DIM, fob + (size_t)i * DIM,
                hc, DIM, hc, DIM, DFF);
        }
    }

    // GCN out + residual x
    gemm128<false><<<dim3(4, 128), 256, 0, stream>>>(
        h, DIM, gcn_out_w, DIM, nullptr, nullptr, 0, t1, DIM, DIM);
    gcn_gather<<<N_NODES / 4, 256, 0, stream>>>(t1, csr_src, csr_off, dinv,
                                                gcn_out_b, x, outp);
}

// Round 2
// 2044.999 us; speedup vs baseline: 5.7552x; 5.7552x over previous
//
#include <hip/hip_runtime.h>
#include <math.h>
#include <stdio.h>

#define N_NODES 16384
#define DIM     512
#define BSZ     16
#define SEQ     1024
#define MCTX    256
#define NHEAD   8
#define DHEAD   64
#define NLAYER  4
#define NEDGE   262144
#define DFF     2048
#define DG      4096
#define LNEPS   1e-5f

typedef unsigned short u16;
typedef __attribute__((ext_vector_type(8))) __bf16 bf16x8;
typedef __attribute__((ext_vector_type(4))) float f32x4;
typedef __attribute__((ext_vector_type(4))) unsigned short u16x4;
typedef __attribute__((ext_vector_type(8))) unsigned short u16x8;

__device__ __forceinline__ u16 f2b(float f) {
    unsigned u = __float_as_uint(f);
    unsigned r = (u + 0x7fff + ((u >> 16) & 1)) >> 16;
    return (u16)r;
}
__device__ __forceinline__ float b2f(u16 h) {
    return __uint_as_float((unsigned)h << 16);
}
__device__ __forceinline__ float gelu_exact(float x) {
    return 0.5f * x * (1.0f + erff(x * 0.70710678118654752f));
}
__device__ __forceinline__ void gload16(const void* g, void* l) {
    __builtin_amdgcn_global_load_lds(
        (const __attribute__((address_space(1))) unsigned int*)g,
        (__attribute__((address_space(3))) unsigned int*)l, 16, 0, 0);
}

// ---------------------------------------------------------------------------
// bf16 MFMA GEMM (m97 structure). A [M][K] bf16 row-major, Bt [N][K] bf16
// row-major (i.e. B transposed). BM=128, BK=64, 256 threads (4 waves 2x2).
// LDS rows are 64 elems (128B = 8 slots of 16B); slot s of row r is stored at
// phys slot s^(r&7)  -> 2-way-max bank aliasing on ds_read_b128 (free).
// global_load_lds stages with the inverse permutation on the SOURCE address.
// Batch: z -> (zhi,zlo) = (z/nlo, z%nlo); offsets per pointer via Hi/Lo strides.
// EPI: 0 = C f32 (+bias) ; 1 = C bf16 (+bias) ; 2 = C f32 = acc+bias+resid ;
//      3 = V-transpose scatter (bf16, per-head [b][h][64][256])
// ---------------------------------------------------------------------------
template<int BN, int EPI>
__global__ __launch_bounds__(256) void bgemm(
    const u16* __restrict__ A, long lda,
    const u16* __restrict__ Bt, long ldb,
    const float* __restrict__ bias,
    const float* __restrict__ resid, long ldr,
    void* __restrict__ Cv, long ldc, int K, int nlo,
    long aHi, long aLo, long bHi, long bLo, long cHi, long cLo)
{
    constexpr int FN = BN / 32;
    __shared__ u16 As[128 * 64];
    __shared__ u16 Bs[BN * 64];

    const int t = threadIdx.x;
    const int z = blockIdx.z;
    const int zhi = z / nlo, zlo = z % nlo;
    const u16* Ag = A + (size_t)zhi * aHi + (size_t)zlo * aLo;
    const u16* Bg = Bt + (size_t)zhi * bHi + (size_t)zlo * bLo;
    const long coff = (long)zhi * cHi + (long)zlo * cLo;

    const int row0 = blockIdx.y * 128;
    const int col0 = blockIdx.x * BN;
    const int wave = t >> 6, lane = t & 63;
    const int wm0 = (wave >> 1) * 64, wn0 = (wave & 1) * (BN / 2);
    const int fr = lane & 15, fq = lane >> 4;
    const int ldsWave = (t & 192) * 16;       // wave*1024 bytes
    const int rS = t >> 3;                    // staging row within 32-row slab
    const int slotP = t & 7;                  // staging dest slot

    f32x4 acc[4][FN];
#pragma unroll
    for (int mi = 0; mi < 4; ++mi)
#pragma unroll
        for (int ni = 0; ni < FN; ++ni) acc[mi][ni] = (f32x4){0.f, 0.f, 0.f, 0.f};

    for (int k0 = 0; k0 < K; k0 += 64) {
#pragma unroll
        for (int i = 0; i < 4; ++i) {
            int r = i * 32 + rS;
            int sl = slotP ^ (r & 7);
            gload16(Ag + (size_t)(row0 + r) * lda + k0 + sl * 8,
                    (char*)As + i * 4096 + ldsWave);
        }
#pragma unroll
        for (int i = 0; i < BN / 32; ++i) {
            int r = i * 32 + rS;
            int sl = slotP ^ (r & 7);
            gload16(Bg + (size_t)(col0 + r) * ldb + k0 + sl * 8,
                    (char*)Bs + i * 4096 + ldsWave);
        }
        __syncthreads();
#pragma unroll
        for (int ks = 0; ks < 2; ++ks) {
            const int ksl = ks * 4 + fq;
            bf16x8 av[4], bv[FN];
#pragma unroll
            for (int mi = 0; mi < 4; ++mi) {
                int r = wm0 + mi * 16 + fr;
                av[mi] = *(const bf16x8*)&As[r * 64 + ((ksl ^ (r & 7)) * 8)];
            }
#pragma unroll
            for (int ni = 0; ni < FN; ++ni) {
                int r = wn0 + ni * 16 + fr;
                bv[ni] = *(const bf16x8*)&Bs[r * 64 + ((ksl ^ (r & 7)) * 8)];
            }
#pragma unroll
            for (int mi = 0; mi < 4; ++mi)
#pragma unroll
                for (int ni = 0; ni < FN; ++ni)
                    acc[mi][ni] = __builtin_amdgcn_mfma_f32_16x16x32_bf16(
                        av[mi], bv[ni], acc[mi][ni], 0, 0, 0);
        }
        __syncthreads();
    }

    float* Cf = (float*)Cv;
    u16* Cb = (u16*)Cv;
#pragma unroll
    for (int mi = 0; mi < 4; ++mi) {
        const int rb = row0 + wm0 + mi * 16 + fq * 4;
#pragma unroll
        for (int ni = 0; ni < FN; ++ni) {
            const int cc = col0 + wn0 + ni * 16 + fr;
            f32x4 v = acc[mi][ni];
            float bval = 0.f;
            if ((EPI == 0 || EPI == 1 || EPI == 2) && bias) bval = bias[cc];
#pragma unroll
            for (int j = 0; j < 4; ++j) {
                const long r = rb + j;
                float o = v[j] + bval;
                if (EPI == 0) {
                    Cf[coff + r * ldc + cc] = o;
                } else if (EPI == 1) {
                    Cb[coff + r * ldc + cc] = f2b(o);
                } else if (EPI == 2) {
                    Cf[coff + r * ldc + cc] = o + resid[r * ldr + cc];
                } else { // EPI == 3 : Vt[b][h][d][m]
                    long dst = (long)((r >> 8) * 8 + (cc >> 6)) * (64 * 256)
                             + (long)(cc & 63) * 256 + (r & 255);
                    Cb[dst] = f2b(o);
                }
            }
        }
    }
}

// ---------------------------------------------------------------------------
// Weight transpose+convert: src f32 [K][N] -> dst bf16 [N][K]
// ---------------------------------------------------------------------------
__global__ __launch_bounds__(256) void transposeW(const float* __restrict__ src,
                                                  u16* __restrict__ dst,
                                                  int K, int N)
{
    __shared__ float tile[64][65];
    const int t = threadIdx.x;
    const int n0 = blockIdx.x * 64, k0 = blockIdx.y * 64;
#pragma unroll
    for (int i = 0; i < 16; ++i) {
        int idx = i * 256 + t;
        int rr = idx >> 6, cc = idx & 63;
        tile[rr][cc] = src[(size_t)(k0 + rr) * N + n0 + cc];
    }
    __syncthreads();
#pragma unroll
    for (int i = 0; i < 16; ++i) {
        int idx = i * 256 + t;
        int rr = idx >> 6, cc = idx & 63;
        dst[(size_t)(n0 + rr) * K + k0 + cc] = f2b(tile[cc][rr]);
    }
}

__global__ __launch_bounds__(256) void conv_f2b(const float* __restrict__ in,
                                                u16* __restrict__ out)
{
    size_t i = (size_t)blockIdx.x * 256 + threadIdx.x;
    float4 v = ((const float4*)in)[i];
    u16x4 o;
    o[0] = f2b(v.x); o[1] = f2b(v.y); o[2] = f2b(v.z); o[3] = f2b(v.w);
    ((u16x4*)out)[i] = o;
}

// ---------------------------------------------------------------------------
// BatchNorm (axis 0)
// ---------------------------------------------------------------------------
__global__ __launch_bounds__(512) void bn_colstats(const float* __restrict__ x,
                                                   float* __restrict__ cs,
                                                   float* __restrict__ cq)
{
    int c = threadIdx.x;
    int r0 = blockIdx.x * 128;
    float s = 0.f, q = 0.f;
    for (int r = 0; r < 128; ++r) {
        float v = x[(size_t)(r0 + r) * DIM + c];
        s += v; q += v * v;
    }
    atomicAdd(&cs[c], s);
    atomicAdd(&cq[c], q);
}

__global__ void bn_finalize(const float* __restrict__ cs, const float* __restrict__ cq,
                            const float* __restrict__ bw, const float* __restrict__ bb,
                            float* __restrict__ scale, float* __restrict__ shift)
{
    int c = threadIdx.x;
    float m   = cs[c] * (1.f / N_NODES);
    float var = cq[c] * (1.f / N_NODES) - m * m;
    float rs  = rsqrtf(var + LNEPS);
    float sc  = rs * bw[c];
    scale[c] = sc;
    shift[c] = bb[c] - m * sc;
}

__global__ __launch_bounds__(256) void bn_apply_b(const float* __restrict__ x,
                                                  const float* __restrict__ scale,
                                                  const float* __restrict__ shift,
                                                  u16* __restrict__ out)
{
    size_t idx = (size_t)blockIdx.x * 256 + threadIdx.x;  // float4 index
    int c4 = (int)(idx & 127);
    float4 v  = ((const float4*)x)[idx];
    float4 sc = ((const float4*)scale)[c4];
    float4 sh = ((const float4*)shift)[c4];
    u16x4 o;
    o[0] = f2b(v.x * sc.x + sh.x); o[1] = f2b(v.y * sc.y + sh.y);
    o[2] = f2b(v.z * sc.z + sh.z); o[3] = f2b(v.w * sc.w + sh.w);
    ((u16x4*)out)[idx] = o;
}

// ---------------------------------------------------------------------------
// LayerNorm rows of 512, f32 in -> bf16 out; one wave per row
// ---------------------------------------------------------------------------
__global__ __launch_bounds__(256) void layernorm_b(const float* __restrict__ in,
                                                   const float* __restrict__ w,
                                                   const float* __restrict__ bsh,
                                                   u16* __restrict__ out)
{
    int lane = threadIdx.x & 63, wv = threadIdx.x >> 6;
    size_t row = (size_t)blockIdx.x * 4 + wv;
    const float* p = in + row * DIM + lane * 8;
    float4 v0 = *(const float4*)p;
    float4 v1 = *(const float4*)(p + 4);
    float s = v0.x + v0.y + v0.z + v0.w + v1.x + v1.y + v1.z + v1.w;
    float q = v0.x * v0.x + v0.y * v0.y + v0.z * v0.z + v0.w * v0.w +
              v1.x * v1.x + v1.y * v1.y + v1.z * v1.z + v1.w * v1.w;
    for (int m = 1; m < 64; m <<= 1) {
        s += __shfl_xor(s, m, 64);
        q += __shfl_xor(q, m, 64);
    }
    float mean = s * (1.f / DIM);
    float rs = rsqrtf(q * (1.f / DIM) - mean * mean + LNEPS);
    float4 w0 = *(const float4*)(w + lane * 8),   w1 = *(const float4*)(w + lane * 8 + 4);
    float4 b0 = *(const float4*)(bsh + lane * 8), b1 = *(const float4*)(bsh + lane * 8 + 4);
    u16x8 o;
    o[0] = f2b((v0.x - mean) * rs * w0.x + b0.x);
    o[1] = f2b((v0.y - mean) * rs * w0.y + b0.y);
    o[2] = f2b((v0.z - mean) * rs * w0.z + b0.z);
    o[3] = f2b((v0.w - mean) * rs * w0.w + b0.w);
    o[4] = f2b((v1.x - mean) * rs * w1.x + b1.x);
    o[5] = f2b((v1.y - mean) * rs * w1.y + b1.y);
    o[6] = f2b((v1.z - mean) * rs * w1.z + b1.z);
    o[7] = f2b((v1.w - mean) * rs * w1.w + b1.w);
    *(u16x8*)(out + row * DIM + lane * 8) = o;
}

// ---------------------------------------------------------------------------
// Softmax row of 256: S f32 -> P bf16 (scale 1/8 folded in)
// ---------------------------------------------------------------------------
__global__ __launch_bounds__(256) void softmax_p(const float* __restrict__ S,
                                                 u16* __restrict__ P)
{
    int lane = threadIdx.x & 63, wv = threadIdx.x >> 6;
    size_t row = (size_t)blockIdx.x * 4 + wv;
    const float* p = S + row * MCTX + lane * 4;
    float4 v = *(const float4*)p;
    v.x *= 0.125f; v.y *= 0.125f; v.z *= 0.125f; v.w *= 0.125f;
    float mx = fmaxf(fmaxf(v.x, v.y), fmaxf(v.z, v.w));
    for (int m = 1; m < 64; m <<= 1) mx = fmaxf(mx, __shfl_xor(mx, m, 64));
    v.x = __expf(v.x - mx); v.y = __expf(v.y - mx);
    v.z = __expf(v.z - mx); v.w = __expf(v.w - mx);
    float s = v.x + v.y + v.z + v.w;
    for (int m = 1; m < 64; m <<= 1) s += __shfl_xor(s, m, 64);
    float inv = 1.f / s;
    u16x4 o;
    o[0] = f2b(v.x * inv); o[1] = f2b(v.y * inv);
    o[2] = f2b(v.z * inv); o[3] = f2b(v.w * inv);
    *(u16x4*)(P + row * MCTX + lane * 4) = o;
}

// ---------------------------------------------------------------------------
// GEGLU activation: U bf16 [rows][4096] -> Ab bf16 [rows][2048]
// ---------------------------------------------------------------------------
__global__ __launch_bounds__(256) void geglu_act(const u16* __restrict__ U,
                                                 u16* __restrict__ Ab)
{
    size_t r = blockIdx.x;
    int j = threadIdx.x * 8;
    u16x8 val = *(const u16x8*)&U[r * DG + j];
    u16x8 gat = *(const u16x8*)&U[r * DG + DFF + j];
    u16x8 o;
#pragma unroll
    for (int e = 0; e < 8; ++e)
        o[e] = f2b(b2f(val[e]) * gelu_exact(b2f(gat[e])));
    *(u16x8*)&Ab[r * DFF + j] = o;
}

// ---------------------------------------------------------------------------
// Graph: edge-dtype detect, degree, dinv, CSR build, gather (bf16 features)
// ---------------------------------------------------------------------------
__global__ void detect_i64(const int* __restrict__ e, int* __restrict__ flag)
{
    int idx = blockIdx.x * blockDim.x + threadIdx.x;
    if (e[2 * idx + 1] != 0) flag[0] = 1;
}

__global__ void deg_count(const int* __restrict__ eb, const int* __restrict__ flag,
                          int* __restrict__ deg)
{
    int e = blockIdx.x * blockDim.x + threadIdx.x;
    int d;
    if (flag[0]) d = eb[NEDGE + e];
    else         d = (int)((const long long*)eb)[NEDGE + e];
    atomicAdd(&deg[d], 1);
}

__global__ void dinv_k(const int* __restrict__ deg, float* __restrict__ dinv)
{
    int i = blockIdx.x * blockDim.x + threadIdx.x;
    dinv[i] = rsqrtf((float)(deg[i] + 1));
}

__global__ __launch_bounds__(1024) void scan_deg(const int* __restrict__ deg,
                                                 int* __restrict__ off)
{
    __shared__ int sums[1024];
    int t = threadIdx.x;
    int base = t * 16;
    int v[16]; int s = 0;
#pragma unroll
    for (int i = 0; i < 16; ++i) { v[i] = deg[base + i]; s += v[i]; }
    sums[t] = s;
    __syncthreads();
    for (int ofs = 1; ofs < 1024; ofs <<= 1) {
        int x = (t >= ofs) ? sums[t - ofs] : 0;
        __syncthreads();
        sums[t] += x;
        __syncthreads();
    }
    int run = (t == 0) ? 0 : sums[t - 1];
#pragma unroll
    for (int i = 0; i < 16; ++i) { off[base + i] = run; run += v[i]; }
    if (t == 1023) off[N_NODES] = run;
}

__global__ void fill_k(const int* __restrict__ eb, const int* __restrict__ flag,
                       const int* __restrict__ off, int* __restrict__ cursor,
                       int* __restrict__ csr)
{
    int e = blockIdx.x * blockDim.x + threadIdx.x;
    int s, d;
    if (flag[0]) { s = eb[e]; d = eb[NEDGE + e]; }
    else {
        const long long* p = (const long long*)eb;
        s = (int)p[e]; d = (int)p[NEDGE + e];
    }
    int pos = atomicAdd(&cursor[d], 1);
    csr[off[d] + pos] = s;
}

__global__ __launch_bounds__(256) void gcn_gather(
    const u16* __restrict__ h2, const int* __restrict__ csr,
    const int* __restrict__ off, const float* __restrict__ dinv,
    const float* __restrict__ bias, const float* __restrict__ addx,
    float* __restrict__ out)
{
    int lane = threadIdx.x & 63, wv = threadIdx.x >> 6;
    int d = blockIdx.x * 4 + wv;
    float acc[8];
#pragma unroll
    for (int j = 0; j < 8; ++j) acc[j] = 0.f;
    int e0 = off[d], e1 = off[d + 1];
    float dd = dinv[d];
    for (int e = e0; e < e1; ++e) {
        int sidx = csr[e];
        float wgt = dinv[sidx] * dd;
        const u16* hp = h2 + (size_t)sidx * DIM;
#pragma unroll
        for (int j = 0; j < 8; ++j) acc[j] = fmaf(b2f(hp[j * 64 + lane]), wgt, acc[j]);
    }
    const u16* hd = h2 + (size_t)d * DIM;
    float sw = dd * dd;
#pragma unroll
    for (int j = 0; j < 8; ++j) acc[j] = fmaf(b2f(hd[j * 64 + lane]), sw, acc[j]);
    float* op = out + (size_t)d * DIM;
#pragma unroll
    for (int j = 0; j < 8; ++j) {
        float o = acc[j] + bias[j * 64 + lane];
        if (addx) o += addx[(size_t)d * DIM + j * 64 + lane];
        op[j * 64 + lane] = o;
    }
}

// ---------------------------------------------------------------------------
extern "C" void kernel_launch(void* const* d_in, const int* in_sizes, int n_in,
                              void* d_out, int out_size, void* d_ws, size_t ws_size,
                              hipStream_t stream)
{
    const float* x         = (const float*)d_in[0];
    const int*   edges     = (const int*)d_in[1];
    const float* cond      = (const float*)d_in[2];
    const float* bn_w      = (const float*)d_in[3];
    const float* bn_b      = (const float*)d_in[4];
    const float* gcn_in_w  = (const float*)d_in[5];
    const float* gcn_in_b  = (const float*)d_in[6];
    const float* gcn_out_w = (const float*)d_in[7];
    const float* gcn_out_b = (const float*)d_in[8];
    const float* Wq  = (const float*)d_in[9];
    const float* Wk  = (const float*)d_in[10];
    const float* Wv  = (const float*)d_in[11];
    const float* Wo  = (const float*)d_in[12];
    const float* ln2w = (const float*)d_in[13];
    const float* ln2b = (const float*)d_in[14];
    const float* ln3w = (const float*)d_in[15];
    const float* ln3b = (const float*)d_in[16];
    const float* ggw = (const float*)d_in[17];
    const float* ggb = (const float*)d_in[18];
    const float* fow = (const float*)d_in[19];
    const float* fob = (const float*)d_in[20];
    float* outp = (float*)d_out;

    // ---- workspace layout ----
    char* wsb = (char*)d_ws;
    size_t wsoff = 0;
    auto alloc = [&](size_t bytes) -> void* {
        void* p = wsb + wsoff;
        wsoff = (wsoff + bytes + 255) & ~(size_t)255;
        return p;
    };
    u16*   wT    = (u16*)  alloc((size_t)17301504 * 2);
    u16*   condb = (u16*)  alloc((size_t)4096 * 512 * 2);
    float* h     = (float*)alloc((size_t)N_NODES * DIM * 4);
    u16*   t0b   = (u16*)  alloc((size_t)N_NODES * DIM * 2);
    u16*   qb    = (u16*)  alloc((size_t)N_NODES * DIM * 2);   // also GCN gemm out
    u16*   ob    = (u16*)  alloc((size_t)N_NODES * DIM * 2);
    u16*   kb    = (u16*)  alloc((size_t)4096 * 512 * 2);
    u16*   Vt    = (u16*)  alloc((size_t)BSZ * NHEAD * DHEAD * MCTX * 2);
    // zero region
    char*  zbase  = wsb + wsoff;
    float* colsum = (float*)alloc(DIM * 4);
    float* colsq  = (float*)alloc(DIM * 4);
    int*   deg    = (int*)  alloc(N_NODES * 4);
    int*   cursor = (int*)  alloc(N_NODES * 4);
    int*   eflag  = (int*)  alloc(256);
    size_t zbytes = (size_t)((wsb + wsoff) - zbase);
    // non-zeroed tail
    float* bscale = (float*)alloc(DIM * 4);
    float* bshift = (float*)alloc(DIM * 4);
    float* dinv   = (float*)alloc(N_NODES * 4);
    int*   csr_off= (int*)  alloc((N_NODES + 16) * 4);
    int*   csr_src= (int*)  alloc((size_t)NEDGE * 4);

    // flexible "big" region: attention S/P chunk  OR  ffn U/Ab chunk
    struct Cfg { int battn, nch; };
    const Cfg cfgs[4] = {{4, 2}, {4, 4}, {2, 8}, {1, 16}};
    int battn = 0, nch = 0;
    size_t bigb = 0;
    for (int c = 0; c < 4; ++c) {
        size_t attnb = (size_t)cfgs[c].battn * NHEAD * SEQ * MCTX * 6;   // S f32 + P bf16
        size_t ffnb  = ((size_t)N_NODES / cfgs[c].nch) * (DG * 2 + DFF * 2);
        size_t need  = attnb > ffnb ? attnb : ffnb;
        if (wsoff + need <= ws_size) { battn = cfgs[c].battn; nch = cfgs[c].nch; bigb = need; break; }
    }
    if (battn == 0) { fprintf(stderr, "ws too small (%zu)\n", ws_size); return; }
    float* Sbuf = (float*)(wsb + wsoff);
    u16*   Pbuf = (u16*)(wsb + wsoff + (size_t)battn * NHEAD * SEQ * MCTX * 4);
    u16*   Ubuf = (u16*)(wsb + wsoff);
    u16*   Abuf = (u16*)(wsb + wsoff + ((size_t)N_NODES / nch) * DG * 2);

    hipMemsetAsync(zbase, 0, zbytes, stream);

    // ---- weight transpose/convert to bf16 [N][K] ----
    u16* gcnInT  = wT;
    u16* gcnOutT = gcnInT + 262144;
    u16* WqT = gcnOutT + 262144;
    u16* WkT = WqT + 4 * 262144;
    u16* WvT = WkT + 4 * 262144;
    u16* WoT = WvT + 4 * 262144;
    u16* ggT = WoT + 4 * 262144;
    u16* foT = ggT + 4 * 2097152;
    transposeW<<<dim3(8, 8), 256, 0, stream>>>(gcn_in_w,  gcnInT, 512, 512);
    transposeW<<<dim3(8, 8), 256, 0, stream>>>(gcn_out_w, gcnOutT, 512, 512);
    for (int i = 0; i < NLAYER; ++i) {
        transposeW<<<dim3(8, 8), 256, 0, stream>>>(Wq + (size_t)i * 262144, WqT + (size_t)i * 262144, 512, 512);
        transposeW<<<dim3(8, 8), 256, 0, stream>>>(Wk + (size_t)i * 262144, WkT + (size_t)i * 262144, 512, 512);
        transposeW<<<dim3(8, 8), 256, 0, stream>>>(Wv + (size_t)i * 262144, WvT + (size_t)i * 262144, 512, 512);
        transposeW<<<dim3(8, 8), 256, 0, stream>>>(Wo + (size_t)i * 262144, WoT + (size_t)i * 262144, 512, 512);
        transposeW<<<dim3(64, 8), 256, 0, stream>>>(ggw + (size_t)i * 512 * DG, ggT + (size_t)i * 2097152, 512, DG);
        transposeW<<<dim3(8, 32), 256, 0, stream>>>(fow + (size_t)i * DFF * 512, foT + (size_t)i * 1048576, DFF, 512);
    }
    conv_f2b<<<2048, 256, 0, stream>>>(cond, condb);

    // ---- BatchNorm ----
    bn_colstats<<<128, 512, 0, stream>>>(x, colsum, colsq);
    bn_finalize<<<1, 512, 0, stream>>>(colsum, colsq, bn_w, bn_b, bscale, bshift);
    bn_apply_b<<<(N_NODES * DIM / 4) / 256, 256, 0, stream>>>(x, bscale, bshift, t0b);

    // ---- graph prep ----
    detect_i64<<<NEDGE / 256, 256, 0, stream>>>(edges, eflag);
    deg_count<<<NEDGE / 256, 256, 0, stream>>>(edges, eflag, deg);
    dinv_k<<<N_NODES / 256, 256, 0, stream>>>(deg, dinv);
    scan_deg<<<1, 1024, 0, stream>>>(deg, csr_off);
    fill_k<<<NEDGE / 256, 256, 0, stream>>>(edges, eflag, csr_off, cursor, csr_src);

    // ---- GCN in ----
    bgemm<128, 1><<<dim3(4, 128, 1), 256, 0, stream>>>(
        t0b, 512, gcnInT, 512, nullptr, nullptr, 0, qb, 512, 512, 1, 0, 0, 0, 0, 0, 0);
    gcn_gather<<<N_NODES / 4, 256, 0, stream>>>(qb, csr_src, csr_off, dinv,
                                                gcn_in_b, nullptr, h);

    const int ffrows = N_NODES / nch;
    const int nachunk = BSZ / battn;
    for (int i = 0; i < NLAYER; ++i) {
        const u16* WqTi = WqT + (size_t)i * 262144;
        const u16* WkTi = WkT + (size_t)i * 262144;
        const u16* WvTi = WvT + (size_t)i * 262144;
        const u16* WoTi = WoT + (size_t)i * 262144;
        const u16* ggTi = ggT + (size_t)i * 2097152;
        const u16* foTi = foT + (size_t)i * 1048576;

        // --- attention ---
        layernorm_b<<<N_NODES / 4, 256, 0, stream>>>(h, ln2w + i * DIM, ln2b + i * DIM, t0b);
        bgemm<128, 1><<<dim3(4, 128, 1), 256, 0, stream>>>(
            t0b, 512, WqTi, 512, nullptr, nullptr, 0, qb, 512, 512, 1, 0, 0, 0, 0, 0, 0);
        bgemm<128, 1><<<dim3(4, 32, 1), 256, 0, stream>>>(
            condb, 512, WkTi, 512, nullptr, nullptr, 0, kb, 512, 512, 1, 0, 0, 0, 0, 0, 0);
        bgemm<128, 3><<<dim3(4, 32, 1), 256, 0, stream>>>(
            condb, 512, WvTi, 512, nullptr, nullptr, 0, Vt, 0, 512, 1, 0, 0, 0, 0, 0, 0);
        for (int c = 0; c < nachunk; ++c) {
            const u16* qc = qb + (size_t)c * battn * SEQ * 512;
            const u16* kc = kb + (size_t)c * battn * MCTX * 512;
            const u16* vc = Vt + (size_t)c * battn * NHEAD * DHEAD * MCTX;
            u16* oc = ob + (size_t)c * battn * SEQ * 512;
            bgemm<128, 0><<<dim3(2, 8, battn * 8), 256, 0, stream>>>(
                qc, 512, kc, 512, nullptr, nullptr, 0, Sbuf, 256, 64, 8,
                (long)SEQ * 512, 64, (long)MCTX * 512, 64,
                (long)NHEAD * SEQ * MCTX, (long)SEQ * MCTX);
            softmax_p<<<battn * 8 * SEQ / 4, 256, 0, stream>>>(Sbuf, Pbuf);
            bgemm<64, 1><<<dim3(1, 8, battn * 8), 256, 0, stream>>>(
                Pbuf, 256, vc, 256, nullptr, nullptr, 0, oc, 512, 256, 8,
                (long)NHEAD * SEQ * MCTX, (long)SEQ * MCTX,
                (long)NHEAD * DHEAD * MCTX, (long)DHEAD * MCTX,
                (long)SEQ * 512, 64);
        }
        bgemm<128, 2><<<dim3(4, 128, 1), 256, 0, stream>>>(
            ob, 512, WoTi, 512, nullptr, h, 512, h, 512, 512, 1, 0, 0, 0, 0, 0, 0);

        // --- GEGLU FFN ---
        layernorm_b<<<N_NODES / 4, 256, 0, stream>>>(h, ln3w + i * DIM, ln3b + i * DIM, t0b);
        for (int c = 0; c < nch; ++c) {
            const u16* ac = t0b + (size_t)c * ffrows * 512;
            float* hc = h + (size_t)c * ffrows * 512;
            bgemm<128, 1><<<dim3(DG / 128, ffrows / 128, 1), 256, 0, stream>>>(
                ac, 512, ggTi, 512, ggb + (size_t)i * DG, nullptr, 0,
                Ubuf, DG, 512, 1, 0, 0, 0, 0, 0, 0);
            geglu_act<<<ffrows, 256, 0, stream>>>(Ubuf, Abuf);
            bgemm<128, 2><<<dim3(4, ffrows / 128, 1), 256, 0, stream>>>(
                Abuf, 2048, foTi, 2048, fob + (size_t)i * DIM, hc, 512,
                hc, 512, 2048, 1, 0, 0, 0, 0, 0, 0);
        }
    }

    // ---- GCN out + residual x ----
    conv_f2b<<<8192, 256, 0, stream>>>(h, t0b);
    bgemm<128, 1><<<dim3(4, 128, 1), 256, 0, stream>>>(
        t0b, 512, gcnOutT, 512, nullptr, nullptr, 0, qb, 512, 512, 1, 0, 0, 0, 0, 0, 0);
    gcn_gather<<<N_NODES / 4, 256, 0, stream>>>(qb, csr_src, csr_off, dinv,
                                                gcn_out_b, x, outp);
}

// Round 3
// 1612.042 us; speedup vs baseline: 7.3009x; 1.2686x over previous
//
#include <hip/hip_runtime.h>
#include <math.h>
#include <stdio.h>

#define N_NODES 16384
#define DIM     512
#define BSZ     16
#define SEQ     1024
#define MCTX    256
#define NHEAD   8
#define DHEAD   64
#define NLAYER  4
#define NEDGE   262144
#define DFF     2048
#define DG      4096
#define LNEPS   1e-5f

typedef unsigned short u16;
typedef __attribute__((ext_vector_type(8))) __bf16 bf16x8;
typedef __attribute__((ext_vector_type(4))) float f32x4;
typedef __attribute__((ext_vector_type(4))) unsigned short u16x4;
typedef __attribute__((ext_vector_type(8))) unsigned short u16x8;

__device__ __forceinline__ u16 f2b(float f) {
    unsigned u = __float_as_uint(f);
    unsigned r = (u + 0x7fff + ((u >> 16) & 1)) >> 16;
    return (u16)r;
}
__device__ __forceinline__ float b2f(u16 h) {
    return __uint_as_float((unsigned)h << 16);
}
__device__ __forceinline__ float gelu_exact(float x) {
    return 0.5f * x * (1.0f + erff(x * 0.70710678118654752f));
}
__device__ __forceinline__ void gload16(const void* g, void* l) {
    __builtin_amdgcn_global_load_lds(
        (const __attribute__((address_space(1))) unsigned int*)g,
        (__attribute__((address_space(3))) unsigned int*)l, 16, 0, 0);
}

// bijective XCD-chunk swizzle (m204): consecutive work-ids land on one XCD.
__device__ __forceinline__ int2 xcd_map() {
    int gx = gridDim.x, gy = gridDim.y;
    int nwg = gx * gy;
    int id = blockIdx.y * gx + blockIdx.x;
    int q = nwg >> 3, r = nwg & 7;
    int xcd = id & 7, idx = id >> 3;
    int nid = (xcd < r ? xcd * (q + 1) : r * (q + 1) + (xcd - r) * q) + idx;
    int2 o; o.x = nid % gx; o.y = nid / gx; return o;
}

// ---------------------------------------------------------------------------
// bf16 MFMA GEMM, 128x128 tile, BK=64, double-buffered LDS (2-phase pipeline):
//   STAGE(next tile) -> compute(cur) -> __syncthreads()
// A [M][K] bf16 row-major, Bt [N][K] bf16 row-major. LDS rows = 64 elems =
// 8 slots of 16B; logical slot s of row r stored at phys s^(r&7) (2-way max
// bank aliasing = free). global_load_lds stages with inverse perm on SOURCE.
// EPI: 1 = bf16 out (+bias) ; 2 = f32 out = acc+bias+resid ;
//      3 = V-transpose scatter (bf16 -> Vt[b][h][d][m]) ; 4 = bf16 rowscale
// ---------------------------------------------------------------------------
template<int EPI>
__global__ __launch_bounds__(256) void bgemm(
    const u16* __restrict__ A, long lda,
    const u16* __restrict__ Bt, long ldb,
    const float* __restrict__ bias,
    const float* __restrict__ resid, long ldr,
    const float* __restrict__ rowscale,
    void* __restrict__ Cv, long ldc, int K, int nlo,
    long aHi, long aLo, long bHi, long bLo, long cHi, long cLo)
{
    __shared__ u16 lds[32768];    // A0 | A1 | B0 | B1, 16KB each

    const int t = threadIdx.x;
    const int z = blockIdx.z;
    const int zhi = z / nlo, zlo = z % nlo;
    const u16* Ag = A + (size_t)zhi * aHi + (size_t)zlo * aLo;
    const u16* Bg = Bt + (size_t)zhi * bHi + (size_t)zlo * bLo;
    const long coff = (long)zhi * cHi + (long)zlo * cLo;

    int2 sw = xcd_map();
    const int row0 = sw.y * 128;
    const int col0 = sw.x * 128;
    const int wave = t >> 6, lane = t & 63;
    const int wm0 = (wave >> 1) * 64, wn0 = (wave & 1) * 64;
    const int fr = lane & 15, fq = lane >> 4;
    const int ldsWave = (t & 192) * 16;    // wave * 1024 bytes
    const int rS = t >> 3;
    const int slotP = t & 7;

    f32x4 acc[4][4];
#pragma unroll
    for (int mi = 0; mi < 4; ++mi)
#pragma unroll
        for (int ni = 0; ni < 4; ++ni) acc[mi][ni] = (f32x4){0.f, 0.f, 0.f, 0.f};

    auto stage = [&](int buf, int k0) {
        u16* Ad = lds + buf * 8192;
        u16* Bd = lds + 16384 + buf * 8192;
#pragma unroll
        for (int i = 0; i < 4; ++i) {
            int r = i * 32 + rS;
            int sl = slotP ^ (r & 7);
            gload16(Ag + (size_t)(row0 + r) * lda + k0 + sl * 8,
                    (char*)Ad + i * 4096 + ldsWave);
        }
#pragma unroll
        for (int i = 0; i < 4; ++i) {
            int r = i * 32 + rS;
            int sl = slotP ^ (r & 7);
            gload16(Bg + (size_t)(col0 + r) * ldb + k0 + sl * 8,
                    (char*)Bd + i * 4096 + ldsWave);
        }
    };
    auto compute = [&](int buf) {
        const u16* Ac = lds + buf * 8192;
        const u16* Bc = lds + 16384 + buf * 8192;
#pragma unroll
        for (int ks = 0; ks < 2; ++ks) {
            const int ksl = ks * 4 + fq;
            bf16x8 av[4], bv[4];
#pragma unroll
            for (int mi = 0; mi < 4; ++mi) {
                int r = wm0 + mi * 16 + fr;
                av[mi] = *(const bf16x8*)&Ac[r * 64 + ((ksl ^ (r & 7)) * 8)];
            }
#pragma unroll
            for (int ni = 0; ni < 4; ++ni) {
                int r = wn0 + ni * 16 + fr;
                bv[ni] = *(const bf16x8*)&Bc[r * 64 + ((ksl ^ (r & 7)) * 8)];
            }
#pragma unroll
            for (int mi = 0; mi < 4; ++mi)
#pragma unroll
                for (int ni = 0; ni < 4; ++ni)
                    acc[mi][ni] = __builtin_amdgcn_mfma_f32_16x16x32_bf16(
                        av[mi], bv[ni], acc[mi][ni], 0, 0, 0);
        }
    };

    int cur = 0;
    stage(0, 0);
    __syncthreads();
    for (int k0 = 64; k0 < K; k0 += 64) {
        stage(cur ^ 1, k0);
        compute(cur);
        __syncthreads();
        cur ^= 1;
    }
    compute(cur);

    float* Cf = (float*)Cv;
    u16* Cb = (u16*)Cv;
#pragma unroll
    for (int mi = 0; mi < 4; ++mi) {
        const int rb = row0 + wm0 + mi * 16 + fq * 4;
#pragma unroll
        for (int ni = 0; ni < 4; ++ni) {
            const int cc = col0 + wn0 + ni * 16 + fr;
            f32x4 v = acc[mi][ni];
            float bval = 0.f;
            if ((EPI == 1 || EPI == 2) && bias) bval = bias[cc];
#pragma unroll
            for (int j = 0; j < 4; ++j) {
                const long r = rb + j;
                float o = v[j] + bval;
                if (EPI == 1) {
                    Cb[coff + r * ldc + cc] = f2b(o);
                } else if (EPI == 2) {
                    Cf[coff + r * ldc + cc] = o + resid[r * ldr + cc];
                } else if (EPI == 3) {   // Vt[b][h][d][m]
                    long dst = (long)((r >> 8) * 8 + (cc >> 6)) * (64 * 256)
                             + (long)(cc & 63) * 256 + (r & 255);
                    Cb[dst] = f2b(o);
                } else {                 // EPI == 4
                    Cb[coff + r * ldc + cc] = f2b(o * rowscale[r]);
                }
            }
        }
    }
}

// ---------------------------------------------------------------------------
// Fused attention: one block = (qchunk of 256 rows, head, batch).
// K [256][64] and V^T [64][256] staged in LDS (slot-swizzled, gload16).
// Per wave / 16-row q-tile: S (32 MFMA) -> in-reg softmax -> P to per-wave
// swizzled LDS tile -> PV (32 MFMA).
// ---------------------------------------------------------------------------
__global__ __launch_bounds__(256) void fused_attn(
    const u16* __restrict__ Q,    // [16384][512]
    const u16* __restrict__ Kp,   // [4096][512]
    const u16* __restrict__ Vt,   // [16][8][64][256]
    u16* __restrict__ O)          // [16384][512]
{
    __shared__ u16 Ks[256 * 64];
    __shared__ u16 Vs[64 * 256];
    __shared__ u16 Ps[4][16 * 256];

    const int t = threadIdx.x;
    const int wave = t >> 6, lane = t & 63;
    const int fr = lane & 15, fq = lane >> 4;
    const int qc = blockIdx.x, h = blockIdx.y, b = blockIdx.z;
    const int ldsW = (t & 192) * 16;

#pragma unroll
    for (int i = 0; i < 8; ++i) {          // K: [m][64], 8 slots/row
        int idx = i * 256 + t;
        int m = idx >> 3, s = idx & 7;
        gload16(Kp + (size_t)(b * MCTX + m) * 512 + h * 64 + ((s ^ (m & 7)) * 8),
                (char*)Ks + i * 4096 + ldsW);
    }
#pragma unroll
    for (int i = 0; i < 8; ++i) {          // V^T: [d][256], 32 slots/row
        int idx = i * 256 + t;
        int d = idx >> 5, s = idx & 31;
        gload16(Vt + (size_t)((b * 8 + h) * 64 + d) * 256 + ((s ^ (d & 7)) * 8),
                (char*)Vs + i * 4096 + ldsW);
    }
    __syncthreads();

    u16* Pw = Ps[wave];
    for (int it = 0; it < 4; ++it) {
        const int q0 = qc * 256 + it * 64 + wave * 16;
        bf16x8 aq[2];
#pragma unroll
        for (int ks = 0; ks < 2; ++ks)
            aq[ks] = *(const bf16x8*)&Q[(size_t)(b * SEQ + q0 + fr) * 512 +
                                        h * 64 + ks * 32 + fq * 8];
        f32x4 accS[16];
#pragma unroll
        for (int ni = 0; ni < 16; ++ni) accS[ni] = (f32x4){0.f, 0.f, 0.f, 0.f};
#pragma unroll
        for (int ni = 0; ni < 16; ++ni) {
            int m = ni * 16 + fr;
#pragma unroll
            for (int ks = 0; ks < 2; ++ks) {
                bf16x8 bv = *(const bf16x8*)&Ks[m * 64 + (((ks * 4 + fq) ^ (m & 7)) * 8)];
                accS[ni] = __builtin_amdgcn_mfma_f32_16x16x32_bf16(
                    aq[ks], bv, accS[ni], 0, 0, 0);
            }
        }
        // softmax over 256 cols (16 frags in-lane x 16 lanes via shfl_xor)
        const float cs = 0.125f;
#pragma unroll
        for (int j = 0; j < 4; ++j) {
            float m0 = accS[0][j];
#pragma unroll
            for (int ni = 1; ni < 16; ++ni) m0 = fmaxf(m0, accS[ni][j]);
            m0 = fmaxf(m0, __shfl_xor(m0, 1, 64));
            m0 = fmaxf(m0, __shfl_xor(m0, 2, 64));
            m0 = fmaxf(m0, __shfl_xor(m0, 4, 64));
            m0 = fmaxf(m0, __shfl_xor(m0, 8, 64));
            float s0 = 0.f;
#pragma unroll
            for (int ni = 0; ni < 16; ++ni) {
                float p = __expf((accS[ni][j] - m0) * cs);
                accS[ni][j] = p;
                s0 += p;
            }
            s0 += __shfl_xor(s0, 1, 64);
            s0 += __shfl_xor(s0, 2, 64);
            s0 += __shfl_xor(s0, 4, 64);
            s0 += __shfl_xor(s0, 8, 64);
            float inv = 1.f / s0;
#pragma unroll
            for (int ni = 0; ni < 16; ++ni) {
                int cc = ni * 16 + fr;
                int rr = fq * 4 + j;
                Pw[rr * 256 + (((cc >> 3) ^ (rr & 7)) * 8) + (cc & 7)] =
                    f2b(accS[ni][j] * inv);
            }
        }
        // PV
        bf16x8 ap[8];
#pragma unroll
        for (int ks = 0; ks < 8; ++ks)
            ap[ks] = *(const bf16x8*)&Pw[fr * 256 + (((ks * 4 + fq) ^ (fr & 7)) * 8)];
        f32x4 accO[4];
#pragma unroll
        for (int ni = 0; ni < 4; ++ni) accO[ni] = (f32x4){0.f, 0.f, 0.f, 0.f};
#pragma unroll
        for (int ni = 0; ni < 4; ++ni) {
            int d = ni * 16 + fr;
#pragma unroll
            for (int ks = 0; ks < 8; ++ks) {
                bf16x8 bv = *(const bf16x8*)&Vs[d * 256 + (((ks * 4 + fq) ^ (d & 7)) * 8)];
                accO[ni] = __builtin_amdgcn_mfma_f32_16x16x32_bf16(
                    ap[ks], bv, accO[ni], 0, 0, 0);
            }
        }
#pragma unroll
        for (int ni = 0; ni < 4; ++ni)
#pragma unroll
            for (int j = 0; j < 4; ++j)
                O[(size_t)(b * SEQ + q0 + fq * 4 + j) * 512 + h * 64 + ni * 16 + fr] =
                    f2b(accO[ni][j]);
    }
}

// ---------------------------------------------------------------------------
// Batched weight transpose+convert: src f32 [K][N] -> dst bf16 [N][K]
// ---------------------------------------------------------------------------
__global__ __launch_bounds__(256) void transposeW(const float* __restrict__ src,
                                                  u16* __restrict__ dst,
                                                  int K, int N,
                                                  long srcZ, long dstZ)
{
    __shared__ float tile[64][65];
    const int t = threadIdx.x;
    const int n0 = blockIdx.x * 64, k0 = blockIdx.y * 64;
    const float* s = src + (size_t)blockIdx.z * srcZ;
    u16* d = dst + (size_t)blockIdx.z * dstZ;
#pragma unroll
    for (int i = 0; i < 16; ++i) {
        int idx = i * 256 + t;
        int rr = idx >> 6, cc = idx & 63;
        tile[rr][cc] = s[(size_t)(k0 + rr) * N + n0 + cc];
    }
    __syncthreads();
#pragma unroll
    for (int i = 0; i < 16; ++i) {
        int idx = i * 256 + t;
        int rr = idx >> 6, cc = idx & 63;
        d[(size_t)(n0 + rr) * K + k0 + cc] = f2b(tile[cc][rr]);
    }
}

__global__ __launch_bounds__(256) void conv_f2b(const float* __restrict__ in,
                                                u16* __restrict__ out)
{
    size_t i = (size_t)blockIdx.x * 256 + threadIdx.x;
    float4 v = ((const float4*)in)[i];
    u16x4 o;
    o[0] = f2b(v.x); o[1] = f2b(v.y); o[2] = f2b(v.z); o[3] = f2b(v.w);
    ((u16x4*)out)[i] = o;
}

// ---------------------------------------------------------------------------
__global__ __launch_bounds__(512) void bn_colstats(const float* __restrict__ x,
                                                   float* __restrict__ cs,
                                                   float* __restrict__ cq)
{
    int c = threadIdx.x;
    int r0 = blockIdx.x * 128;
    float s = 0.f, q = 0.f;
    for (int r = 0; r < 128; ++r) {
        float v = x[(size_t)(r0 + r) * DIM + c];
        s += v; q += v * v;
    }
    atomicAdd(&cs[c], s);
    atomicAdd(&cq[c], q);
}

__global__ void bn_finalize(const float* __restrict__ cs, const float* __restrict__ cq,
                            const float* __restrict__ bw, const float* __restrict__ bb,
                            float* __restrict__ scale, float* __restrict__ shift)
{
    int c = threadIdx.x;
    float m   = cs[c] * (1.f / N_NODES);
    float var = cq[c] * (1.f / N_NODES) - m * m;
    float rs  = rsqrtf(var + LNEPS);
    float sc  = rs * bw[c];
    scale[c] = sc;
    shift[c] = bb[c] - m * sc;
}

__global__ __launch_bounds__(256) void bn_apply_b(const float* __restrict__ x,
                                                  const float* __restrict__ scale,
                                                  const float* __restrict__ shift,
                                                  u16* __restrict__ out)
{
    size_t idx = (size_t)blockIdx.x * 256 + threadIdx.x;
    int c4 = (int)(idx & 127);
    float4 v  = ((const float4*)x)[idx];
    float4 sc = ((const float4*)scale)[c4];
    float4 sh = ((const float4*)shift)[c4];
    u16x4 o;
    o[0] = f2b(v.x * sc.x + sh.x); o[1] = f2b(v.y * sc.y + sh.y);
    o[2] = f2b(v.z * sc.z + sh.z); o[3] = f2b(v.w * sc.w + sh.w);
    ((u16x4*)out)[idx] = o;
}

__global__ __launch_bounds__(256) void layernorm_b(const float* __restrict__ in,
                                                   const float* __restrict__ w,
                                                   const float* __restrict__ bsh,
                                                   u16* __restrict__ out)
{
    int lane = threadIdx.x & 63, wv = threadIdx.x >> 6;
    size_t row = (size_t)blockIdx.x * 4 + wv;
    const float* p = in + row * DIM + lane * 8;
    float4 v0 = *(const float4*)p;
    float4 v1 = *(const float4*)(p + 4);
    float s = v0.x + v0.y + v0.z + v0.w + v1.x + v1.y + v1.z + v1.w;
    float q = v0.x * v0.x + v0.y * v0.y + v0.z * v0.z + v0.w * v0.w +
              v1.x * v1.x + v1.y * v1.y + v1.z * v1.z + v1.w * v1.w;
    for (int m = 1; m < 64; m <<= 1) {
        s += __shfl_xor(s, m, 64);
        q += __shfl_xor(q, m, 64);
    }
    float mean = s * (1.f / DIM);
    float rs = rsqrtf(q * (1.f / DIM) - mean * mean + LNEPS);
    float4 w0 = *(const float4*)(w + lane * 8),   w1 = *(const float4*)(w + lane * 8 + 4);
    float4 b0 = *(const float4*)(bsh + lane * 8), b1 = *(const float4*)(bsh + lane * 8 + 4);
    u16x8 o;
    o[0] = f2b((v0.x - mean) * rs * w0.x + b0.x);
    o[1] = f2b((v0.y - mean) * rs * w0.y + b0.y);
    o[2] = f2b((v0.z - mean) * rs * w0.z + b0.z);
    o[3] = f2b((v0.w - mean) * rs * w0.w + b0.w);
    o[4] = f2b((v1.x - mean) * rs * w1.x + b1.x);
    o[5] = f2b((v1.y - mean) * rs * w1.y + b1.y);
    o[6] = f2b((v1.z - mean) * rs * w1.z + b1.z);
    o[7] = f2b((v1.w - mean) * rs * w1.w + b1.w);
    *(u16x8*)(out + row * DIM + lane * 8) = o;
}

__global__ __launch_bounds__(256) void geglu_act(const u16* __restrict__ U,
                                                 u16* __restrict__ Ab)
{
    size_t r = blockIdx.x;
    int j = threadIdx.x * 8;
    u16x8 val = *(const u16x8*)&U[r * DG + j];
    u16x8 gat = *(const u16x8*)&U[r * DG + DFF + j];
    u16x8 o;
#pragma unroll
    for (int e = 0; e < 8; ++e)
        o[e] = f2b(b2f(val[e]) * gelu_exact(b2f(gat[e])));
    *(u16x8*)&Ab[r * DFF + j] = o;
}

// ---------------------------------------------------------------------------
__global__ void detect_i64(const int* __restrict__ e, int* __restrict__ flag)
{
    int idx = blockIdx.x * blockDim.x + threadIdx.x;
    if (e[2 * idx + 1] != 0) flag[0] = 1;
}

__global__ void deg_count(const int* __restrict__ eb, const int* __restrict__ flag,
                          int* __restrict__ deg)
{
    int e = blockIdx.x * blockDim.x + threadIdx.x;
    int d;
    if (flag[0]) d = eb[NEDGE + e];
    else         d = (int)((const long long*)eb)[NEDGE + e];
    atomicAdd(&deg[d], 1);
}

__global__ void dinv_k(const int* __restrict__ deg, float* __restrict__ dinv)
{
    int i = blockIdx.x * blockDim.x + threadIdx.x;
    dinv[i] = rsqrtf((float)(deg[i] + 1));
}

__global__ __launch_bounds__(1024) void scan_deg(const int* __restrict__ deg,
                                                 int* __restrict__ off)
{
    __shared__ int sums[1024];
    int t = threadIdx.x;
    int base = t * 16;
    int v[16]; int s = 0;
#pragma unroll
    for (int i = 0; i < 16; ++i) { v[i] = deg[base + i]; s += v[i]; }
    sums[t] = s;
    __syncthreads();
    for (int ofs = 1; ofs < 1024; ofs <<= 1) {
        int x = (t >= ofs) ? sums[t - ofs] : 0;
        __syncthreads();
        sums[t] += x;
        __syncthreads();
    }
    int run = (t == 0) ? 0 : sums[t - 1];
#pragma unroll
    for (int i = 0; i < 16; ++i) { off[base + i] = run; run += v[i]; }
    if (t == 1023) off[N_NODES] = run;
}

__global__ void fill_k(const int* __restrict__ eb, const int* __restrict__ flag,
                       const int* __restrict__ off, int* __restrict__ cursor,
                       int* __restrict__ csr)
{
    int e = blockIdx.x * blockDim.x + threadIdx.x;
    int s, d;
    if (flag[0]) { s = eb[e]; d = eb[NEDGE + e]; }
    else {
        const long long* p = (const long long*)eb;
        s = (int)p[e]; d = (int)p[NEDGE + e];
    }
    int pos = atomicAdd(&cursor[d], 1);
    csr[off[d] + pos] = s;
}

// h2 rows are PRE-SCALED by dinv[row] (bgemm EPI=4):
// out = dd * (sum_src h2[src] + h2[d]) + bias (+ addx)
__global__ __launch_bounds__(256) void gcn_gather(
    const u16* __restrict__ h2, const int* __restrict__ csr,
    const int* __restrict__ off, const float* __restrict__ dinv,
    const float* __restrict__ bias, const float* __restrict__ addx,
    float* __restrict__ out)
{
    int lane = threadIdx.x & 63, wv = threadIdx.x >> 6;
    int d = blockIdx.x * 4 + wv;
    float acc[8];
#pragma unroll
    for (int j = 0; j < 8; ++j) acc[j] = 0.f;
    int e0 = off[d], e1 = off[d + 1];
    float dd = dinv[d];
    int sidx = (e0 < e1) ? csr[e0] : 0;
    for (int e = e0; e < e1; ++e) {
        int snext = (e + 1 < e1) ? csr[e + 1] : 0;
        u16x8 v = *(const u16x8*)&h2[(size_t)sidx * DIM + lane * 8];
#pragma unroll
        for (int j = 0; j < 8; ++j) acc[j] += b2f(v[j]);
        sidx = snext;
    }
    u16x8 vd = *(const u16x8*)&h2[(size_t)d * DIM + lane * 8];
#pragma unroll
    for (int j = 0; j < 8; ++j) acc[j] = (acc[j] + b2f(vd[j])) * dd;
    float o[8];
#pragma unroll
    for (int j = 0; j < 8; ++j) {
        o[j] = acc[j] + bias[lane * 8 + j];
        if (addx) o[j] += addx[(size_t)d * DIM + lane * 8 + j];
    }
    float* op = out + (size_t)d * DIM + lane * 8;
    *(float4*)op = make_float4(o[0], o[1], o[2], o[3]);
    *(float4*)(op + 4) = make_float4(o[4], o[5], o[6], o[7]);
}

// ---------------------------------------------------------------------------
extern "C" void kernel_launch(void* const* d_in, const int* in_sizes, int n_in,
                              void* d_out, int out_size, void* d_ws, size_t ws_size,
                              hipStream_t stream)
{
    const float* x         = (const float*)d_in[0];
    const int*   edges     = (const int*)d_in[1];
    const float* cond      = (const float*)d_in[2];
    const float* bn_w      = (const float*)d_in[3];
    const float* bn_b      = (const float*)d_in[4];
    const float* gcn_in_w  = (const float*)d_in[5];
    const float* gcn_in_b  = (const float*)d_in[6];
    const float* gcn_out_w = (const float*)d_in[7];
    const float* gcn_out_b = (const float*)d_in[8];
    const float* Wq  = (const float*)d_in[9];
    const float* Wk  = (const float*)d_in[10];
    const float* Wv  = (const float*)d_in[11];
    const float* Wo  = (const float*)d_in[12];
    const float* ln2w = (const float*)d_in[13];
    const float* ln2b = (const float*)d_in[14];
    const float* ln3w = (const float*)d_in[15];
    const float* ln3b = (const float*)d_in[16];
    const float* ggw = (const float*)d_in[17];
    const float* ggb = (const float*)d_in[18];
    const float* fow = (const float*)d_in[19];
    const float* fob = (const float*)d_in[20];
    float* outp = (float*)d_out;

    char* wsb = (char*)d_ws;
    size_t wsoff = 0;
    auto alloc = [&](size_t bytes) -> void* {
        void* p = wsb + wsoff;
        wsoff = (wsoff + bytes + 255) & ~(size_t)255;
        return p;
    };
    u16*   wT    = (u16*)  alloc((size_t)17301504 * 2);
    u16*   condb = (u16*)  alloc((size_t)4096 * 512 * 2);
    float* h     = (float*)alloc((size_t)N_NODES * DIM * 4);
    u16*   t0b   = (u16*)  alloc((size_t)N_NODES * DIM * 2);
    u16*   qb    = (u16*)  alloc((size_t)N_NODES * DIM * 2);
    u16*   ob    = (u16*)  alloc((size_t)N_NODES * DIM * 2);
    u16*   kb    = (u16*)  alloc((size_t)4096 * 512 * 2);
    u16*   Vt    = (u16*)  alloc((size_t)BSZ * NHEAD * DHEAD * MCTX * 2);
    char*  zbase  = wsb + wsoff;
    float* colsum = (float*)alloc(DIM * 4);
    float* colsq  = (float*)alloc(DIM * 4);
    int*   deg    = (int*)  alloc(N_NODES * 4);
    int*   cursor = (int*)  alloc(N_NODES * 4);
    int*   eflag  = (int*)  alloc(256);
    size_t zbytes = (size_t)((wsb + wsoff) - zbase);
    float* bscale = (float*)alloc(DIM * 4);
    float* bshift = (float*)alloc(DIM * 4);
    float* dinv   = (float*)alloc(N_NODES * 4);
    int*   csr_off= (int*)  alloc((N_NODES + 16) * 4);
    int*   csr_src= (int*)  alloc((size_t)NEDGE * 4);

    // FFN chunking (U + Ab buffers)
    int nch = 0;
    for (int c = 1; c <= 16; c *= 2) {
        size_t need = ((size_t)N_NODES / c) * (DG + DFF) * 2;
        if (wsoff + need <= ws_size) { nch = c; break; }
    }
    if (nch == 0) { fprintf(stderr, "ws too small (%zu)\n", ws_size); return; }
    u16* Ubuf = (u16*)(wsb + wsoff);
    u16* Abuf = (u16*)(wsb + wsoff + ((size_t)N_NODES / nch) * DG * 2);

    hipMemsetAsync(zbase, 0, zbytes, stream);

    // weight transposes (batched over layers)
    u16* gcnInT  = wT;
    u16* gcnOutT = gcnInT + 262144;
    u16* WqT = gcnOutT + 262144;
    u16* WkT = WqT + 4 * 262144;
    u16* WvT = WkT + 4 * 262144;
    u16* WoT = WvT + 4 * 262144;
    u16* ggT = WoT + 4 * 262144;
    u16* foT = ggT + 4 * 2097152;
    transposeW<<<dim3(8, 8, 1), 256, 0, stream>>>(gcn_in_w,  gcnInT, 512, 512, 0, 0);
    transposeW<<<dim3(8, 8, 1), 256, 0, stream>>>(gcn_out_w, gcnOutT, 512, 512, 0, 0);
    transposeW<<<dim3(8, 8, 4), 256, 0, stream>>>(Wq, WqT, 512, 512, 262144, 262144);
    transposeW<<<dim3(8, 8, 4), 256, 0, stream>>>(Wk, WkT, 512, 512, 262144, 262144);
    transposeW<<<dim3(8, 8, 4), 256, 0, stream>>>(Wv, WvT, 512, 512, 262144, 262144);
    transposeW<<<dim3(8, 8, 4), 256, 0, stream>>>(Wo, WoT, 512, 512, 262144, 262144);
    transposeW<<<dim3(64, 8, 4), 256, 0, stream>>>(ggw, ggT, 512, DG, 2097152, 2097152);
    transposeW<<<dim3(8, 32, 4), 256, 0, stream>>>(fow, foT, DFF, 512, 1048576, 1048576);
    conv_f2b<<<2048, 256, 0, stream>>>(cond, condb);

    // BatchNorm
    bn_colstats<<<128, 512, 0, stream>>>(x, colsum, colsq);
    bn_finalize<<<1, 512, 0, stream>>>(colsum, colsq, bn_w, bn_b, bscale, bshift);
    bn_apply_b<<<(N_NODES * DIM / 4) / 256, 256, 0, stream>>>(x, bscale, bshift, t0b);

    // graph prep
    detect_i64<<<NEDGE / 256, 256, 0, stream>>>(edges, eflag);
    deg_count<<<NEDGE / 256, 256, 0, stream>>>(edges, eflag, deg);
    dinv_k<<<N_NODES / 256, 256, 0, stream>>>(deg, dinv);
    scan_deg<<<1, 1024, 0, stream>>>(deg, csr_off);
    fill_k<<<NEDGE / 256, 256, 0, stream>>>(edges, eflag, csr_off, cursor, csr_src);

    // GCN in (rows pre-scaled by dinv via EPI=4)
    bgemm<4><<<dim3(4, 128, 1), 256, 0, stream>>>(
        t0b, 512, gcnInT, 512, nullptr, nullptr, 0, dinv, qb, 512, 512, 1,
        0, 0, 0, 0, 0, 0);
    gcn_gather<<<N_NODES / 4, 256, 0, stream>>>(qb, csr_src, csr_off, dinv,
                                                gcn_in_b, nullptr, h);

    const int ffrows = N_NODES / nch;
    for (int i = 0; i < NLAYER; ++i) {
        const u16* WqTi = WqT + (size_t)i * 262144;
        const u16* WkTi = WkT + (size_t)i * 262144;
        const u16* WvTi = WvT + (size_t)i * 262144;
        const u16* WoTi = WoT + (size_t)i * 262144;
        const u16* ggTi = ggT + (size_t)i * 2097152;
        const u16* foTi = foT + (size_t)i * 1048576;

        // attention
        layernorm_b<<<N_NODES / 4, 256, 0, stream>>>(h, ln2w + i * DIM, ln2b + i * DIM, t0b);
        bgemm<1><<<dim3(4, 128, 1), 256, 0, stream>>>(
            t0b, 512, WqTi, 512, nullptr, nullptr, 0, nullptr, qb, 512, 512, 1,
            0, 0, 0, 0, 0, 0);
        bgemm<1><<<dim3(4, 32, 1), 256, 0, stream>>>(
            condb, 512, WkTi, 512, nullptr, nullptr, 0, nullptr, kb, 512, 512, 1,
            0, 0, 0, 0, 0, 0);
        bgemm<3><<<dim3(4, 32, 1), 256, 0, stream>>>(
            condb, 512, WvTi, 512, nullptr, nullptr, 0, nullptr, Vt, 0, 512, 1,
            0, 0, 0, 0, 0, 0);
        fused_attn<<<dim3(4, 8, 16), 256, 0, stream>>>(qb, kb, Vt, ob);
        bgemm<2><<<dim3(4, 128, 1), 256, 0, stream>>>(
            ob, 512, WoTi, 512, nullptr, h, 512, nullptr, h, 512, 512, 1,
            0, 0, 0, 0, 0, 0);

        // GEGLU FFN
        layernorm_b<<<N_NODES / 4, 256, 0, stream>>>(h, ln3w + i * DIM, ln3b + i * DIM, t0b);
        for (int c = 0; c < nch; ++c) {
            const u16* ac = t0b + (size_t)c * ffrows * 512;
            float* hc = h + (size_t)c * ffrows * 512;
            bgemm<1><<<dim3(DG / 128, ffrows / 128, 1), 256, 0, stream>>>(
                ac, 512, ggTi, 512, ggb + (size_t)i * DG, nullptr, 0, nullptr,
                Ubuf, DG, 512, 1, 0, 0, 0, 0, 0, 0);
            geglu_act<<<ffrows, 256, 0, stream>>>(Ubuf, Abuf);
            bgemm<2><<<dim3(4, ffrows / 128, 1), 256, 0, stream>>>(
                Abuf, 2048, foTi, 2048, fob + (size_t)i * DIM, hc, 512, nullptr,
                hc, 512, 2048, 1, 0, 0, 0, 0, 0, 0);
        }
    }

    // GCN out + residual x
    conv_f2b<<<8192, 256, 0, stream>>>(h, t0b);
    bgemm<4><<<dim3(4, 128, 1), 256, 0, stream>>>(
        t0b, 512, gcnOutT, 512, nullptr, nullptr, 0, dinv, qb, 512, 512, 1,
        0, 0, 0, 0, 0, 0);
    gcn_gather<<<N_NODES / 4, 256, 0, stream>>>(qb, csr_src, csr_off, dinv,
                                                gcn_out_b, x, outp);
}

// Round 4
// 1528.560 us; speedup vs baseline: 7.6996x; 1.0546x over previous
//
#include <hip/hip_runtime.h>
#include <math.h>
#include <stdio.h>

#define N_NODES 16384
#define DIM     512
#define BSZ     16
#define SEQ     1024
#define MCTX    256
#define NHEAD   8
#define DHEAD   64
#define NLAYER  4
#define NEDGE   262144
#define DFF     2048
#define DG      4096
#define LNEPS   1e-5f

typedef unsigned short u16;
typedef __attribute__((ext_vector_type(8))) __bf16 bf16x8;
typedef __attribute__((ext_vector_type(4))) float f32x4;
typedef __attribute__((ext_vector_type(4))) unsigned short u16x4;
typedef __attribute__((ext_vector_type(8))) unsigned short u16x8;

__device__ __forceinline__ u16 f2b(float f) {
    unsigned u = __float_as_uint(f);
    unsigned r = (u + 0x7fff + ((u >> 16) & 1)) >> 16;
    return (u16)r;
}
__device__ __forceinline__ float b2f(u16 h) {
    return __uint_as_float((unsigned)h << 16);
}
__device__ __forceinline__ float gelu_exact(float x) {
    return 0.5f * x * (1.0f + erff(x * 0.70710678118654752f));
}
__device__ __forceinline__ void gload16(const void* g, void* l) {
    __builtin_amdgcn_global_load_lds(
        (const __attribute__((address_space(1))) unsigned int*)g,
        (__attribute__((address_space(3))) unsigned int*)l, 16, 0, 0);
}

// bijective XCD-chunk swizzle (m204)
__device__ __forceinline__ int2 xcd_map() {
    int gx = gridDim.x, gy = gridDim.y;
    int nwg = gx * gy;
    int id = blockIdx.y * gx + blockIdx.x;
    int q = nwg >> 3, r = nwg & 7;
    int xcd = id & 7, idx = id >> 3;
    int nid = (xcd < r ? xcd * (q + 1) : r * (q + 1) + (xcd - r) * q) + idx;
    int2 o; o.x = nid % gx; o.y = nid / gx; return o;
}

// ---------------------------------------------------------------------------
// bf16 MFMA GEMM, 128x128 tile, BK=64, double-buffered LDS, XCD swizzle.
// A [M][K] bf16 row-major, Bt [N][K] bf16 row-major.
// EPI: 1 = bf16 out (+bias) ; 2 = f32 out = acc+bias+resid ;
//      3 = V-transpose (LDS bounce -> Vt[b][h][d][m], coalesced) ;
//      4 = bf16 rowscale ; 5 = fused GEGLU (pair-interleaved W, bf16 out N/2)
// ---------------------------------------------------------------------------
template<int EPI>
__global__ __launch_bounds__(256) void bgemm(
    const u16* __restrict__ A, long lda,
    const u16* __restrict__ Bt, long ldb,
    const float* __restrict__ bias,
    const float* __restrict__ resid, long ldr,
    const float* __restrict__ rowscale,
    void* __restrict__ Cv, long ldc, int K, int nlo,
    long aHi, long aLo, long bHi, long bLo, long cHi, long cLo)
{
    __shared__ u16 lds[32768];    // A0 | A1 | B0 | B1, 16KB each

    const int t = threadIdx.x;
    const int z = blockIdx.z;
    const int zhi = z / nlo, zlo = z % nlo;
    const u16* Ag = A + (size_t)zhi * aHi + (size_t)zlo * aLo;
    const u16* Bg = Bt + (size_t)zhi * bHi + (size_t)zlo * bLo;
    const long coff = (long)zhi * cHi + (long)zlo * cLo;

    int2 sw = xcd_map();
    const int row0 = sw.y * 128;
    const int col0 = sw.x * 128;
    const int wave = t >> 6, lane = t & 63;
    const int wm0 = (wave >> 1) * 64, wn0 = (wave & 1) * 64;
    const int fr = lane & 15, fq = lane >> 4;
    const int ldsWave = (t & 192) * 16;
    const int rS = t >> 3;
    const int slotP = t & 7;

    f32x4 acc[4][4];
#pragma unroll
    for (int mi = 0; mi < 4; ++mi)
#pragma unroll
        for (int ni = 0; ni < 4; ++ni) acc[mi][ni] = (f32x4){0.f, 0.f, 0.f, 0.f};

    auto stage = [&](int buf, int k0) {
        u16* Ad = lds + buf * 8192;
        u16* Bd = lds + 16384 + buf * 8192;
#pragma unroll
        for (int i = 0; i < 4; ++i) {
            int r = i * 32 + rS;
            int sl = slotP ^ (r & 7);
            gload16(Ag + (size_t)(row0 + r) * lda + k0 + sl * 8,
                    (char*)Ad + i * 4096 + ldsWave);
        }
#pragma unroll
        for (int i = 0; i < 4; ++i) {
            int r = i * 32 + rS;
            int sl = slotP ^ (r & 7);
            gload16(Bg + (size_t)(col0 + r) * ldb + k0 + sl * 8,
                    (char*)Bd + i * 4096 + ldsWave);
        }
    };
    auto compute = [&](int buf) {
        const u16* Ac = lds + buf * 8192;
        const u16* Bc = lds + 16384 + buf * 8192;
#pragma unroll
        for (int ks = 0; ks < 2; ++ks) {
            const int ksl = ks * 4 + fq;
            bf16x8 av[4], bv[4];
#pragma unroll
            for (int mi = 0; mi < 4; ++mi) {
                int r = wm0 + mi * 16 + fr;
                av[mi] = *(const bf16x8*)&Ac[r * 64 + ((ksl ^ (r & 7)) * 8)];
            }
#pragma unroll
            for (int ni = 0; ni < 4; ++ni) {
                int r = wn0 + ni * 16 + fr;
                bv[ni] = *(const bf16x8*)&Bc[r * 64 + ((ksl ^ (r & 7)) * 8)];
            }
#pragma unroll
            for (int mi = 0; mi < 4; ++mi)
#pragma unroll
                for (int ni = 0; ni < 4; ++ni)
                    acc[mi][ni] = __builtin_amdgcn_mfma_f32_16x16x32_bf16(
                        av[mi], bv[ni], acc[mi][ni], 0, 0, 0);
        }
    };

    int cur = 0;
    stage(0, 0);
    __syncthreads();
    for (int k0 = 64; k0 < K; k0 += 64) {
        stage(cur ^ 1, k0);
        compute(cur);
        __syncthreads();
        cur ^= 1;
    }
    compute(cur);

    if (EPI == 3) {
        // per-wave 64x64 tile -> LDS (padded) -> coalesced Vt[b][h][d][m]
        __syncthreads();
        u16* Tw = lds + wave * 4608;   // 64 x 72
#pragma unroll
        for (int mi = 0; mi < 4; ++mi)
#pragma unroll
            for (int ni = 0; ni < 4; ++ni)
#pragma unroll
                for (int j = 0; j < 4; ++j)
                    Tw[(ni * 16 + fr) * 72 + mi * 16 + fq * 4 + j] =
                        f2b(acc[mi][ni][j]);
        const int r0w = row0 + wm0;
        const int b = r0w >> 8, m0w = r0w & 255;
        const int cc0 = col0 + wn0, hh = cc0 >> 6;
        u16* dst = (u16*)Cv + ((size_t)(b * 8 + hh) * 64) * 256 + m0w;
#pragma unroll
        for (int it = 0; it < 8; ++it) {
            int dl = it * 8 + (lane >> 3);
            int ml = (lane & 7) * 8;
            u16x8 v = *(const u16x8*)&Tw[dl * 72 + ml];
            *(u16x8*)&dst[(size_t)dl * 256 + ml] = v;
        }
        return;
    }

    float* Cf = (float*)Cv;
    u16* Cb = (u16*)Cv;
#pragma unroll
    for (int mi = 0; mi < 4; ++mi) {
        const int rb = row0 + wm0 + mi * 16 + fq * 4;
#pragma unroll
        for (int ni = 0; ni < 4; ++ni) {
            const int cc = col0 + wn0 + ni * 16 + fr;
            f32x4 v = acc[mi][ni];
            float bval = 0.f;
            if ((EPI == 1 || EPI == 2) && bias) bval = bias[cc];
            if (EPI == 5) bval = bias[(cc & 1) ? (cc >> 1) + DFF : (cc >> 1)];
#pragma unroll
            for (int j = 0; j < 4; ++j) {
                const long r = rb + j;
                float o = v[j] + bval;
                if (EPI == 1) {
                    Cb[coff + r * ldc + cc] = f2b(o);
                } else if (EPI == 2) {
                    Cf[coff + r * ldc + cc] = o + resid[r * ldr + cc];
                } else if (EPI == 4) {
                    Cb[coff + r * ldc + cc] = f2b(o * rowscale[r]);
                } else if (EPI == 5) {
                    float g = __shfl_xor(o, 1, 64);
                    if ((fr & 1) == 0)
                        Cb[coff + r * ldc + (cc >> 1)] = f2b(o * gelu_exact(g));
                }
            }
        }
    }
}

// ---------------------------------------------------------------------------
// Fused attention (MCTX fits LDS). Per block: 256 q-rows, one (head, batch).
// ---------------------------------------------------------------------------
__global__ __launch_bounds__(256) void fused_attn(
    const u16* __restrict__ Q,    // [16384][512]
    const u16* __restrict__ Kp,   // [4096][512]
    const u16* __restrict__ Vt,   // [16][8][64][256]
    u16* __restrict__ O)          // [16384][512]
{
    __shared__ u16 Ks[256 * 64];
    __shared__ u16 Vs[64 * 256];
    __shared__ u16 Ps[4][16 * 256];

    const int t = threadIdx.x;
    const int wave = t >> 6, lane = t & 63;
    const int fr = lane & 15, fq = lane >> 4;
    const int qc = blockIdx.x, h = blockIdx.y, b = blockIdx.z;
    const int ldsW = (t & 192) * 16;

#pragma unroll
    for (int i = 0; i < 8; ++i) {
        int idx = i * 256 + t;
        int m = idx >> 3, s = idx & 7;
        gload16(Kp + (size_t)(b * MCTX + m) * 512 + h * 64 + ((s ^ (m & 7)) * 8),
                (char*)Ks + i * 4096 + ldsW);
    }
#pragma unroll
    for (int i = 0; i < 8; ++i) {
        int idx = i * 256 + t;
        int d = idx >> 5, s = idx & 31;
        gload16(Vt + (size_t)((b * 8 + h) * 64 + d) * 256 + ((s ^ (d & 7)) * 8),
                (char*)Vs + i * 4096 + ldsW);
    }
    __syncthreads();

    u16* Pw = Ps[wave];
    for (int it = 0; it < 4; ++it) {
        const int q0 = qc * 256 + it * 64 + wave * 16;
        bf16x8 aq[2];
#pragma unroll
        for (int ks = 0; ks < 2; ++ks)
            aq[ks] = *(const bf16x8*)&Q[(size_t)(b * SEQ + q0 + fr) * 512 +
                                        h * 64 + ks * 32 + fq * 8];
        f32x4 accS[16];
#pragma unroll
        for (int ni = 0; ni < 16; ++ni) accS[ni] = (f32x4){0.f, 0.f, 0.f, 0.f};
#pragma unroll
        for (int ni = 0; ni < 16; ++ni) {
            int m = ni * 16 + fr;
#pragma unroll
            for (int ks = 0; ks < 2; ++ks) {
                bf16x8 bv = *(const bf16x8*)&Ks[m * 64 + (((ks * 4 + fq) ^ (m & 7)) * 8)];
                accS[ni] = __builtin_amdgcn_mfma_f32_16x16x32_bf16(
                    aq[ks], bv, accS[ni], 0, 0, 0);
            }
        }
        const float cs = 0.125f;
#pragma unroll
        for (int j = 0; j < 4; ++j) {
            float m0 = accS[0][j];
#pragma unroll
            for (int ni = 1; ni < 16; ++ni) m0 = fmaxf(m0, accS[ni][j]);
            m0 = fmaxf(m0, __shfl_xor(m0, 1, 64));
            m0 = fmaxf(m0, __shfl_xor(m0, 2, 64));
            m0 = fmaxf(m0, __shfl_xor(m0, 4, 64));
            m0 = fmaxf(m0, __shfl_xor(m0, 8, 64));
            float s0 = 0.f;
#pragma unroll
            for (int ni = 0; ni < 16; ++ni) {
                float p = __expf((accS[ni][j] - m0) * cs);
                accS[ni][j] = p;
                s0 += p;
            }
            s0 += __shfl_xor(s0, 1, 64);
            s0 += __shfl_xor(s0, 2, 64);
            s0 += __shfl_xor(s0, 4, 64);
            s0 += __shfl_xor(s0, 8, 64);
            float inv = 1.f / s0;
#pragma unroll
            for (int ni = 0; ni < 16; ++ni) {
                int cc = ni * 16 + fr;
                int rr = fq * 4 + j;
                Pw[rr * 256 + (((cc >> 3) ^ (rr & 7)) * 8) + (cc & 7)] =
                    f2b(accS[ni][j] * inv);
            }
        }
        bf16x8 ap[8];
#pragma unroll
        for (int ks = 0; ks < 8; ++ks)
            ap[ks] = *(const bf16x8*)&Pw[fr * 256 + (((ks * 4 + fq) ^ (fr & 7)) * 8)];
        f32x4 accO[4];
#pragma unroll
        for (int ni = 0; ni < 4; ++ni) accO[ni] = (f32x4){0.f, 0.f, 0.f, 0.f};
#pragma unroll
        for (int ni = 0; ni < 4; ++ni) {
            int d = ni * 16 + fr;
#pragma unroll
            for (int ks = 0; ks < 8; ++ks) {
                bf16x8 bv = *(const bf16x8*)&Vs[d * 256 + (((ks * 4 + fq) ^ (d & 7)) * 8)];
                accO[ni] = __builtin_amdgcn_mfma_f32_16x16x32_bf16(
                    ap[ks], bv, accO[ni], 0, 0, 0);
            }
        }
#pragma unroll
        for (int ni = 0; ni < 4; ++ni)
#pragma unroll
            for (int j = 0; j < 4; ++j)
                O[(size_t)(b * SEQ + q0 + fq * 4 + j) * 512 + h * 64 + ni * 16 + fr] =
                    f2b(accO[ni][j]);
    }
}

// ---------------------------------------------------------------------------
// Batched weight transpose+convert: src f32 [K][N] -> dst bf16 [N][K].
// permN > 0: destination row p = (n<permN) ? 2n : 2(n-permN)+1 (GEGLU pairing)
// ---------------------------------------------------------------------------
__global__ __launch_bounds__(256) void transposeW(const float* __restrict__ src,
                                                  u16* __restrict__ dst,
                                                  int K, int N,
                                                  long srcZ, long dstZ, int permN)
{
    __shared__ float tile[64][65];
    const int t = threadIdx.x;
    const int n0 = blockIdx.x * 64, k0 = blockIdx.y * 64;
    const float* s = src + (size_t)blockIdx.z * srcZ;
    u16* d = dst + (size_t)blockIdx.z * dstZ;
#pragma unroll
    for (int i = 0; i < 16; ++i) {
        int idx = i * 256 + t;
        int rr = idx >> 6, cc = idx & 63;
        tile[rr][cc] = s[(size_t)(k0 + rr) * N + n0 + cc];
    }
    __syncthreads();
#pragma unroll
    for (int i = 0; i < 16; ++i) {
        int idx = i * 256 + t;
        int rr = idx >> 6, cc = idx & 63;
        int n = n0 + rr;
        int p = permN ? ((n < permN) ? 2 * n : 2 * (n - permN) + 1) : n;
        d[(size_t)p * K + k0 + cc] = f2b(tile[cc][rr]);
    }
}

__global__ __launch_bounds__(256) void conv_f2b(const float* __restrict__ in,
                                                u16* __restrict__ out)
{
    size_t i = (size_t)blockIdx.x * 256 + threadIdx.x;
    float4 v = ((const float4*)in)[i];
    u16x4 o;
    o[0] = f2b(v.x); o[1] = f2b(v.y); o[2] = f2b(v.z); o[3] = f2b(v.w);
    ((u16x4*)out)[i] = o;
}

// ---------------------------------------------------------------------------
__global__ __launch_bounds__(512) void bn_colstats(const float* __restrict__ x,
                                                   float* __restrict__ cs,
                                                   float* __restrict__ cq)
{
    int c = threadIdx.x;
    int r0 = blockIdx.x * 128;
    float s = 0.f, q = 0.f;
    for (int r = 0; r < 128; ++r) {
        float v = x[(size_t)(r0 + r) * DIM + c];
        s += v; q += v * v;
    }
    atomicAdd(&cs[c], s);
    atomicAdd(&cq[c], q);
}

__global__ void bn_finalize(const float* __restrict__ cs, const float* __restrict__ cq,
                            const float* __restrict__ bw, const float* __restrict__ bb,
                            float* __restrict__ scale, float* __restrict__ shift)
{
    int c = threadIdx.x;
    float m   = cs[c] * (1.f / N_NODES);
    float var = cq[c] * (1.f / N_NODES) - m * m;
    float rs  = rsqrtf(var + LNEPS);
    float sc  = rs * bw[c];
    scale[c] = sc;
    shift[c] = bb[c] - m * sc;
}

__global__ __launch_bounds__(256) void bn_apply_b(const float* __restrict__ x,
                                                  const float* __restrict__ scale,
                                                  const float* __restrict__ shift,
                                                  u16* __restrict__ out)
{
    size_t idx = (size_t)blockIdx.x * 256 + threadIdx.x;
    int c4 = (int)(idx & 127);
    float4 v  = ((const float4*)x)[idx];
    float4 sc = ((const float4*)scale)[c4];
    float4 sh = ((const float4*)shift)[c4];
    u16x4 o;
    o[0] = f2b(v.x * sc.x + sh.x); o[1] = f2b(v.y * sc.y + sh.y);
    o[2] = f2b(v.z * sc.z + sh.z); o[3] = f2b(v.w * sc.w + sh.w);
    ((u16x4*)out)[idx] = o;
}

__global__ __launch_bounds__(256) void layernorm_b(const float* __restrict__ in,
                                                   const float* __restrict__ w,
                                                   const float* __restrict__ bsh,
                                                   u16* __restrict__ out)
{
    int lane = threadIdx.x & 63, wv = threadIdx.x >> 6;
    size_t row = (size_t)blockIdx.x * 4 + wv;
    const float* p = in + row * DIM + lane * 8;
    float4 v0 = *(const float4*)p;
    float4 v1 = *(const float4*)(p + 4);
    float s = v0.x + v0.y + v0.z + v0.w + v1.x + v1.y + v1.z + v1.w;
    float q = v0.x * v0.x + v0.y * v0.y + v0.z * v0.z + v0.w * v0.w +
              v1.x * v1.x + v1.y * v1.y + v1.z * v1.z + v1.w * v1.w;
    for (int m = 1; m < 64; m <<= 1) {
        s += __shfl_xor(s, m, 64);
        q += __shfl_xor(q, m, 64);
    }
    float mean = s * (1.f / DIM);
    float rs = rsqrtf(q * (1.f / DIM) - mean * mean + LNEPS);
    float4 w0 = *(const float4*)(w + lane * 8),   w1 = *(const float4*)(w + lane * 8 + 4);
    float4 b0 = *(const float4*)(bsh + lane * 8), b1 = *(const float4*)(bsh + lane * 8 + 4);
    u16x8 o;
    o[0] = f2b((v0.x - mean) * rs * w0.x + b0.x);
    o[1] = f2b((v0.y - mean) * rs * w0.y + b0.y);
    o[2] = f2b((v0.z - mean) * rs * w0.z + b0.z);
    o[3] = f2b((v0.w - mean) * rs * w0.w + b0.w);
    o[4] = f2b((v1.x - mean) * rs * w1.x + b1.x);
    o[5] = f2b((v1.y - mean) * rs * w1.y + b1.y);
    o[6] = f2b((v1.z - mean) * rs * w1.z + b1.z);
    o[7] = f2b((v1.w - mean) * rs * w1.w + b1.w);
    *(u16x8*)(out + row * DIM + lane * 8) = o;
}

// ---------------------------------------------------------------------------
__global__ void detect_i64(const int* __restrict__ e, int* __restrict__ flag)
{
    int idx = blockIdx.x * blockDim.x + threadIdx.x;
    if (e[2 * idx + 1] != 0) flag[0] = 1;
}

__global__ void deg_count(const int* __restrict__ eb, const int* __restrict__ flag,
                          int* __restrict__ deg)
{
    int e = blockIdx.x * blockDim.x + threadIdx.x;
    int d;
    if (flag[0]) d = eb[NEDGE + e];
    else         d = (int)((const long long*)eb)[NEDGE + e];
    atomicAdd(&deg[d], 1);
}

__global__ void dinv_k(const int* __restrict__ deg, float* __restrict__ dinv)
{
    int i = blockIdx.x * blockDim.x + threadIdx.x;
    dinv[i] = rsqrtf((float)(deg[i] + 1));
}

__global__ __launch_bounds__(1024) void scan_deg(const int* __restrict__ deg,
                                                 int* __restrict__ off)
{
    __shared__ int sums[1024];
    int t = threadIdx.x;
    int base = t * 16;
    int v[16]; int s = 0;
#pragma unroll
    for (int i = 0; i < 16; ++i) { v[i] = deg[base + i]; s += v[i]; }
    sums[t] = s;
    __syncthreads();
    for (int ofs = 1; ofs < 1024; ofs <<= 1) {
        int x = (t >= ofs) ? sums[t - ofs] : 0;
        __syncthreads();
        sums[t] += x;
        __syncthreads();
    }
    int run = (t == 0) ? 0 : sums[t - 1];
#pragma unroll
    for (int i = 0; i < 16; ++i) { off[base + i] = run; run += v[i]; }
    if (t == 1023) off[N_NODES] = run;
}

__global__ void fill_k(const int* __restrict__ eb, const int* __restrict__ flag,
                       const int* __restrict__ off, int* __restrict__ cursor,
                       int* __restrict__ csr)
{
    int e = blockIdx.x * blockDim.x + threadIdx.x;
    int s, d;
    if (flag[0]) { s = eb[e]; d = eb[NEDGE + e]; }
    else {
        const long long* p = (const long long*)eb;
        s = (int)p[e]; d = (int)p[NEDGE + e];
    }
    int pos = atomicAdd(&cursor[d], 1);
    csr[off[d] + pos] = s;
}

// h2 rows are PRE-SCALED by dinv[row]; 1-ahead row prefetch, chain ends on
// the self row: out = dd * (sum_src h2[src] + h2[d]) + bias (+ addx)
__global__ __launch_bounds__(256) void gcn_gather(
    const u16* __restrict__ h2, const int* __restrict__ csr,
    const int* __restrict__ off, const float* __restrict__ dinv,
    const float* __restrict__ bias, const float* __restrict__ addx,
    float* __restrict__ out)
{
    int lane = threadIdx.x & 63, wv = threadIdx.x >> 6;
    int d = blockIdx.x * 4 + wv;
    float acc[8];
#pragma unroll
    for (int j = 0; j < 8; ++j) acc[j] = 0.f;
    int e0 = off[d], e1 = off[d + 1];
    float dd = dinv[d];
    int sidx = (e0 < e1) ? csr[e0] : d;
    u16x8 v = *(const u16x8*)&h2[(size_t)sidx * DIM + lane * 8];
    for (int e = e0; e < e1; ++e) {
        int snext = (e + 1 < e1) ? csr[e + 1] : d;
        u16x8 vn = *(const u16x8*)&h2[(size_t)snext * DIM + lane * 8];
#pragma unroll
        for (int j = 0; j < 8; ++j) acc[j] += b2f(v[j]);
        v = vn;
    }
#pragma unroll
    for (int j = 0; j < 8; ++j) acc[j] = (acc[j] + b2f(v[j])) * dd;
    float o[8];
#pragma unroll
    for (int j = 0; j < 8; ++j) {
        o[j] = acc[j] + bias[lane * 8 + j];
        if (addx) o[j] += addx[(size_t)d * DIM + lane * 8 + j];
    }
    float* op = out + (size_t)d * DIM + lane * 8;
    *(float4*)op = make_float4(o[0], o[1], o[2], o[3]);
    *(float4*)(op + 4) = make_float4(o[4], o[5], o[6], o[7]);
}

// ---------------------------------------------------------------------------
extern "C" void kernel_launch(void* const* d_in, const int* in_sizes, int n_in,
                              void* d_out, int out_size, void* d_ws, size_t ws_size,
                              hipStream_t stream)
{
    const float* x         = (const float*)d_in[0];
    const int*   edges     = (const int*)d_in[1];
    const float* cond      = (const float*)d_in[2];
    const float* bn_w      = (const float*)d_in[3];
    const float* bn_b      = (const float*)d_in[4];
    const float* gcn_in_w  = (const float*)d_in[5];
    const float* gcn_in_b  = (const float*)d_in[6];
    const float* gcn_out_w = (const float*)d_in[7];
    const float* gcn_out_b = (const float*)d_in[8];
    const float* Wq  = (const float*)d_in[9];
    const float* Wk  = (const float*)d_in[10];
    const float* Wv  = (const float*)d_in[11];
    const float* Wo  = (const float*)d_in[12];
    const float* ln2w = (const float*)d_in[13];
    const float* ln2b = (const float*)d_in[14];
    const float* ln3w = (const float*)d_in[15];
    const float* ln3b = (const float*)d_in[16];
    const float* ggw = (const float*)d_in[17];
    const float* ggb = (const float*)d_in[18];
    const float* fow = (const float*)d_in[19];
    const float* fob = (const float*)d_in[20];
    float* outp = (float*)d_out;

    char* wsb = (char*)d_ws;
    size_t wsoff = 0;
    auto alloc = [&](size_t bytes) -> void* {
        void* p = wsb + wsoff;
        wsoff = (wsoff + bytes + 255) & ~(size_t)255;
        return p;
    };
    u16*   wT    = (u16*)  alloc((size_t)17301504 * 2);
    u16*   condb = (u16*)  alloc((size_t)4096 * 512 * 2);
    float* h     = (float*)alloc((size_t)N_NODES * DIM * 4);
    u16*   t0b   = (u16*)  alloc((size_t)N_NODES * DIM * 2);
    u16*   qb    = (u16*)  alloc((size_t)N_NODES * DIM * 2);
    u16*   ob    = (u16*)  alloc((size_t)N_NODES * DIM * 2);
    u16*   kb    = (u16*)  alloc((size_t)4096 * 512 * 2);
    u16*   Vt    = (u16*)  alloc((size_t)BSZ * NHEAD * DHEAD * MCTX * 2);
    char*  zbase  = wsb + wsoff;
    float* colsum = (float*)alloc(DIM * 4);
    float* colsq  = (float*)alloc(DIM * 4);
    int*   deg    = (int*)  alloc(N_NODES * 4);
    int*   cursor = (int*)  alloc(N_NODES * 4);
    int*   eflag  = (int*)  alloc(256);
    size_t zbytes = (size_t)((wsb + wsoff) - zbase);
    float* bscale = (float*)alloc(DIM * 4);
    float* bshift = (float*)alloc(DIM * 4);
    float* dinv   = (float*)alloc(N_NODES * 4);
    int*   csr_off= (int*)  alloc((N_NODES + 16) * 4);
    int*   csr_src= (int*)  alloc((size_t)NEDGE * 4);

    // FFN chunking: only Ab [rows][2048] bf16 needed now
    int nch = 0;
    for (int c = 1; c <= 16; c *= 2) {
        size_t need = ((size_t)N_NODES / c) * DFF * 2;
        if (wsoff + need <= ws_size) { nch = c; break; }
    }
    if (nch == 0) { fprintf(stderr, "ws too small (%zu)\n", ws_size); return; }
    u16* Abuf = (u16*)(wsb + wsoff);

    hipMemsetAsync(zbase, 0, zbytes, stream);

    // weight transposes (batched over layers); gg uses pair-interleave perm
    u16* gcnInT  = wT;
    u16* gcnOutT = gcnInT + 262144;
    u16* WqT = gcnOutT + 262144;
    u16* WkT = WqT + 4 * 262144;
    u16* WvT = WkT + 4 * 262144;
    u16* WoT = WvT + 4 * 262144;
    u16* ggT = WoT + 4 * 262144;
    u16* foT = ggT + 4 * 2097152;
    transposeW<<<dim3(8, 8, 1), 256, 0, stream>>>(gcn_in_w,  gcnInT, 512, 512, 0, 0, 0);
    transposeW<<<dim3(8, 8, 1), 256, 0, stream>>>(gcn_out_w, gcnOutT, 512, 512, 0, 0, 0);
    transposeW<<<dim3(8, 8, 4), 256, 0, stream>>>(Wq, WqT, 512, 512, 262144, 262144, 0);
    transposeW<<<dim3(8, 8, 4), 256, 0, stream>>>(Wk, WkT, 512, 512, 262144, 262144, 0);
    transposeW<<<dim3(8, 8, 4), 256, 0, stream>>>(Wv, WvT, 512, 512, 262144, 262144, 0);
    transposeW<<<dim3(8, 8, 4), 256, 0, stream>>>(Wo, WoT, 512, 512, 262144, 262144, 0);
    transposeW<<<dim3(64, 8, 4), 256, 0, stream>>>(ggw, ggT, 512, DG, 2097152, 2097152, DFF);
    transposeW<<<dim3(8, 32, 4), 256, 0, stream>>>(fow, foT, DFF, 512, 1048576, 1048576, 0);
    conv_f2b<<<2048, 256, 0, stream>>>(cond, condb);

    // BatchNorm
    bn_colstats<<<128, 512, 0, stream>>>(x, colsum, colsq);
    bn_finalize<<<1, 512, 0, stream>>>(colsum, colsq, bn_w, bn_b, bscale, bshift);
    bn_apply_b<<<(N_NODES * DIM / 4) / 256, 256, 0, stream>>>(x, bscale, bshift, t0b);

    // graph prep
    detect_i64<<<NEDGE / 256, 256, 0, stream>>>(edges, eflag);
    deg_count<<<NEDGE / 256, 256, 0, stream>>>(edges, eflag, deg);
    dinv_k<<<N_NODES / 256, 256, 0, stream>>>(deg, dinv);
    scan_deg<<<1, 1024, 0, stream>>>(deg, csr_off);
    fill_k<<<NEDGE / 256, 256, 0, stream>>>(edges, eflag, csr_off, cursor, csr_src);

    // GCN in (rows pre-scaled by dinv via EPI=4)
    bgemm<4><<<dim3(4, 128, 1), 256, 0, stream>>>(
        t0b, 512, gcnInT, 512, nullptr, nullptr, 0, dinv, qb, 512, 512, 1,
        0, 0, 0, 0, 0, 0);
    gcn_gather<<<N_NODES / 4, 256, 0, stream>>>(qb, csr_src, csr_off, dinv,
                                                gcn_in_b, nullptr, h);

    const int ffrows = N_NODES / nch;
    for (int i = 0; i < NLAYER; ++i) {
        const u16* WqTi = WqT + (size_t)i * 262144;
        const u16* WkTi = WkT + (size_t)i * 262144;
        const u16* WvTi = WvT + (size_t)i * 262144;
        const u16* WoTi = WoT + (size_t)i * 262144;
        const u16* ggTi = ggT + (size_t)i * 2097152;
        const u16* foTi = foT + (size_t)i * 1048576;

        // attention
        layernorm_b<<<N_NODES / 4, 256, 0, stream>>>(h, ln2w + i * DIM, ln2b + i * DIM, t0b);
        bgemm<1><<<dim3(4, 128, 1), 256, 0, stream>>>(
            t0b, 512, WqTi, 512, nullptr, nullptr, 0, nullptr, qb, 512, 512, 1,
            0, 0, 0, 0, 0, 0);
        bgemm<1><<<dim3(4, 32, 1), 256, 0, stream>>>(
            condb, 512, WkTi, 512, nullptr, nullptr, 0, nullptr, kb, 512, 512, 1,
            0, 0, 0, 0, 0, 0);
        bgemm<3><<<dim3(4, 32, 1), 256, 0, stream>>>(
            condb, 512, WvTi, 512, nullptr, nullptr, 0, nullptr, Vt, 0, 512, 1,
            0, 0, 0, 0, 0, 0);
        fused_attn<<<dim3(4, 8, 16), 256, 0, stream>>>(qb, kb, Vt, ob);
        bgemm<2><<<dim3(4, 128, 1), 256, 0, stream>>>(
            ob, 512, WoTi, 512, nullptr, h, 512, nullptr, h, 512, 512, 1,
            0, 0, 0, 0, 0, 0);

        // GEGLU FFN (act fused into GEMM epilogue)
        layernorm_b<<<N_NODES / 4, 256, 0, stream>>>(h, ln3w + i * DIM, ln3b + i * DIM, t0b);
        for (int c = 0; c < nch; ++c) {
            const u16* ac = t0b + (size_t)c * ffrows * 512;
            float* hc = h + (size_t)c * ffrows * 512;
            bgemm<5><<<dim3(DG / 128, ffrows / 128, 1), 256, 0, stream>>>(
                ac, 512, ggTi, 512, ggb + (size_t)i * DG, nullptr, 0, nullptr,
                Abuf, DFF, 512, 1, 0, 0, 0, 0, 0, 0);
            bgemm<2><<<dim3(4, ffrows / 128, 1), 256, 0, stream>>>(
                Abuf, 2048, foTi, 2048, fob + (size_t)i * DIM, hc, 512, nullptr,
                hc, 512, 2048, 1, 0, 0, 0, 0, 0, 0);
        }
    }

    // GCN out + residual x
    conv_f2b<<<8192, 256, 0, stream>>>(h, t0b);
    bgemm<4><<<dim3(4, 128, 1), 256, 0, stream>>>(
        t0b, 512, gcnOutT, 512, nullptr, nullptr, 0, dinv, qb, 512, 512, 1,
        0, 0, 0, 0, 0, 0);
    gcn_gather<<<N_NODES / 4, 256, 0, stream>>>(qb, csr_src, csr_off, dinv,
                                                gcn_out_b, x, outp);
}

// Round 5
// 1322.703 us; speedup vs baseline: 8.8979x; 1.1556x over previous
//
#include <hip/hip_runtime.h>
#include <math.h>
#include <stdio.h>

#define N_NODES 16384
#define DIM     512
#define BSZ     16
#define SEQ     1024
#define MCTX    256
#define NHEAD   8
#define DHEAD   64
#define NLAYER  4
#define NEDGE   262144
#define DFF     2048
#define DG      4096
#define LNEPS   1e-5f

typedef unsigned short u16;
typedef __attribute__((ext_vector_type(8))) __bf16 bf16x8;
typedef __attribute__((ext_vector_type(4))) float f32x4;
typedef __attribute__((ext_vector_type(4))) unsigned short u16x4;
typedef __attribute__((ext_vector_type(8))) unsigned short u16x8;

__device__ __forceinline__ u16 f2b(float f) {
    unsigned u = __float_as_uint(f);
    unsigned r = (u + 0x7fff + ((u >> 16) & 1)) >> 16;
    return (u16)r;
}
__device__ __forceinline__ float b2f(u16 h) {
    return __uint_as_float((unsigned)h << 16);
}
__device__ __forceinline__ float gelu_exact(float x) {
    return 0.5f * x * (1.0f + erff(x * 0.70710678118654752f));
}
__device__ __forceinline__ void gload16(const void* g, void* l) {
    __builtin_amdgcn_global_load_lds(
        (const __attribute__((address_space(1))) unsigned int*)g,
        (__attribute__((address_space(3))) unsigned int*)l, 16, 0, 0);
}

// bijective XCD-chunk swizzle (m204)
__device__ __forceinline__ int2 xcd_map() {
    int gx = gridDim.x, gy = gridDim.y;
    int nwg = gx * gy;
    int id = blockIdx.y * gx + blockIdx.x;
    int q = nwg >> 3, r = nwg & 7;
    int xcd = id & 7, idx = id >> 3;
    int nid = (xcd < r ? xcd * (q + 1) : r * (q + 1) + (xcd - r) * q) + idx;
    int2 o; o.x = nid % gx; o.y = nid / gx; return o;
}

// ---------------------------------------------------------------------------
// 256x256 8-phase bf16 GEMM with fused GEGLU epilogue (pair-interleaved W).
// A [M][512] bf16, Bt [4096][512] bf16 (frag-pair-permuted), out [M][2048] bf16.
// 512 threads = 8 waves (2M x 4N), per-wave 128x64 output, BK=64, 128KiB LDS.
// Phases per K-tile: quadrants (0,0),(0,1),(1,0),(1,1); one half-tile staged
// per phase; vmcnt(4) once per K-tile (counted, never 0 in steady state).
// ---------------------------------------------------------------------------
__global__ __launch_bounds__(512, 2) void bgemm256_geglu(
    const u16* __restrict__ A, long lda,
    const u16* __restrict__ Bt, long ldb,
    const float* __restrict__ bias,
    u16* __restrict__ Cb, int K)
{
    __shared__ u16 lds[65536];   // A0 A1 B0 B1, 32KB each (u16 offsets 16384)

    const int t = threadIdx.x;
    const int w = t >> 6, lane = t & 63;
    const int fr = lane & 15, fq = lane >> 4;
    int2 sw = xcd_map();
    const int row0 = sw.y * 256;
    const int col0 = sw.x * 256;
    const int wm0 = (w >> 2) * 128, wn0 = (w & 3) * 64;
    const int sl = (lane & 7) ^ ((lane >> 3) & 7);   // src slot for staging

    f32x4 acc[8][4];
#pragma unroll
    for (int mf = 0; mf < 8; ++mf)
#pragma unroll
        for (int nf = 0; nf < 4; ++nf) acc[mf][nf] = (f32x4){0.f, 0.f, 0.f, 0.f};

    // stage A region P (rows with (r&64)==P*64) of K-tile kt_ into buffer bb
    auto stageA = [&](int kt_, int P, int bb) {
        const int k0 = kt_ << 6;
#pragma unroll
        for (int rd = 0; rd < 2; ++rd) {
            int rbase = rd * 128 + P * 64 + w * 8;            // wave-uniform
            int r = rbase + (lane >> 3);
            gload16(A + (size_t)(row0 + r) * lda + k0 + sl * 8,
                    (char*)(lds + bb * 16384) + rbase * 128);
        }
    };
    // stage B region Q (rows with (n&32)==Q*32)
    auto stageB = [&](int kt_, int Q, int bb) {
        const int k0 = kt_ << 6;
#pragma unroll
        for (int rd = 0; rd < 2; ++rd) {
            int jb = rd * 64 + w * 8;
            int nbase = ((jb >> 5) << 6) + Q * 32 + (jb & 31); // wave-uniform
            int n = nbase + (lane >> 3);
            gload16(Bt + (size_t)(col0 + n) * ldb + k0 + sl * 8,
                    (char*)(lds + 32768 + bb * 16384) + nbase * 128);
        }
    };

#define PHASE(MH, NH, STAGE_STMT, WC) do {                                    \
    const u16* Ab_ = lds + b * 16384;                                         \
    const u16* Bb_ = lds + 32768 + b * 16384;                                 \
    bf16x8 av[4][2], bv[2][2];                                                \
    _Pragma("unroll")                                                         \
    for (int mi = 0; mi < 4; ++mi) {                                          \
        int r = wm0 + MH * 64 + mi * 16 + fr;                                 \
        _Pragma("unroll")                                                     \
        for (int ks = 0; ks < 2; ++ks)                                        \
            av[mi][ks] = *(const bf16x8*)&Ab_[r * 64 + (((ks*4+fq) ^ (fr&7)) * 8)]; \
    }                                                                         \
    _Pragma("unroll")                                                         \
    for (int ni = 0; ni < 2; ++ni) {                                          \
        int n = wn0 + NH * 32 + ni * 16 + fr;                                 \
        _Pragma("unroll")                                                     \
        for (int ks = 0; ks < 2; ++ks)                                        \
            bv[ni][ks] = *(const bf16x8*)&Bb_[n * 64 + (((ks*4+fq) ^ (fr&7)) * 8)]; \
    }                                                                         \
    STAGE_STMT;                                                               \
    __builtin_amdgcn_s_barrier();                                             \
    asm volatile("s_waitcnt lgkmcnt(0)" ::: "memory");                        \
    __builtin_amdgcn_s_setprio(1);                                            \
    _Pragma("unroll")                                                         \
    for (int mi = 0; mi < 4; ++mi)                                            \
        _Pragma("unroll")                                                     \
        for (int ni = 0; ni < 2; ++ni)                                        \
            _Pragma("unroll")                                                 \
            for (int ks = 0; ks < 2; ++ks)                                    \
                acc[MH*4+mi][NH*2+ni] = __builtin_amdgcn_mfma_f32_16x16x32_bf16( \
                    av[mi][ks], bv[ni][ks], acc[MH*4+mi][NH*2+ni], 0, 0, 0);  \
    __builtin_amdgcn_s_setprio(0);                                            \
    { int wc_ = (WC);                                                         \
      if (wc_ == 4)      asm volatile("s_waitcnt vmcnt(4)" ::: "memory");     \
      else if (wc_ == 0) asm volatile("s_waitcnt vmcnt(0)" ::: "memory"); }   \
    __builtin_amdgcn_s_barrier();                                             \
} while (0)

    // prologue: tile0 all 4 regions + tile1 first 2 regions (steady-state order)
    stageA(0, 0, 0); stageB(0, 0, 0); stageA(0, 1, 0); stageB(0, 1, 0);
    stageA(1, 0, 1); stageB(1, 0, 1);
    asm volatile("s_waitcnt vmcnt(4)" ::: "memory");
    __builtin_amdgcn_s_barrier();

    const int NT = K >> 6;
    for (int kt = 0; kt < NT; ++kt) {
        const int b = kt & 1;
        const bool s1 = (kt + 1 < NT), s2 = (kt + 2 < NT);
        PHASE(0, 0, if (s1) stageA(kt + 1, 1, b ^ 1), -1);
        PHASE(0, 1, if (s1) stageB(kt + 1, 1, b ^ 1), -1);
        PHASE(1, 0, if (s2) stageA(kt + 2, 0, b), -1);
        PHASE(1, 1, if (s2) stageB(kt + 2, 0, b), s2 ? 4 : (s1 ? 0 : -1));
    }
#undef PHASE

    // fused GEGLU epilogue: acc[mf][2P]=val frag, acc[mf][2P+1]=gate frag
    const int nbase = (col0 + wn0) >> 1;
    float bval[2], bgat[2];
#pragma unroll
    for (int P = 0; P < 2; ++P) {
        int n = nbase + P * 16 + fr;
        bval[P] = bias[n];
        bgat[P] = bias[DFF + n];
    }
#pragma unroll
    for (int mf = 0; mf < 8; ++mf) {
        const int rb = row0 + wm0 + mf * 16 + fq * 4;
#pragma unroll
        for (int P = 0; P < 2; ++P) {
            const int n = nbase + P * 16 + fr;
#pragma unroll
            for (int j = 0; j < 4; ++j) {
                float v = acc[mf][2 * P][j] + bval[P];
                float g = acc[mf][2 * P + 1][j] + bgat[P];
                Cb[(size_t)(rb + j) * DFF + n] = f2b(v * gelu_exact(g));
            }
        }
    }
}

// ---------------------------------------------------------------------------
// bf16 MFMA GEMM, 128x128 tile, BK=64, double-buffered LDS, XCD swizzle.
// EPI: 1 = bf16 out (+bias) ; 2 = f32 out = acc+bias+resid ;
//      3 = V-transpose (LDS bounce -> Vt[b][h][d][m]) ; 4 = bf16 rowscale
// ---------------------------------------------------------------------------
template<int EPI>
__global__ __launch_bounds__(256) void bgemm(
    const u16* __restrict__ A, long lda,
    const u16* __restrict__ Bt, long ldb,
    const float* __restrict__ bias,
    const float* __restrict__ resid, long ldr,
    const float* __restrict__ rowscale,
    void* __restrict__ Cv, long ldc, int K, int nlo,
    long aHi, long aLo, long bHi, long bLo, long cHi, long cLo)
{
    __shared__ u16 lds[32768];    // A0 | A1 | B0 | B1, 16KB each

    const int t = threadIdx.x;
    const int z = blockIdx.z;
    const int zhi = z / nlo, zlo = z % nlo;
    const u16* Ag = A + (size_t)zhi * aHi + (size_t)zlo * aLo;
    const u16* Bg = Bt + (size_t)zhi * bHi + (size_t)zlo * bLo;
    const long coff = (long)zhi * cHi + (long)zlo * cLo;

    int2 sw = xcd_map();
    const int row0 = sw.y * 128;
    const int col0 = sw.x * 128;
    const int wave = t >> 6, lane = t & 63;
    const int wm0 = (wave >> 1) * 64, wn0 = (wave & 1) * 64;
    const int fr = lane & 15, fq = lane >> 4;
    const int ldsWave = (t & 192) * 16;
    const int rS = t >> 3;
    const int slotP = t & 7;

    f32x4 acc[4][4];
#pragma unroll
    for (int mi = 0; mi < 4; ++mi)
#pragma unroll
        for (int ni = 0; ni < 4; ++ni) acc[mi][ni] = (f32x4){0.f, 0.f, 0.f, 0.f};

    auto stage = [&](int buf, int k0) {
        u16* Ad = lds + buf * 8192;
        u16* Bd = lds + 16384 + buf * 8192;
#pragma unroll
        for (int i = 0; i < 4; ++i) {
            int r = i * 32 + rS;
            int s2 = slotP ^ (r & 7);
            gload16(Ag + (size_t)(row0 + r) * lda + k0 + s2 * 8,
                    (char*)Ad + i * 4096 + ldsWave);
        }
#pragma unroll
        for (int i = 0; i < 4; ++i) {
            int r = i * 32 + rS;
            int s2 = slotP ^ (r & 7);
            gload16(Bg + (size_t)(col0 + r) * ldb + k0 + s2 * 8,
                    (char*)Bd + i * 4096 + ldsWave);
        }
    };
    auto compute = [&](int buf) {
        const u16* Ac = lds + buf * 8192;
        const u16* Bc = lds + 16384 + buf * 8192;
#pragma unroll
        for (int ks = 0; ks < 2; ++ks) {
            const int ksl = ks * 4 + fq;
            bf16x8 av[4], bv[4];
#pragma unroll
            for (int mi = 0; mi < 4; ++mi) {
                int r = wm0 + mi * 16 + fr;
                av[mi] = *(const bf16x8*)&Ac[r * 64 + ((ksl ^ (r & 7)) * 8)];
            }
#pragma unroll
            for (int ni = 0; ni < 4; ++ni) {
                int r = wn0 + ni * 16 + fr;
                bv[ni] = *(const bf16x8*)&Bc[r * 64 + ((ksl ^ (r & 7)) * 8)];
            }
#pragma unroll
            for (int mi = 0; mi < 4; ++mi)
#pragma unroll
                for (int ni = 0; ni < 4; ++ni)
                    acc[mi][ni] = __builtin_amdgcn_mfma_f32_16x16x32_bf16(
                        av[mi], bv[ni], acc[mi][ni], 0, 0, 0);
        }
    };

    int cur = 0;
    stage(0, 0);
    __syncthreads();
    for (int k0 = 64; k0 < K; k0 += 64) {
        stage(cur ^ 1, k0);
        compute(cur);
        __syncthreads();
        cur ^= 1;
    }
    compute(cur);

    if (EPI == 3) {
        __syncthreads();
        u16* Tw = lds + wave * 4608;   // 64 x 72
#pragma unroll
        for (int mi = 0; mi < 4; ++mi)
#pragma unroll
            for (int ni = 0; ni < 4; ++ni)
#pragma unroll
                for (int j = 0; j < 4; ++j)
                    Tw[(ni * 16 + fr) * 72 + mi * 16 + fq * 4 + j] =
                        f2b(acc[mi][ni][j]);
        const int r0w = row0 + wm0;
        const int b = r0w >> 8, m0w = r0w & 255;
        const int cc0 = col0 + wn0, hh = cc0 >> 6;
        u16* dst = (u16*)Cv + ((size_t)(b * 8 + hh) * 64) * 256 + m0w;
#pragma unroll
        for (int it = 0; it < 8; ++it) {
            int dl = it * 8 + (lane >> 3);
            int ml = (lane & 7) * 8;
            u16x8 v = *(const u16x8*)&Tw[dl * 72 + ml];
            *(u16x8*)&dst[(size_t)dl * 256 + ml] = v;
        }
        return;
    }

    float* Cf = (float*)Cv;
    u16* Cb = (u16*)Cv;
#pragma unroll
    for (int mi = 0; mi < 4; ++mi) {
        const int rb = row0 + wm0 + mi * 16 + fq * 4;
#pragma unroll
        for (int ni = 0; ni < 4; ++ni) {
            const int cc = col0 + wn0 + ni * 16 + fr;
            f32x4 v = acc[mi][ni];
            float bval = 0.f;
            if ((EPI == 1 || EPI == 2) && bias) bval = bias[cc];
#pragma unroll
            for (int j = 0; j < 4; ++j) {
                const long r = rb + j;
                float o = v[j] + bval;
                if (EPI == 1) {
                    Cb[coff + r * ldc + cc] = f2b(o);
                } else if (EPI == 2) {
                    Cf[coff + r * ldc + cc] = o + resid[r * ldr + cc];
                } else if (EPI == 4) {
                    Cb[coff + r * ldc + cc] = f2b(o * rowscale[r]);
                }
            }
        }
    }
}

// ---------------------------------------------------------------------------
// Batched weight transpose+convert: src f32 [K][N] -> dst bf16 [N][K].
// permN > 0: GEGLU frag-pair interleave — val n -> (n/16)*32 + n%16,
//            gate m=n-permN -> (m/16)*32 + 16 + m%16
// ---------------------------------------------------------------------------
__global__ __launch_bounds__(256) void transposeW(const float* __restrict__ src,
                                                  u16* __restrict__ dst,
                                                  int K, int N,
                                                  long srcZ, long dstZ, int permN)
{
    __shared__ float tile[64][65];
    const int t = threadIdx.x;
    const int n0 = blockIdx.x * 64, k0 = blockIdx.y * 64;
    const float* s = src + (size_t)blockIdx.z * srcZ;
    u16* d = dst + (size_t)blockIdx.z * dstZ;
#pragma unroll
    for (int i = 0; i < 16; ++i) {
        int idx = i * 256 + t;
        int rr = idx >> 6, cc = idx & 63;
        tile[rr][cc] = s[(size_t)(k0 + rr) * N + n0 + cc];
    }
    __syncthreads();
#pragma unroll
    for (int i = 0; i < 16; ++i) {
        int idx = i * 256 + t;
        int rr = idx >> 6, cc = idx & 63;
        int n = n0 + rr;
        int p = n;
        if (permN) {
            p = (n < permN) ? (((n >> 4) << 5) + (n & 15))
                            : ((((n - permN) >> 4) << 5) + 16 + ((n - permN) & 15));
        }
        d[(size_t)p * K + k0 + cc] = f2b(tile[cc][rr]);
    }
}

__global__ __launch_bounds__(256) void conv_f2b(const float* __restrict__ in,
                                                u16* __restrict__ out)
{
    size_t i = (size_t)blockIdx.x * 256 + threadIdx.x;
    float4 v = ((const float4*)in)[i];
    u16x4 o;
    o[0] = f2b(v.x); o[1] = f2b(v.y); o[2] = f2b(v.z); o[3] = f2b(v.w);
    ((u16x4*)out)[i] = o;
}

// ---------------------------------------------------------------------------
__global__ __launch_bounds__(512) void bn_colstats(const float* __restrict__ x,
                                                   float* __restrict__ cs,
                                                   float* __restrict__ cq)
{
    int c = threadIdx.x;
    int r0 = blockIdx.x * 128;
    float s = 0.f, q = 0.f;
    for (int r = 0; r < 128; ++r) {
        float v = x[(size_t)(r0 + r) * DIM + c];
        s += v; q += v * v;
    }
    atomicAdd(&cs[c], s);
    atomicAdd(&cq[c], q);
}

__global__ void bn_finalize(const float* __restrict__ cs, const float* __restrict__ cq,
                            const float* __restrict__ bw, const float* __restrict__ bb,
                            float* __restrict__ scale, float* __restrict__ shift)
{
    int c = threadIdx.x;
    float m   = cs[c] * (1.f / N_NODES);
    float var = cq[c] * (1.f / N_NODES) - m * m;
    float rs  = rsqrtf(var + LNEPS);
    float sc  = rs * bw[c];
    scale[c] = sc;
    shift[c] = bb[c] - m * sc;
}

__global__ __launch_bounds__(256) void bn_apply_b(const float* __restrict__ x,
                                                  const float* __restrict__ scale,
                                                  const float* __restrict__ shift,
                                                  u16* __restrict__ out)
{
    size_t idx = (size_t)blockIdx.x * 256 + threadIdx.x;
    int c4 = (int)(idx & 127);
    float4 v  = ((const float4*)x)[idx];
    float4 sc = ((const float4*)scale)[c4];
    float4 sh = ((const float4*)shift)[c4];
    u16x4 o;
    o[0] = f2b(v.x * sc.x + sh.x); o[1] = f2b(v.y * sc.y + sh.y);
    o[2] = f2b(v.z * sc.z + sh.z); o[3] = f2b(v.w * sc.w + sh.w);
    ((u16x4*)out)[idx] = o;
}

__global__ __launch_bounds__(256) void layernorm_b(const float* __restrict__ in,
                                                   const float* __restrict__ w,
                                                   const float* __restrict__ bsh,
                                                   u16* __restrict__ out)
{
    int lane = threadIdx.x & 63, wv = threadIdx.x >> 6;
    size_t row = (size_t)blockIdx.x * 4 + wv;
    const float* p = in + row * DIM + lane * 8;
    float4 v0 = *(const float4*)p;
    float4 v1 = *(const float4*)(p + 4);
    float s = v0.x + v0.y + v0.z + v0.w + v1.x + v1.y + v1.z + v1.w;
    float q = v0.x * v0.x + v0.y * v0.y + v0.z * v0.z + v0.w * v0.w +
              v1.x * v1.x + v1.y * v1.y + v1.z * v1.z + v1.w * v1.w;
    for (int m = 1; m < 64; m <<= 1) {
        s += __shfl_xor(s, m, 64);
        q += __shfl_xor(q, m, 64);
    }
    float mean = s * (1.f / DIM);
    float rs = rsqrtf(q * (1.f / DIM) - mean * mean + LNEPS);
    float4 w0 = *(const float4*)(w + lane * 8),   w1 = *(const float4*)(w + lane * 8 + 4);
    float4 b0 = *(const float4*)(bsh + lane * 8), b1 = *(const float4*)(bsh + lane * 8 + 4);
    u16x8 o;
    o[0] = f2b((v0.x - mean) * rs * w0.x + b0.x);
    o[1] = f2b((v0.y - mean) * rs * w0.y + b0.y);
    o[2] = f2b((v0.z - mean) * rs * w0.z + b0.z);
    o[3] = f2b((v0.w - mean) * rs * w0.w + b0.w);
    o[4] = f2b((v1.x - mean) * rs * w1.x + b1.x);
    o[5] = f2b((v1.y - mean) * rs * w1.y + b1.y);
    o[6] = f2b((v1.z - mean) * rs * w1.z + b1.z);
    o[7] = f2b((v1.w - mean) * rs * w1.w + b1.w);
    *(u16x8*)(out + row * DIM + lane * 8) = o;
}

// ---------------------------------------------------------------------------
// Fused attention (MCTX fits LDS). Per block: 256 q-rows, one (head, batch).
// ---------------------------------------------------------------------------
__global__ __launch_bounds__(256) void fused_attn(
    const u16* __restrict__ Q,    // [16384][512]
    const u16* __restrict__ Kp,   // [4096][512]
    const u16* __restrict__ Vt,   // [16][8][64][256]
    u16* __restrict__ O)          // [16384][512]
{
    __shared__ u16 Ks[256 * 64];
    __shared__ u16 Vs[64 * 256];
    __shared__ u16 Ps[4][16 * 256];

    const int t = threadIdx.x;
    const int wave = t >> 6, lane = t & 63;
    const int fr = lane & 15, fq = lane >> 4;
    const int qc = blockIdx.x, h = blockIdx.y, b = blockIdx.z;
    const int ldsW = (t & 192) * 16;

#pragma unroll
    for (int i = 0; i < 8; ++i) {
        int idx = i * 256 + t;
        int m = idx >> 3, s = idx & 7;
        gload16(Kp + (size_t)(b * MCTX + m) * 512 + h * 64 + ((s ^ (m & 7)) * 8),
                (char*)Ks + i * 4096 + ldsW);
    }
#pragma unroll
    for (int i = 0; i < 8; ++i) {
        int idx = i * 256 + t;
        int d = idx >> 5, s = idx & 31;
        gload16(Vt + (size_t)((b * 8 + h) * 64 + d) * 256 + ((s ^ (d & 7)) * 8),
                (char*)Vs + i * 4096 + ldsW);
    }
    __syncthreads();

    u16* Pw = Ps[wave];
    for (int it = 0; it < 4; ++it) {
        const int q0 = qc * 256 + it * 64 + wave * 16;
        bf16x8 aq[2];
#pragma unroll
        for (int ks = 0; ks < 2; ++ks)
            aq[ks] = *(const bf16x8*)&Q[(size_t)(b * SEQ + q0 + fr) * 512 +
                                        h * 64 + ks * 32 + fq * 8];
        f32x4 accS[16];
#pragma unroll
        for (int ni = 0; ni < 16; ++ni) accS[ni] = (f32x4){0.f, 0.f, 0.f, 0.f};
#pragma unroll
        for (int ni = 0; ni < 16; ++ni) {
            int m = ni * 16 + fr;
#pragma unroll
            for (int ks = 0; ks < 2; ++ks) {
                bf16x8 bv = *(const bf16x8*)&Ks[m * 64 + (((ks * 4 + fq) ^ (m & 7)) * 8)];
                accS[ni] = __builtin_amdgcn_mfma_f32_16x16x32_bf16(
                    aq[ks], bv, accS[ni], 0, 0, 0);
            }
        }
        const float cs = 0.125f;
#pragma unroll
        for (int j = 0; j < 4; ++j) {
            float m0 = accS[0][j];
#pragma unroll
            for (int ni = 1; ni < 16; ++ni) m0 = fmaxf(m0, accS[ni][j]);
            m0 = fmaxf(m0, __shfl_xor(m0, 1, 64));
            m0 = fmaxf(m0, __shfl_xor(m0, 2, 64));
            m0 = fmaxf(m0, __shfl_xor(m0, 4, 64));
            m0 = fmaxf(m0, __shfl_xor(m0, 8, 64));
            float s0 = 0.f;
#pragma unroll
            for (int ni = 0; ni < 16; ++ni) {
                float p = __expf((accS[ni][j] - m0) * cs);
                accS[ni][j] = p;
                s0 += p;
            }
            s0 += __shfl_xor(s0, 1, 64);
            s0 += __shfl_xor(s0, 2, 64);
            s0 += __shfl_xor(s0, 4, 64);
            s0 += __shfl_xor(s0, 8, 64);
            float inv = 1.f / s0;
#pragma unroll
            for (int ni = 0; ni < 16; ++ni) {
                int cc = ni * 16 + fr;
                int rr = fq * 4 + j;
                Pw[rr * 256 + (((cc >> 3) ^ (rr & 7)) * 8) + (cc & 7)] =
                    f2b(accS[ni][j] * inv);
            }
        }
        bf16x8 ap[8];
#pragma unroll
        for (int ks = 0; ks < 8; ++ks)
            ap[ks] = *(const bf16x8*)&Pw[fr * 256 + (((ks * 4 + fq) ^ (fr & 7)) * 8)];
        f32x4 accO[4];
#pragma unroll
        for (int ni = 0; ni < 4; ++ni) accO[ni] = (f32x4){0.f, 0.f, 0.f, 0.f};
#pragma unroll
        for (int ni = 0; ni < 4; ++ni) {
            int d = ni * 16 + fr;
#pragma unroll
            for (int ks = 0; ks < 8; ++ks) {
                bf16x8 bv = *(const bf16x8*)&Vs[d * 256 + (((ks * 4 + fq) ^ (d & 7)) * 8)];
                accO[ni] = __builtin_amdgcn_mfma_f32_16x16x32_bf16(
                    ap[ks], bv, accO[ni], 0, 0, 0);
            }
        }
#pragma unroll
        for (int ni = 0; ni < 4; ++ni)
#pragma unroll
            for (int j = 0; j < 4; ++j)
                O[(size_t)(b * SEQ + q0 + fq * 4 + j) * 512 + h * 64 + ni * 16 + fr] =
                    f2b(accO[ni][j]);
    }
}

// ---------------------------------------------------------------------------
__global__ void detect_i64(const int* __restrict__ e, int* __restrict__ flag)
{
    int idx = blockIdx.x * blockDim.x + threadIdx.x;
    if (e[2 * idx + 1] != 0) flag[0] = 1;
}

__global__ void deg_count(const int* __restrict__ eb, const int* __restrict__ flag,
                          int* __restrict__ deg)
{
    int e = blockIdx.x * blockDim.x + threadIdx.x;
    int d;
    if (flag[0]) d = eb[NEDGE + e];
    else         d = (int)((const long long*)eb)[NEDGE + e];
    atomicAdd(&deg[d], 1);
}

__global__ void dinv_k(const int* __restrict__ deg, float* __restrict__ dinv)
{
    int i = blockIdx.x * blockDim.x + threadIdx.x;
    dinv[i] = rsqrtf((float)(deg[i] + 1));
}

__global__ __launch_bounds__(1024) void scan_deg(const int* __restrict__ deg,
                                                 int* __restrict__ off)
{
    __shared__ int sums[1024];
    int t = threadIdx.x;
    int base = t * 16;
    int v[16]; int s = 0;
#pragma unroll
    for (int i = 0; i < 16; ++i) { v[i] = deg[base + i]; s += v[i]; }
    sums[t] = s;
    __syncthreads();
    for (int ofs = 1; ofs < 1024; ofs <<= 1) {
        int x = (t >= ofs) ? sums[t - ofs] : 0;
        __syncthreads();
        sums[t] += x;
        __syncthreads();
    }
    int run = (t == 0) ? 0 : sums[t - 1];
#pragma unroll
    for (int i = 0; i < 16; ++i) { off[base + i] = run; run += v[i]; }
    if (t == 1023) off[N_NODES] = run;
}

__global__ void fill_k(const int* __restrict__ eb, const int* __restrict__ flag,
                       const int* __restrict__ off, int* __restrict__ cursor,
                       int* __restrict__ csr)
{
    int e = blockIdx.x * blockDim.x + threadIdx.x;
    int s, d;
    if (flag[0]) { s = eb[e]; d = eb[NEDGE + e]; }
    else {
        const long long* p = (const long long*)eb;
        s = (int)p[e]; d = (int)p[NEDGE + e];
    }
    int pos = atomicAdd(&cursor[d], 1);
    csr[off[d] + pos] = s;
}

// h2 rows are PRE-SCALED by dinv[row]; 1-ahead row prefetch.
__global__ __launch_bounds__(256) void gcn_gather(
    const u16* __restrict__ h2, const int* __restrict__ csr,
    const int* __restrict__ off, const float* __restrict__ dinv,
    const float* __restrict__ bias, const float* __restrict__ addx,
    float* __restrict__ out)
{
    int lane = threadIdx.x & 63, wv = threadIdx.x >> 6;
    int d = blockIdx.x * 4 + wv;
    float acc[8];
#pragma unroll
    for (int j = 0; j < 8; ++j) acc[j] = 0.f;
    int e0 = off[d], e1 = off[d + 1];
    float dd = dinv[d];
    int sidx = (e0 < e1) ? csr[e0] : d;
    u16x8 v = *(const u16x8*)&h2[(size_t)sidx * DIM + lane * 8];
    for (int e = e0; e < e1; ++e) {
        int snext = (e + 1 < e1) ? csr[e + 1] : d;
        u16x8 vn = *(const u16x8*)&h2[(size_t)snext * DIM + lane * 8];
#pragma unroll
        for (int j = 0; j < 8; ++j) acc[j] += b2f(v[j]);
        v = vn;
    }
#pragma unroll
    for (int j = 0; j < 8; ++j) acc[j] = (acc[j] + b2f(v[j])) * dd;
    float o[8];
#pragma unroll
    for (int j = 0; j < 8; ++j) {
        o[j] = acc[j] + bias[lane * 8 + j];
        if (addx) o[j] += addx[(size_t)d * DIM + lane * 8 + j];
    }
    float* op = out + (size_t)d * DIM + lane * 8;
    *(float4*)op = make_float4(o[0], o[1], o[2], o[3]);
    *(float4*)(op + 4) = make_float4(o[4], o[5], o[6], o[7]);
}

// ---------------------------------------------------------------------------
extern "C" void kernel_launch(void* const* d_in, const int* in_sizes, int n_in,
                              void* d_out, int out_size, void* d_ws, size_t ws_size,
                              hipStream_t stream)
{
    const float* x         = (const float*)d_in[0];
    const int*   edges     = (const int*)d_in[1];
    const float* cond      = (const float*)d_in[2];
    const float* bn_w      = (const float*)d_in[3];
    const float* bn_b      = (const float*)d_in[4];
    const float* gcn_in_w  = (const float*)d_in[5];
    const float* gcn_in_b  = (const float*)d_in[6];
    const float* gcn_out_w = (const float*)d_in[7];
    const float* gcn_out_b = (const float*)d_in[8];
    const float* Wq  = (const float*)d_in[9];
    const float* Wk  = (const float*)d_in[10];
    const float* Wv  = (const float*)d_in[11];
    const float* Wo  = (const float*)d_in[12];
    const float* ln2w = (const float*)d_in[13];
    const float* ln2b = (const float*)d_in[14];
    const float* ln3w = (const float*)d_in[15];
    const float* ln3b = (const float*)d_in[16];
    const float* ggw = (const float*)d_in[17];
    const float* ggb = (const float*)d_in[18];
    const float* fow = (const float*)d_in[19];
    const float* fob = (const float*)d_in[20];
    float* outp = (float*)d_out;

    char* wsb = (char*)d_ws;
    size_t wsoff = 0;
    auto alloc = [&](size_t bytes) -> void* {
        void* p = wsb + wsoff;
        wsoff = (wsoff + bytes + 255) & ~(size_t)255;
        return p;
    };
    u16*   wT    = (u16*)  alloc((size_t)17301504 * 2);
    u16*   condb = (u16*)  alloc((size_t)4096 * 512 * 2);
    float* h     = (float*)alloc((size_t)N_NODES * DIM * 4);
    u16*   t0b   = (u16*)  alloc((size_t)N_NODES * DIM * 2);
    u16*   qb    = (u16*)  alloc((size_t)N_NODES * DIM * 2);
    u16*   ob    = (u16*)  alloc((size_t)N_NODES * DIM * 2);
    u16*   kb    = (u16*)  alloc((size_t)4096 * 512 * 2);
    u16*   Vt    = (u16*)  alloc((size_t)BSZ * NHEAD * DHEAD * MCTX * 2);
    char*  zbase  = wsb + wsoff;
    float* colsum = (float*)alloc(DIM * 4);
    float* colsq  = (float*)alloc(DIM * 4);
    int*   deg    = (int*)  alloc(N_NODES * 4);
    int*   cursor = (int*)  alloc(N_NODES * 4);
    int*   eflag  = (int*)  alloc(256);
    size_t zbytes = (size_t)((wsb + wsoff) - zbase);
    float* bscale = (float*)alloc(DIM * 4);
    float* bshift = (float*)alloc(DIM * 4);
    float* dinv   = (float*)alloc(N_NODES * 4);
    int*   csr_off= (int*)  alloc((N_NODES + 16) * 4);
    int*   csr_src= (int*)  alloc((size_t)NEDGE * 4);

    // FFN chunking: Ab [rows][2048] bf16 ; rows must stay multiple of 256
    int nch = 0;
    for (int c = 1; c <= 16; c *= 2) {
        size_t need = ((size_t)N_NODES / c) * DFF * 2;
        if (wsoff + need <= ws_size) { nch = c; break; }
    }
    if (nch == 0) { fprintf(stderr, "ws too small (%zu)\n", ws_size); return; }
    u16* Abuf = (u16*)(wsb + wsoff);

    hipMemsetAsync(zbase, 0, zbytes, stream);

    // weight transposes (batched over layers); gg uses frag-pair perm
    u16* gcnInT  = wT;
    u16* gcnOutT = gcnInT + 262144;
    u16* WqT = gcnOutT + 262144;
    u16* WkT = WqT + 4 * 262144;
    u16* WvT = WkT + 4 * 262144;
    u16* WoT = WvT + 4 * 262144;
    u16* ggT = WoT + 4 * 262144;
    u16* foT = ggT + 4 * 2097152;
    transposeW<<<dim3(8, 8, 1), 256, 0, stream>>>(gcn_in_w,  gcnInT, 512, 512, 0, 0, 0);
    transposeW<<<dim3(8, 8, 1), 256, 0, stream>>>(gcn_out_w, gcnOutT, 512, 512, 0, 0, 0);
    transposeW<<<dim3(8, 8, 4), 256, 0, stream>>>(Wq, WqT, 512, 512, 262144, 262144, 0);
    transposeW<<<dim3(8, 8, 4), 256, 0, stream>>>(Wk, WkT, 512, 512, 262144, 262144, 0);
    transposeW<<<dim3(8, 8, 4), 256, 0, stream>>>(Wv, WvT, 512, 512, 262144, 262144, 0);
    transposeW<<<dim3(8, 8, 4), 256, 0, stream>>>(Wo, WoT, 512, 512, 262144, 262144, 0);
    transposeW<<<dim3(64, 8, 4), 256, 0, stream>>>(ggw, ggT, 512, DG, 2097152, 2097152, DFF);
    transposeW<<<dim3(8, 32, 4), 256, 0, stream>>>(fow, foT, DFF, 512, 1048576, 1048576, 0);
    conv_f2b<<<2048, 256, 0, stream>>>(cond, condb);

    // BatchNorm
    bn_colstats<<<128, 512, 0, stream>>>(x, colsum, colsq);
    bn_finalize<<<1, 512, 0, stream>>>(colsum, colsq, bn_w, bn_b, bscale, bshift);
    bn_apply_b<<<(N_NODES * DIM / 4) / 256, 256, 0, stream>>>(x, bscale, bshift, t0b);

    // graph prep
    detect_i64<<<NEDGE / 256, 256, 0, stream>>>(edges, eflag);
    deg_count<<<NEDGE / 256, 256, 0, stream>>>(edges, eflag, deg);
    dinv_k<<<N_NODES / 256, 256, 0, stream>>>(deg, dinv);
    scan_deg<<<1, 1024, 0, stream>>>(deg, csr_off);
    fill_k<<<NEDGE / 256, 256, 0, stream>>>(edges, eflag, csr_off, cursor, csr_src);

    // GCN in (rows pre-scaled by dinv via EPI=4)
    bgemm<4><<<dim3(4, 128, 1), 256, 0, stream>>>(
        t0b, 512, gcnInT, 512, nullptr, nullptr, 0, dinv, qb, 512, 512, 1,
        0, 0, 0, 0, 0, 0);
    gcn_gather<<<N_NODES / 4, 256, 0, stream>>>(qb, csr_src, csr_off, dinv,
                                                gcn_in_b, nullptr, h);

    const int ffrows = N_NODES / nch;
    for (int i = 0; i < NLAYER; ++i) {
        const u16* WqTi = WqT + (size_t)i * 262144;
        const u16* WkTi = WkT + (size_t)i * 262144;
        const u16* WvTi = WvT + (size_t)i * 262144;
        const u16* WoTi = WoT + (size_t)i * 262144;
        const u16* ggTi = ggT + (size_t)i * 2097152;
        const u16* foTi = foT + (size_t)i * 1048576;

        // attention
        layernorm_b<<<N_NODES / 4, 256, 0, stream>>>(h, ln2w + i * DIM, ln2b + i * DIM, t0b);
        bgemm<1><<<dim3(4, 128, 1), 256, 0, stream>>>(
            t0b, 512, WqTi, 512, nullptr, nullptr, 0, nullptr, qb, 512, 512, 1,
            0, 0, 0, 0, 0, 0);
        bgemm<1><<<dim3(4, 32, 1), 256, 0, stream>>>(
            condb, 512, WkTi, 512, nullptr, nullptr, 0, nullptr, kb, 512, 512, 1,
            0, 0, 0, 0, 0, 0);
        bgemm<3><<<dim3(4, 32, 1), 256, 0, stream>>>(
            condb, 512, WvTi, 512, nullptr, nullptr, 0, nullptr, Vt, 0, 512, 1,
            0, 0, 0, 0, 0, 0);
        fused_attn<<<dim3(4, 8, 16), 256, 0, stream>>>(qb, kb, Vt, ob);
        bgemm<2><<<dim3(4, 128, 1), 256, 0, stream>>>(
            ob, 512, WoTi, 512, nullptr, h, 512, nullptr, h, 512, 512, 1,
            0, 0, 0, 0, 0, 0);

        // GEGLU FFN: 256^2 8-phase GEMM with fused pair-in-thread activation
        layernorm_b<<<N_NODES / 4, 256, 0, stream>>>(h, ln3w + i * DIM, ln3b + i * DIM, t0b);
        for (int c = 0; c < nch; ++c) {
            const u16* ac = t0b + (size_t)c * ffrows * 512;
            float* hc = h + (size_t)c * ffrows * 512;
            bgemm256_geglu<<<dim3(DG / 256, ffrows / 256), 512, 0, stream>>>(
                ac, 512, ggTi, 512, ggb + (size_t)i * DG, Abuf, 512);
            bgemm<2><<<dim3(4, ffrows / 128, 1), 256, 0, stream>>>(
                Abuf, 2048, foTi, 2048, fob + (size_t)i * DIM, hc, 512, nullptr,
                hc, 512, 2048, 1, 0, 0, 0, 0, 0, 0);
        }
    }

    // GCN out + residual x
    conv_f2b<<<8192, 256, 0, stream>>>(h, t0b);
    bgemm<4><<<dim3(4, 128, 1), 256, 0, stream>>>(
        t0b, 512, gcnOutT, 512, nullptr, nullptr, 0, dinv, qb, 512, 512, 1,
        0, 0, 0, 0, 0, 0);
    gcn_gather<<<N_NODES / 4, 256, 0, stream>>>(qb, csr_src, csr_off, dinv,
                                                gcn_out_b, x, outp);
}

// Round 6
// 1234.705 us; speedup vs baseline: 9.5321x; 1.0713x over previous
//
#include <hip/hip_runtime.h>
#include <math.h>
#include <stdio.h>

#define N_NODES 16384
#define DIM     512
#define BSZ     16
#define SEQ     1024
#define MCTX    256
#define NHEAD   8
#define DHEAD   64
#define NLAYER  4
#define NEDGE   262144
#define DFF     2048
#define DG      4096
#define LNEPS   1e-5f

typedef unsigned short u16;
typedef __attribute__((ext_vector_type(8))) __bf16 bf16x8;
typedef __attribute__((ext_vector_type(4))) float f32x4;
typedef __attribute__((ext_vector_type(4))) unsigned short u16x4;
typedef __attribute__((ext_vector_type(8))) unsigned short u16x8;

__device__ __forceinline__ u16 f2b(float f) {
    unsigned u = __float_as_uint(f);
    unsigned r = (u + 0x7fff + ((u >> 16) & 1)) >> 16;
    return (u16)r;
}
__device__ __forceinline__ float b2f(u16 h) {
    return __uint_as_float((unsigned)h << 16);
}
__device__ __forceinline__ float gelu_exact(float x) {
    return 0.5f * x * (1.0f + erff(x * 0.70710678118654752f));
}
// tanh-approx gelu via hardware exp; |err| vs exact < 2e-3
__device__ __forceinline__ float gelu_fast(float x) {
    float u = x * (0.7978845608f + 0.0356774081f * x * x);
    float e = __expf(2.f * u);
    float t = 1.f - 2.f / (e + 1.f);
    return 0.5f * x * (1.f + t);
}
__device__ __forceinline__ void gload16(const void* g, void* l) {
    __builtin_amdgcn_global_load_lds(
        (const __attribute__((address_space(1))) unsigned int*)g,
        (__attribute__((address_space(3))) unsigned int*)l, 16, 0, 0);
}

// bijective XCD-chunk swizzle (m204)
__device__ __forceinline__ int2 xcd_map() {
    int gx = gridDim.x, gy = gridDim.y;
    int nwg = gx * gy;
    int id = blockIdx.y * gx + blockIdx.x;
    int q = nwg >> 3, r = nwg & 7;
    int xcd = id & 7, idx = id >> 3;
    int nid = (xcd < r ? xcd * (q + 1) : r * (q + 1) + (xcd - r) * q) + idx;
    int2 o; o.x = nid % gx; o.y = nid / gx; return o;
}

// ---------------------------------------------------------------------------
// 256x256 8-phase bf16 GEMM with fused GEGLU epilogue (pair-interleaved W).
// Reuse-ordered quadrants (0,0)->(0,1)->(1,1)->(1,0); B-Q0 fragments are
// register-carried ph0->ph3, so ds_reads per K-tile/wave = 12/4/8/0 (was 48).
// Staging safety: each region staged only after its last read in the tile.
// vmcnt(4) once per K-tile (counted, never 0 in steady state).
// ---------------------------------------------------------------------------
__global__ __launch_bounds__(512, 2) void bgemm256_geglu(
    const u16* __restrict__ A, long lda,
    const u16* __restrict__ Bt, long ldb,
    const float* __restrict__ bias,
    u16* __restrict__ Cb, int K)
{
    __shared__ u16 lds[65536];   // A0 A1 B0 B1, 32KB each (u16 offsets 16384)

    const int t = threadIdx.x;
    const int w = t >> 6, lane = t & 63;
    const int fr = lane & 15, fq = lane >> 4;
    int2 sw = xcd_map();
    const int row0 = sw.y * 256;
    const int col0 = sw.x * 256;
    const int wm0 = (w >> 2) * 128, wn0 = (w & 3) * 64;
    const int sl = (lane & 7) ^ ((lane >> 3) & 7);   // src slot for staging

    f32x4 acc[8][4];
#pragma unroll
    for (int mf = 0; mf < 8; ++mf)
#pragma unroll
        for (int nf = 0; nf < 4; ++nf) acc[mf][nf] = (f32x4){0.f, 0.f, 0.f, 0.f};

    auto stageA = [&](int kt_, int P, int bb) {
        const int k0 = kt_ << 6;
#pragma unroll
        for (int rd = 0; rd < 2; ++rd) {
            int rbase = rd * 128 + P * 64 + w * 8;            // wave-uniform
            int r = rbase + (lane >> 3);
            gload16(A + (size_t)(row0 + r) * lda + k0 + sl * 8,
                    (char*)(lds + bb * 16384) + rbase * 128);
        }
    };
    auto stageB = [&](int kt_, int Q, int bb) {
        const int k0 = kt_ << 6;
#pragma unroll
        for (int rd = 0; rd < 2; ++rd) {
            int jb = rd * 64 + w * 8;
            int nbase = ((jb >> 5) << 6) + Q * 32 + (jb & 31); // wave-uniform
            int n = nbase + (lane >> 3);
            gload16(Bt + (size_t)(col0 + n) * ldb + k0 + sl * 8,
                    (char*)(lds + 32768 + bb * 16384) + nbase * 128);
        }
    };

#define READ_A(MH, DST) do {                                                   \
    _Pragma("unroll")                                                          \
    for (int mi = 0; mi < 4; ++mi) {                                           \
        int r = wm0 + (MH) * 64 + mi * 16 + fr;                                \
        _Pragma("unroll")                                                      \
        for (int ks = 0; ks < 2; ++ks)                                         \
            DST[mi][ks] = *(const bf16x8*)&Ab_[r * 64 + (((ks*4+fq) ^ (fr&7)) * 8)]; \
    } } while (0)
#define READ_B(NH, DST) do {                                                   \
    _Pragma("unroll")                                                          \
    for (int ni = 0; ni < 2; ++ni) {                                           \
        int n = wn0 + (NH) * 32 + ni * 16 + fr;                                \
        _Pragma("unroll")                                                      \
        for (int ks = 0; ks < 2; ++ks)                                         \
            DST[ni][ks] = *(const bf16x8*)&Bb_[n * 64 + (((ks*4+fq) ^ (fr&7)) * 8)]; \
    } } while (0)
#define MFMA16(MH, NH, AV, BV)                                                 \
    _Pragma("unroll")                                                          \
    for (int mi = 0; mi < 4; ++mi)                                             \
        _Pragma("unroll")                                                      \
        for (int ni = 0; ni < 2; ++ni)                                         \
            _Pragma("unroll")                                                  \
            for (int ks = 0; ks < 2; ++ks)                                     \
                acc[(MH)*4+mi][(NH)*2+ni] = __builtin_amdgcn_mfma_f32_16x16x32_bf16( \
                    AV[mi][ks], BV[ni][ks], acc[(MH)*4+mi][(NH)*2+ni], 0, 0, 0)

    // prologue: tile0 all 4 regions + tile1 first 2 regions
    stageA(0, 0, 0); stageB(0, 0, 0); stageA(0, 1, 0); stageB(0, 1, 0);
    stageA(1, 0, 1); stageB(1, 0, 1);
    asm volatile("s_waitcnt vmcnt(4)" ::: "memory");
    __builtin_amdgcn_s_barrier();

    const int NT = K >> 6;
    for (int kt = 0; kt < NT; ++kt) {
        const int b = kt & 1;
        const bool s1 = (kt + 1 < NT), s2 = (kt + 2 < NT);
        const u16* Ab_ = lds + b * 16384;
        const u16* Bb_ = lds + 32768 + b * 16384;
        bf16x8 aR[4][2], bR[2][2], bK[2][2];

        // ph0: read A-P0 (8) + B-Q0 (4, kept in regs to ph3); MFMA (0,0)
        READ_A(0, aR); READ_B(0, bK);
        if (s1) stageA(kt + 1, 1, b ^ 1);
        __builtin_amdgcn_s_barrier();
        asm volatile("s_waitcnt lgkmcnt(0)" ::: "memory");
        __builtin_amdgcn_s_setprio(1);
        MFMA16(0, 0, aR, bK);
        __builtin_amdgcn_s_setprio(0);
        __builtin_amdgcn_s_barrier();

        // ph1: read B-Q1 (4); A-P0 reused from regs; MFMA (0,1)
        READ_B(1, bR);
        if (s1) stageB(kt + 1, 1, b ^ 1);
        __builtin_amdgcn_s_barrier();
        asm volatile("s_waitcnt lgkmcnt(0)" ::: "memory");
        __builtin_amdgcn_s_setprio(1);
        MFMA16(0, 1, aR, bR);
        __builtin_amdgcn_s_setprio(0);
        __builtin_amdgcn_s_barrier();

        // ph2: read A-P1 (8); B-Q1 reused; MFMA (1,1)
        READ_A(1, aR);
        if (s2) stageA(kt + 2, 0, b);
        __builtin_amdgcn_s_barrier();
        asm volatile("s_waitcnt lgkmcnt(0)" ::: "memory");
        __builtin_amdgcn_s_setprio(1);
        MFMA16(1, 1, aR, bR);
        __builtin_amdgcn_s_setprio(0);
        __builtin_amdgcn_s_barrier();

        // ph3: no ds_reads; A-P1 + register-carried B-Q0; MFMA (1,0)
        if (s2) stageB(kt + 2, 0, b);
        __builtin_amdgcn_s_barrier();
        __builtin_amdgcn_s_setprio(1);
        MFMA16(1, 0, aR, bK);
        __builtin_amdgcn_s_setprio(0);
        if (s2)      asm volatile("s_waitcnt vmcnt(4)" ::: "memory");
        else if (s1) asm volatile("s_waitcnt vmcnt(0)" ::: "memory");
        __builtin_amdgcn_s_barrier();
    }
#undef READ_A
#undef READ_B
#undef MFMA16

    // fused GEGLU epilogue: acc[mf][2P]=val frag, acc[mf][2P+1]=gate frag
    const int nbase = (col0 + wn0) >> 1;
    float bval[2], bgat[2];
#pragma unroll
    for (int P = 0; P < 2; ++P) {
        int n = nbase + P * 16 + fr;
        bval[P] = bias[n];
        bgat[P] = bias[DFF + n];
    }
#pragma unroll
    for (int mf = 0; mf < 8; ++mf) {
        const int rb = row0 + wm0 + mf * 16 + fq * 4;
#pragma unroll
        for (int P = 0; P < 2; ++P) {
            const int n = nbase + P * 16 + fr;
#pragma unroll
            for (int j = 0; j < 4; ++j) {
                float v = acc[mf][2 * P][j] + bval[P];
                float g = acc[mf][2 * P + 1][j] + bgat[P];
                Cb[(size_t)(rb + j) * DFF + n] = f2b(v * gelu_fast(g));
            }
        }
    }
}

// ---------------------------------------------------------------------------
// bf16 MFMA GEMM, 128x128 tile, BK=64, double-buffered LDS, XCD swizzle.
// EPI: 1 = bf16 out (+bias) ; 2 = f32 out = acc+bias+resid ;
//      3 = V-transpose (LDS bounce -> Vt[z][b][h][d][m]) ; 4 = bf16 rowscale
// ---------------------------------------------------------------------------
template<int EPI>
__global__ __launch_bounds__(256) void bgemm(
    const u16* __restrict__ A, long lda,
    const u16* __restrict__ Bt, long ldb,
    const float* __restrict__ bias,
    const float* __restrict__ resid, long ldr,
    const float* __restrict__ rowscale,
    void* __restrict__ Cv, long ldc, int K, int nlo,
    long aHi, long aLo, long bHi, long bLo, long cHi, long cLo)
{
    __shared__ u16 lds[32768];    // A0 | A1 | B0 | B1, 16KB each

    const int t = threadIdx.x;
    const int z = blockIdx.z;
    const int zhi = z / nlo, zlo = z % nlo;
    const u16* Ag = A + (size_t)zhi * aHi + (size_t)zlo * aLo;
    const u16* Bg = Bt + (size_t)zhi * bHi + (size_t)zlo * bLo;
    const long coff = (long)zhi * cHi + (long)zlo * cLo;

    int2 sw = xcd_map();
    const int row0 = sw.y * 128;
    const int col0 = sw.x * 128;
    const int wave = t >> 6, lane = t & 63;
    const int wm0 = (wave >> 1) * 64, wn0 = (wave & 1) * 64;
    const int fr = lane & 15, fq = lane >> 4;
    const int ldsWave = (t & 192) * 16;
    const int rS = t >> 3;
    const int slotP = t & 7;

    f32x4 acc[4][4];
#pragma unroll
    for (int mi = 0; mi < 4; ++mi)
#pragma unroll
        for (int ni = 0; ni < 4; ++ni) acc[mi][ni] = (f32x4){0.f, 0.f, 0.f, 0.f};

    auto stage = [&](int buf, int k0) {
        u16* Ad = lds + buf * 8192;
        u16* Bd = lds + 16384 + buf * 8192;
#pragma unroll
        for (int i = 0; i < 4; ++i) {
            int r = i * 32 + rS;
            int s2 = slotP ^ (r & 7);
            gload16(Ag + (size_t)(row0 + r) * lda + k0 + s2 * 8,
                    (char*)Ad + i * 4096 + ldsWave);
        }
#pragma unroll
        for (int i = 0; i < 4; ++i) {
            int r = i * 32 + rS;
            int s2 = slotP ^ (r & 7);
            gload16(Bg + (size_t)(col0 + r) * ldb + k0 + s2 * 8,
                    (char*)Bd + i * 4096 + ldsWave);
        }
    };
    auto compute = [&](int buf) {
        const u16* Ac = lds + buf * 8192;
        const u16* Bc = lds + 16384 + buf * 8192;
#pragma unroll
        for (int ks = 0; ks < 2; ++ks) {
            const int ksl = ks * 4 + fq;
            bf16x8 av[4], bv[4];
#pragma unroll
            for (int mi = 0; mi < 4; ++mi) {
                int r = wm0 + mi * 16 + fr;
                av[mi] = *(const bf16x8*)&Ac[r * 64 + ((ksl ^ (r & 7)) * 8)];
            }
#pragma unroll
            for (int ni = 0; ni < 4; ++ni) {
                int r = wn0 + ni * 16 + fr;
                bv[ni] = *(const bf16x8*)&Bc[r * 64 + ((ksl ^ (r & 7)) * 8)];
            }
#pragma unroll
            for (int mi = 0; mi < 4; ++mi)
#pragma unroll
                for (int ni = 0; ni < 4; ++ni)
                    acc[mi][ni] = __builtin_amdgcn_mfma_f32_16x16x32_bf16(
                        av[mi], bv[ni], acc[mi][ni], 0, 0, 0);
        }
    };

    int cur = 0;
    stage(0, 0);
    __syncthreads();
    for (int k0 = 64; k0 < K; k0 += 64) {
        stage(cur ^ 1, k0);
        compute(cur);
        __syncthreads();
        cur ^= 1;
    }
    compute(cur);

    if (EPI == 3) {
        __syncthreads();
        u16* Tw = lds + wave * 4608;   // 64 x 72
#pragma unroll
        for (int mi = 0; mi < 4; ++mi)
#pragma unroll
            for (int ni = 0; ni < 4; ++ni)
#pragma unroll
                for (int j = 0; j < 4; ++j)
                    Tw[(ni * 16 + fr) * 72 + mi * 16 + fq * 4 + j] =
                        f2b(acc[mi][ni][j]);
        const int r0w = row0 + wm0;
        const int b = r0w >> 8, m0w = r0w & 255;
        const int cc0 = col0 + wn0, hh = cc0 >> 6;
        u16* dst = (u16*)Cv + coff + ((size_t)(b * 8 + hh) * 64) * 256 + m0w;
#pragma unroll
        for (int it = 0; it < 8; ++it) {
            int dl = it * 8 + (lane >> 3);
            int ml = (lane & 7) * 8;
            u16x8 v = *(const u16x8*)&Tw[dl * 72 + ml];
            *(u16x8*)&dst[(size_t)dl * 256 + ml] = v;
        }
        return;
    }

    float* Cf = (float*)Cv;
    u16* Cb = (u16*)Cv;
#pragma unroll
    for (int mi = 0; mi < 4; ++mi) {
        const int rb = row0 + wm0 + mi * 16 + fq * 4;
#pragma unroll
        for (int ni = 0; ni < 4; ++ni) {
            const int cc = col0 + wn0 + ni * 16 + fr;
            f32x4 v = acc[mi][ni];
            float bval = 0.f;
            if ((EPI == 1 || EPI == 2) && bias) bval = bias[cc];
#pragma unroll
            for (int j = 0; j < 4; ++j) {
                const long r = rb + j;
                float o = v[j] + bval;
                if (EPI == 1) {
                    Cb[coff + r * ldc + cc] = f2b(o);
                } else if (EPI == 2) {
                    Cf[coff + r * ldc + cc] = o + resid[r * ldr + cc];
                } else if (EPI == 4) {
                    Cb[coff + r * ldc + cc] = f2b(o * rowscale[r]);
                }
            }
        }
    }
}

// ---------------------------------------------------------------------------
// Batched weight transpose+convert: src f32 [K][N] -> dst bf16 [N][K].
// permN > 0: GEGLU frag-pair interleave — val n -> (n/16)*32 + n%16,
//            gate m=n-permN -> (m/16)*32 + 16 + m%16
// ---------------------------------------------------------------------------
__global__ __launch_bounds__(256) void transposeW(const float* __restrict__ src,
                                                  u16* __restrict__ dst,
                                                  int K, int N,
                                                  long srcZ, long dstZ, int permN)
{
    __shared__ float tile[64][65];
    const int t = threadIdx.x;
    const int n0 = blockIdx.x * 64, k0 = blockIdx.y * 64;
    const float* s = src + (size_t)blockIdx.z * srcZ;
    u16* d = dst + (size_t)blockIdx.z * dstZ;
#pragma unroll
    for (int i = 0; i < 16; ++i) {
        int idx = i * 256 + t;
        int rr = idx >> 6, cc = idx & 63;
        tile[rr][cc] = s[(size_t)(k0 + rr) * N + n0 + cc];
    }
    __syncthreads();
#pragma unroll
    for (int i = 0; i < 16; ++i) {
        int idx = i * 256 + t;
        int rr = idx >> 6, cc = idx & 63;
        int n = n0 + rr;
        int p = n;
        if (permN) {
            p = (n < permN) ? (((n >> 4) << 5) + (n & 15))
                            : ((((n - permN) >> 4) << 5) + 16 + ((n - permN) & 15));
        }
        d[(size_t)p * K + k0 + cc] = f2b(tile[cc][rr]);
    }
}

__global__ __launch_bounds__(256) void conv_f2b(const float* __restrict__ in,
                                                u16* __restrict__ out)
{
    size_t i = (size_t)blockIdx.x * 256 + threadIdx.x;
    float4 v = ((const float4*)in)[i];
    u16x4 o;
    o[0] = f2b(v.x); o[1] = f2b(v.y); o[2] = f2b(v.z); o[3] = f2b(v.w);
    ((u16x4*)out)[i] = o;
}

// ---------------------------------------------------------------------------
__global__ __launch_bounds__(512) void bn_colstats(const float* __restrict__ x,
                                                   float* __restrict__ cs,
                                                   float* __restrict__ cq)
{
    int c = threadIdx.x;
    int r0 = blockIdx.x * 128;
    float s = 0.f, q = 0.f;
    for (int r = 0; r < 128; ++r) {
        float v = x[(size_t)(r0 + r) * DIM + c];
        s += v; q += v * v;
    }
    atomicAdd(&cs[c], s);
    atomicAdd(&cq[c], q);
}

__global__ void bn_finalize(const float* __restrict__ cs, const float* __restrict__ cq,
                            const float* __restrict__ bw, const float* __restrict__ bb,
                            float* __restrict__ scale, float* __restrict__ shift)
{
    int c = threadIdx.x;
    float m   = cs[c] * (1.f / N_NODES);
    float var = cq[c] * (1.f / N_NODES) - m * m;
    float rs  = rsqrtf(var + LNEPS);
    float sc  = rs * bw[c];
    scale[c] = sc;
    shift[c] = bb[c] - m * sc;
}

__global__ __launch_bounds__(256) void bn_apply_b(const float* __restrict__ x,
                                                  const float* __restrict__ scale,
                                                  const float* __restrict__ shift,
                                                  u16* __restrict__ out)
{
    size_t idx = (size_t)blockIdx.x * 256 + threadIdx.x;
    int c4 = (int)(idx & 127);
    float4 v  = ((const float4*)x)[idx];
    float4 sc = ((const float4*)scale)[c4];
    float4 sh = ((const float4*)shift)[c4];
    u16x4 o;
    o[0] = f2b(v.x * sc.x + sh.x); o[1] = f2b(v.y * sc.y + sh.y);
    o[2] = f2b(v.z * sc.z + sh.z); o[3] = f2b(v.w * sc.w + sh.w);
    ((u16x4*)out)[idx] = o;
}

__global__ __launch_bounds__(256) void layernorm_b(const float* __restrict__ in,
                                                   const float* __restrict__ w,
                                                   const float* __restrict__ bsh,
                                                   u16* __restrict__ out)
{
    int lane = threadIdx.x & 63, wv = threadIdx.x >> 6;
    size_t row = (size_t)blockIdx.x * 4 + wv;
    const float* p = in + row * DIM + lane * 8;
    float4 v0 = *(const float4*)p;
    float4 v1 = *(const float4*)(p + 4);
    float s = v0.x + v0.y + v0.z + v0.w + v1.x + v1.y + v1.z + v1.w;
    float q = v0.x * v0.x + v0.y * v0.y + v0.z * v0.z + v0.w * v0.w +
              v1.x * v1.x + v1.y * v1.y + v1.z * v1.z + v1.w * v1.w;
    for (int m = 1; m < 64; m <<= 1) {
        s += __shfl_xor(s, m, 64);
        q += __shfl_xor(q, m, 64);
    }
    float mean = s * (1.f / DIM);
    float rs = rsqrtf(q * (1.f / DIM) - mean * mean + LNEPS);
    float4 w0 = *(const float4*)(w + lane * 8),   w1 = *(const float4*)(w + lane * 8 + 4);
    float4 b0 = *(const float4*)(bsh + lane * 8), b1 = *(const float4*)(bsh + lane * 8 + 4);
    u16x8 o;
    o[0] = f2b((v0.x - mean) * rs * w0.x + b0.x);
    o[1] = f2b((v0.y - mean) * rs * w0.y + b0.y);
    o[2] = f2b((v0.z - mean) * rs * w0.z + b0.z);
    o[3] = f2b((v0.w - mean) * rs * w0.w + b0.w);
    o[4] = f2b((v1.x - mean) * rs * w1.x + b1.x);
    o[5] = f2b((v1.y - mean) * rs * w1.y + b1.y);
    o[6] = f2b((v1.z - mean) * rs * w1.z + b1.z);
    o[7] = f2b((v1.w - mean) * rs * w1.w + b1.w);
    *(u16x8*)(out + row * DIM + lane * 8) = o;
}

// ---------------------------------------------------------------------------
// Fused attention (MCTX fits LDS). Per block: 256 q-rows, one (head, batch).
// ---------------------------------------------------------------------------
__global__ __launch_bounds__(256) void fused_attn(
    const u16* __restrict__ Q,    // [16384][512]
    const u16* __restrict__ Kp,   // [4096][512]
    const u16* __restrict__ Vt,   // [16][8][64][256]
    u16* __restrict__ O)          // [16384][512]
{
    __shared__ u16 Ks[256 * 64];
    __shared__ u16 Vs[64 * 256];
    __shared__ u16 Ps[4][16 * 256];

    const int t = threadIdx.x;
    const int wave = t >> 6, lane = t & 63;
    const int fr = lane & 15, fq = lane >> 4;
    const int qc = blockIdx.x, h = blockIdx.y, b = blockIdx.z;
    const int ldsW = (t & 192) * 16;

#pragma unroll
    for (int i = 0; i < 8; ++i) {
        int idx = i * 256 + t;
        int m = idx >> 3, s = idx & 7;
        gload16(Kp + (size_t)(b * MCTX + m) * 512 + h * 64 + ((s ^ (m & 7)) * 8),
                (char*)Ks + i * 4096 + ldsW);
    }
#pragma unroll
    for (int i = 0; i < 8; ++i) {
        int idx = i * 256 + t;
        int d = idx >> 5, s = idx & 31;
        gload16(Vt + (size_t)((b * 8 + h) * 64 + d) * 256 + ((s ^ (d & 7)) * 8),
                (char*)Vs + i * 4096 + ldsW);
    }
    __syncthreads();

    u16* Pw = Ps[wave];
    for (int it = 0; it < 4; ++it) {
        const int q0 = qc * 256 + it * 64 + wave * 16;
        bf16x8 aq[2];
#pragma unroll
        for (int ks = 0; ks < 2; ++ks)
            aq[ks] = *(const bf16x8*)&Q[(size_t)(b * SEQ + q0 + fr) * 512 +
                                        h * 64 + ks * 32 + fq * 8];
        f32x4 accS[16];
#pragma unroll
        for (int ni = 0; ni < 16; ++ni) accS[ni] = (f32x4){0.f, 0.f, 0.f, 0.f};
#pragma unroll
        for (int ni = 0; ni < 16; ++ni) {
            int m = ni * 16 + fr;
#pragma unroll
            for (int ks = 0; ks < 2; ++ks) {
                bf16x8 bv = *(const bf16x8*)&Ks[m * 64 + (((ks * 4 + fq) ^ (m & 7)) * 8)];
                accS[ni] = __builtin_amdgcn_mfma_f32_16x16x32_bf16(
                    aq[ks], bv, accS[ni], 0, 0, 0);
            }
        }
        const float cs = 0.125f;
#pragma unroll
        for (int j = 0; j < 4; ++j) {
            float m0 = accS[0][j];
#pragma unroll
            for (int ni = 1; ni < 16; ++ni) m0 = fmaxf(m0, accS[ni][j]);
            m0 = fmaxf(m0, __shfl_xor(m0, 1, 64));
            m0 = fmaxf(m0, __shfl_xor(m0, 2, 64));
            m0 = fmaxf(m0, __shfl_xor(m0, 4, 64));
            m0 = fmaxf(m0, __shfl_xor(m0, 8, 64));
            float s0 = 0.f;
#pragma unroll
            for (int ni = 0; ni < 16; ++ni) {
                float p = __expf((accS[ni][j] - m0) * cs);
                accS[ni][j] = p;
                s0 += p;
            }
            s0 += __shfl_xor(s0, 1, 64);
            s0 += __shfl_xor(s0, 2, 64);
            s0 += __shfl_xor(s0, 4, 64);
            s0 += __shfl_xor(s0, 8, 64);
            float inv = 1.f / s0;
#pragma unroll
            for (int ni = 0; ni < 16; ++ni) {
                int cc = ni * 16 + fr;
                int rr = fq * 4 + j;
                Pw[rr * 256 + (((cc >> 3) ^ (rr & 7)) * 8) + (cc & 7)] =
                    f2b(accS[ni][j] * inv);
            }
        }
        bf16x8 ap[8];
#pragma unroll
        for (int ks = 0; ks < 8; ++ks)
            ap[ks] = *(const bf16x8*)&Pw[fr * 256 + (((ks * 4 + fq) ^ (fr & 7)) * 8)];
        f32x4 accO[4];
#pragma unroll
        for (int ni = 0; ni < 4; ++ni) accO[ni] = (f32x4){0.f, 0.f, 0.f, 0.f};
#pragma unroll
        for (int ni = 0; ni < 4; ++ni) {
            int d = ni * 16 + fr;
#pragma unroll
            for (int ks = 0; ks < 8; ++ks) {
                bf16x8 bv = *(const bf16x8*)&Vs[d * 256 + (((ks * 4 + fq) ^ (d & 7)) * 8)];
                accO[ni] = __builtin_amdgcn_mfma_f32_16x16x32_bf16(
                    ap[ks], bv, accO[ni], 0, 0, 0);
            }
        }
#pragma unroll
        for (int ni = 0; ni < 4; ++ni)
#pragma unroll
            for (int j = 0; j < 4; ++j)
                O[(size_t)(b * SEQ + q0 + fq * 4 + j) * 512 + h * 64 + ni * 16 + fr] =
                    f2b(accO[ni][j]);
    }
}

// ---------------------------------------------------------------------------
__global__ void detect_i64(const int* __restrict__ e, int* __restrict__ flag)
{
    int idx = blockIdx.x * blockDim.x + threadIdx.x;
    if (e[2 * idx + 1] != 0) flag[0] = 1;
}

__global__ void deg_count(const int* __restrict__ eb, const int* __restrict__ flag,
                          int* __restrict__ deg)
{
    int e = blockIdx.x * blockDim.x + threadIdx.x;
    int d;
    if (flag[0]) d = eb[NEDGE + e];
    else         d = (int)((const long long*)eb)[NEDGE + e];
    atomicAdd(&deg[d], 1);
}

__global__ void dinv_k(const int* __restrict__ deg, float* __restrict__ dinv)
{
    int i = blockIdx.x * blockDim.x + threadIdx.x;
    dinv[i] = rsqrtf((float)(deg[i] + 1));
}

__global__ __launch_bounds__(1024) void scan_deg(const int* __restrict__ deg,
                                                 int* __restrict__ off)
{
    __shared__ int sums[1024];
    int t = threadIdx.x;
    int base = t * 16;
    int v[16]; int s = 0;
#pragma unroll
    for (int i = 0; i < 16; ++i) { v[i] = deg[base + i]; s += v[i]; }
    sums[t] = s;
    __syncthreads();
    for (int ofs = 1; ofs < 1024; ofs <<= 1) {
        int x = (t >= ofs) ? sums[t - ofs] : 0;
        __syncthreads();
        sums[t] += x;
        __syncthreads();
    }
    int run = (t == 0) ? 0 : sums[t - 1];
#pragma unroll
    for (int i = 0; i < 16; ++i) { off[base + i] = run; run += v[i]; }
    if (t == 1023) off[N_NODES] = run;
}

__global__ void fill_k(const int* __restrict__ eb, const int* __restrict__ flag,
                       const int* __restrict__ off, int* __restrict__ cursor,
                       int* __restrict__ csr)
{
    int e = blockIdx.x * blockDim.x + threadIdx.x;
    int s, d;
    if (flag[0]) { s = eb[e]; d = eb[NEDGE + e]; }
    else {
        const long long* p = (const long long*)eb;
        s = (int)p[e]; d = (int)p[NEDGE + e];
    }
    int pos = atomicAdd(&cursor[d], 1);
    csr[off[d] + pos] = s;
}

// h2 rows are PRE-SCALED by dinv[row]; 1-ahead row prefetch.
__global__ __launch_bounds__(256) void gcn_gather(
    const u16* __restrict__ h2, const int* __restrict__ csr,
    const int* __restrict__ off, const float* __restrict__ dinv,
    const float* __restrict__ bias, const float* __restrict__ addx,
    float* __restrict__ out)
{
    int lane = threadIdx.x & 63, wv = threadIdx.x >> 6;
    int d = blockIdx.x * 4 + wv;
    float acc[8];
#pragma unroll
    for (int j = 0; j < 8; ++j) acc[j] = 0.f;
    int e0 = off[d], e1 = off[d + 1];
    float dd = dinv[d];
    int sidx = (e0 < e1) ? csr[e0] : d;
    u16x8 v = *(const u16x8*)&h2[(size_t)sidx * DIM + lane * 8];
    for (int e = e0; e < e1; ++e) {
        int snext = (e + 1 < e1) ? csr[e + 1] : d;
        u16x8 vn = *(const u16x8*)&h2[(size_t)snext * DIM + lane * 8];
#pragma unroll
        for (int j = 0; j < 8; ++j) acc[j] += b2f(v[j]);
        v = vn;
    }
#pragma unroll
    for (int j = 0; j < 8; ++j) acc[j] = (acc[j] + b2f(v[j])) * dd;
    float o[8];
#pragma unroll
    for (int j = 0; j < 8; ++j) {
        o[j] = acc[j] + bias[lane * 8 + j];
        if (addx) o[j] += addx[(size_t)d * DIM + lane * 8 + j];
    }
    float* op = out + (size_t)d * DIM + lane * 8;
    *(float4*)op = make_float4(o[0], o[1], o[2], o[3]);
    *(float4*)(op + 4) = make_float4(o[4], o[5], o[6], o[7]);
}

// ---------------------------------------------------------------------------
extern "C" void kernel_launch(void* const* d_in, const int* in_sizes, int n_in,
                              void* d_out, int out_size, void* d_ws, size_t ws_size,
                              hipStream_t stream)
{
    const float* x         = (const float*)d_in[0];
    const int*   edges     = (const int*)d_in[1];
    const float* cond      = (const float*)d_in[2];
    const float* bn_w      = (const float*)d_in[3];
    const float* bn_b      = (const float*)d_in[4];
    const float* gcn_in_w  = (const float*)d_in[5];
    const float* gcn_in_b  = (const float*)d_in[6];
    const float* gcn_out_w = (const float*)d_in[7];
    const float* gcn_out_b = (const float*)d_in[8];
    const float* Wq  = (const float*)d_in[9];
    const float* Wk  = (const float*)d_in[10];
    const float* Wv  = (const float*)d_in[11];
    const float* Wo  = (const float*)d_in[12];
    const float* ln2w = (const float*)d_in[13];
    const float* ln2b = (const float*)d_in[14];
    const float* ln3w = (const float*)d_in[15];
    const float* ln3b = (const float*)d_in[16];
    const float* ggw = (const float*)d_in[17];
    const float* ggb = (const float*)d_in[18];
    const float* fow = (const float*)d_in[19];
    const float* fob = (const float*)d_in[20];
    float* outp = (float*)d_out;

    char* wsb = (char*)d_ws;
    size_t wsoff = 0;
    auto alloc = [&](size_t bytes) -> void* {
        void* p = wsb + wsoff;
        wsoff = (wsoff + bytes + 255) & ~(size_t)255;
        return p;
    };
    u16*   wT    = (u16*)  alloc((size_t)17301504 * 2);
    u16*   condb = (u16*)  alloc((size_t)4096 * 512 * 2);
    float* h     = (float*)alloc((size_t)N_NODES * DIM * 4);
    u16*   t0b   = (u16*)  alloc((size_t)N_NODES * DIM * 2);
    u16*   qb    = (u16*)  alloc((size_t)N_NODES * DIM * 2);
    u16*   ob    = (u16*)  alloc((size_t)N_NODES * DIM * 2);
    u16*   kb    = (u16*)  alloc((size_t)NLAYER * 4096 * 512 * 2);          // all layers
    u16*   Vt    = (u16*)  alloc((size_t)NLAYER * BSZ * NHEAD * DHEAD * MCTX * 2);
    char*  zbase  = wsb + wsoff;
    float* colsum = (float*)alloc(DIM * 4);
    float* colsq  = (float*)alloc(DIM * 4);
    int*   deg    = (int*)  alloc(N_NODES * 4);
    int*   cursor = (int*)  alloc(N_NODES * 4);
    int*   eflag  = (int*)  alloc(256);
    size_t zbytes = (size_t)((wsb + wsoff) - zbase);
    float* bscale = (float*)alloc(DIM * 4);
    float* bshift = (float*)alloc(DIM * 4);
    float* dinv   = (float*)alloc(N_NODES * 4);
    int*   csr_off= (int*)  alloc((N_NODES + 16) * 4);
    int*   csr_src= (int*)  alloc((size_t)NEDGE * 4);

    // FFN chunking: Ab [rows][2048] bf16 ; rows stay multiple of 256
    int nch = 0;
    for (int c = 1; c <= 16; c *= 2) {
        size_t need = ((size_t)N_NODES / c) * DFF * 2;
        if (wsoff + need <= ws_size) { nch = c; break; }
    }
    if (nch == 0) { fprintf(stderr, "ws too small (%zu)\n", ws_size); return; }
    u16* Abuf = (u16*)(wsb + wsoff);

    hipMemsetAsync(zbase, 0, zbytes, stream);

    // weight transposes (batched over layers); gg uses frag-pair perm
    u16* gcnInT  = wT;
    u16* gcnOutT = gcnInT + 262144;
    u16* WqT = gcnOutT + 262144;
    u16* WkT = WqT + 4 * 262144;
    u16* WvT = WkT + 4 * 262144;
    u16* WoT = WvT + 4 * 262144;
    u16* ggT = WoT + 4 * 262144;
    u16* foT = ggT + 4 * 2097152;
    transposeW<<<dim3(8, 8, 1), 256, 0, stream>>>(gcn_in_w,  gcnInT, 512, 512, 0, 0, 0);
    transposeW<<<dim3(8, 8, 1), 256, 0, stream>>>(gcn_out_w, gcnOutT, 512, 512, 0, 0, 0);
    transposeW<<<dim3(8, 8, 4), 256, 0, stream>>>(Wq, WqT, 512, 512, 262144, 262144, 0);
    transposeW<<<dim3(8, 8, 4), 256, 0, stream>>>(Wk, WkT, 512, 512, 262144, 262144, 0);
    transposeW<<<dim3(8, 8, 4), 256, 0, stream>>>(Wv, WvT, 512, 512, 262144, 262144, 0);
    transposeW<<<dim3(8, 8, 4), 256, 0, stream>>>(Wo, WoT, 512, 512, 262144, 262144, 0);
    transposeW<<<dim3(64, 8, 4), 256, 0, stream>>>(ggw, ggT, 512, DG, 2097152, 2097152, DFF);
    transposeW<<<dim3(8, 32, 4), 256, 0, stream>>>(fow, foT, DFF, 512, 1048576, 1048576, 0);
    conv_f2b<<<2048, 256, 0, stream>>>(cond, condb);

    // BatchNorm
    bn_colstats<<<128, 512, 0, stream>>>(x, colsum, colsq);
    bn_finalize<<<1, 512, 0, stream>>>(colsum, colsq, bn_w, bn_b, bscale, bshift);
    bn_apply_b<<<(N_NODES * DIM / 4) / 256, 256, 0, stream>>>(x, bscale, bshift, t0b);

    // graph prep
    detect_i64<<<NEDGE / 256, 256, 0, stream>>>(edges, eflag);
    deg_count<<<NEDGE / 256, 256, 0, stream>>>(edges, eflag, deg);
    dinv_k<<<N_NODES / 256, 256, 0, stream>>>(deg, dinv);
    scan_deg<<<1, 1024, 0, stream>>>(deg, csr_off);
    fill_k<<<NEDGE / 256, 256, 0, stream>>>(edges, eflag, csr_off, cursor, csr_src);

    // K/V projections for ALL layers (cond is layer-invariant), batched z=4
    bgemm<1><<<dim3(4, 32, 4), 256, 0, stream>>>(
        condb, 512, WkT, 512, nullptr, nullptr, 0, nullptr, kb, 512, 512, 1,
        0, 0, 262144, 0, (long)4096 * 512, 0);
    bgemm<3><<<dim3(4, 32, 4), 256, 0, stream>>>(
        condb, 512, WvT, 512, nullptr, nullptr, 0, nullptr, Vt, 0, 512, 1,
        0, 0, 262144, 0, (long)BSZ * NHEAD * DHEAD * MCTX, 0);

    // GCN in (rows pre-scaled by dinv via EPI=4)
    bgemm<4><<<dim3(4, 128, 1), 256, 0, stream>>>(
        t0b, 512, gcnInT, 512, nullptr, nullptr, 0, dinv, qb, 512, 512, 1,
        0, 0, 0, 0, 0, 0);
    gcn_gather<<<N_NODES / 4, 256, 0, stream>>>(qb, csr_src, csr_off, dinv,
                                                gcn_in_b, nullptr, h);

    const int ffrows = N_NODES / nch;
    for (int i = 0; i < NLAYER; ++i) {
        const u16* WqTi = WqT + (size_t)i * 262144;
        const u16* WoTi = WoT + (size_t)i * 262144;
        const u16* ggTi = ggT + (size_t)i * 2097152;
        const u16* foTi = foT + (size_t)i * 1048576;
        const u16* kbi  = kb + (size_t)i * 4096 * 512;
        const u16* Vti  = Vt + (size_t)i * BSZ * NHEAD * DHEAD * MCTX;

        // attention
        layernorm_b<<<N_NODES / 4, 256, 0, stream>>>(h, ln2w + i * DIM, ln2b + i * DIM, t0b);
        bgemm<1><<<dim3(4, 128, 1), 256, 0, stream>>>(
            t0b, 512, WqTi, 512, nullptr, nullptr, 0, nullptr, qb, 512, 512, 1,
            0, 0, 0, 0, 0, 0);
        fused_attn<<<dim3(4, 8, 16), 256, 0, stream>>>(qb, kbi, Vti, ob);
        bgemm<2><<<dim3(4, 128, 1), 256, 0, stream>>>(
            ob, 512, WoTi, 512, nullptr, h, 512, nullptr, h, 512, 512, 1,
            0, 0, 0, 0, 0, 0);

        // GEGLU FFN: 256^2 8-phase GEMM with fused pair-in-thread activation
        layernorm_b<<<N_NODES / 4, 256, 0, stream>>>(h, ln3w + i * DIM, ln3b + i * DIM, t0b);
        for (int c = 0; c < nch; ++c) {
            const u16* ac = t0b + (size_t)c * ffrows * 512;
            float* hc = h + (size_t)c * ffrows * 512;
            bgemm256_geglu<<<dim3(DG / 256, ffrows / 256), 512, 0, stream>>>(
                ac, 512, ggTi, 512, ggb + (size_t)i * DG, Abuf, 512);
            bgemm<2><<<dim3(4, ffrows / 128, 1), 256, 0, stream>>>(
                Abuf, 2048, foTi, 2048, fob + (size_t)i * DIM, hc, 512, nullptr,
                hc, 512, 2048, 1, 0, 0, 0, 0, 0, 0);
        }
    }

    // GCN out + residual x
    conv_f2b<<<8192, 256, 0, stream>>>(h, t0b);
    bgemm<4><<<dim3(4, 128, 1), 256, 0, stream>>>(
        t0b, 512, gcnOutT, 512, nullptr, nullptr, 0, dinv, qb, 512, 512, 1,
        0, 0, 0, 0, 0, 0);
    gcn_gather<<<N_NODES / 4, 256, 0, stream>>>(qb, csr_src, csr_off, dinv,
                                                gcn_out_b, x, outp);
}